// Round 2
// baseline (360.712 us; speedup 1.0000x reference)
//
#include <hip/hip_runtime.h>
#include <hip/hip_bf16.h>
#include <math.h>

// Transformer block (pre-LN attn + MLP), B=4 T=1024 H=1024 K=16 HD=64.
// GEMMs: bf16 MFMA 16x16x32, global_load_lds width=16 staging, BK=64 with
// xor-swizzled LDS chunk placement (0 bank conflicts, verified R8).
// R12: mlp2 stays 128x128 (AI=64) but split-K 2 -> 4: grid(32,8,4)=1024
// blocks = 4 blocks/CU. R11's 512-block config was latency-bound (2
// blocks/CU, Occupancy 17.8%, MfmaUtil 20.7%) -- the 2-barrier loop needs
// ~4 co-resident blocks/CU to hide the staging drain (m114). Cost: atomic
// WRITE_SIZE doubles to ~64MB (~+5us), gain ~-20us on the GEMM.
// Attention: fused flash-style, 64-row Q-tiles, exp2-domain softmax (scale
// folded into Q); masked logits FILLED with 1e-9; fully-masked K-tiles
// contribute exp(1e-9-m)*suffixV analytically (TV precomputed).

typedef __attribute__((ext_vector_type(8))) short bf16x8;
typedef __attribute__((ext_vector_type(4))) float f32x4;

#define DEVINL __device__ __forceinline__

#define LOG2E_SCALE 0.18033688f      /* 0.125 * log2(e) */
#define MASK2 1.4426950408889634e-9f /* 1e-9 * log2(e) */

DEVINL void stage16(const __hip_bfloat16* g, short* l) {
  __builtin_amdgcn_global_load_lds(
      (const __attribute__((address_space(1))) unsigned int*)g,
      (__attribute__((address_space(3))) unsigned int*)l, 16, 0, 0);
}

DEVINL float bf2f(short u) {
  unsigned x = ((unsigned)(unsigned short)u) << 16;
  float f; __builtin_memcpy(&f, &x, 4); return f;
}

DEVINL short f2bf_s(float f) {
  __hip_bfloat16 h = __float2bfloat16(f);
  short s; __builtin_memcpy(&s, &h, 2); return s;
}

DEVINL float block_sum(float v, float* sb) {
  #pragma unroll
  for (int o = 32; o; o >>= 1) v += __shfl_down(v, o);
  const int lane = threadIdx.x & 63, w = threadIdx.x >> 6;
  if (lane == 0) sb[w] = v;
  __syncthreads();
  float r = sb[0] + sb[1] + sb[2] + sb[3];
  __syncthreads();
  return r;
}

// ---- GEMM core BK=64: C[M,N] += A[M,Kd] * Bt[N,Kd]^T, 256 threads ----
template<int BM, int BN, int WM, int WN>
DEVINL void gemm_core64(const __hip_bfloat16* __restrict__ A, int lda,
                        const __hip_bfloat16* __restrict__ Bt, int ldb,
                        int Kd, int row0, int col0,
                        f32x4 (&acc)[WM/16][WN/16],
                        short* lds_a, short* lds_b) {
  constexpr int MI = WM / 16, NI = WN / 16, WNC = BN / WN;
  constexpr int CA = BM * 8, CB = BN * 8;  // 16B chunks per tile
  const int tid = threadIdx.x;
  const int lane = tid & 63, wave = tid >> 6;
  const int wm = (wave / WNC) * WM, wn = (wave % WNC) * WN;
  const int lr = lane & 15, lq = lane >> 4;
  for (int k0 = 0; k0 < Kd; k0 += 64) {
    #pragma unroll
    for (int c = tid; c < CA; c += 256) {
      const int r = c >> 3, kc = ((c & 7) ^ (r & 7)) << 3;
      stage16(A + (size_t)(row0 + r) * lda + k0 + kc, lds_a + c * 8);
    }
    #pragma unroll
    for (int c = tid; c < CB; c += 256) {
      const int r = c >> 3, kc = ((c & 7) ^ (r & 7)) << 3;
      stage16(Bt + (size_t)(col0 + r) * ldb + k0 + kc, lds_b + c * 8);
    }
    __syncthreads();
    #pragma unroll
    for (int s = 0; s < 2; s++) {
      bf16x8 af[MI], bfr[NI];
      #pragma unroll
      for (int mi = 0; mi < MI; mi++) {
        const int m = wm + mi * 16 + lr;
        af[mi] = *(const bf16x8*)(lds_a + m * 64 + (((s * 4 + lq) ^ (m & 7)) << 3));
      }
      #pragma unroll
      for (int ni = 0; ni < NI; ni++) {
        const int n = wn + ni * 16 + lr;
        bfr[ni] = *(const bf16x8*)(lds_b + n * 64 + (((s * 4 + lq) ^ (n & 7)) << 3));
      }
      #pragma unroll
      for (int mi = 0; mi < MI; mi++)
        #pragma unroll
        for (int ni = 0; ni < NI; ni++)
          acc[mi][ni] = __builtin_amdgcn_mfma_f32_16x16x32_bf16(
              af[mi], bfr[ni], acc[mi][ni], 0, 0, 0);
    }
    __syncthreads();
  }
}

// ---- transpose + f32->bf16: src[R][C] -> dst[(c+off)][r], dst pitch P ----
__global__ __launch_bounds__(256) void k_tcvt(const float* __restrict__ src,
                                              __hip_bfloat16* __restrict__ dst,
                                              int R, int C, int dstOff, int dstPitch) {
  __shared__ float tile[32][33];
  const int c0 = blockIdx.x * 32, r0 = blockIdx.y * 32;
  const int tx = threadIdx.x, ty = threadIdx.y;  // (32,8)
  #pragma unroll
  for (int i = 0; i < 32; i += 8)
    tile[ty + i][tx] = src[(size_t)(r0 + ty + i) * C + c0 + tx];
  __syncthreads();
  #pragma unroll
  for (int i = 0; i < 32; i += 8)
    dst[(size_t)(c0 + ty + i + dstOff) * dstPitch + r0 + tx] =
        __float2bfloat16(tile[tx][ty + i]);
}

// fused Wq/Wk/Wv transpose (z picks source; all 1024x1024, dst pitch 1024)
__global__ __launch_bounds__(256) void k_tcvt3(const float* __restrict__ Wq,
                                               const float* __restrict__ Wk,
                                               const float* __restrict__ Wv,
                                               __hip_bfloat16* __restrict__ dst) {
  __shared__ float tile[32][33];
  const float* src = blockIdx.z == 0 ? Wq : (blockIdx.z == 1 ? Wk : Wv);
  const int dstOff = blockIdx.z << 10;
  const int c0 = blockIdx.x * 32, r0 = blockIdx.y * 32;
  const int tx = threadIdx.x, ty = threadIdx.y;
  #pragma unroll
  for (int i = 0; i < 32; i += 8)
    tile[ty + i][tx] = src[(size_t)(r0 + ty + i) * 1024 + c0 + tx];
  __syncthreads();
  #pragma unroll
  for (int i = 0; i < 32; i += 8)
    dst[(size_t)(c0 + ty + i + dstOff) * 1024 + r0 + tx] =
        __float2bfloat16(tile[tx][ty + i]);
}

__global__ __launch_bounds__(256) void k_pack_bias(const float* __restrict__ bq,
                                                   const float* __restrict__ bk,
                                                   const float* __restrict__ bv,
                                                   float* __restrict__ o) {
  const int i = blockIdx.x * 256 + threadIdx.x;
  if (i < 3072)
    o[i] = i < 1024 ? bq[i] : (i < 2048 ? bk[i - 1024] : bv[i - 2048]);
}

// ---- LayerNorm (+residual add; optionally init out = x2 + b2) ----
__global__ __launch_bounds__(256) void k_ln(const float* __restrict__ x,
                                            const float* __restrict__ y,
                                            const float* __restrict__ g,
                                            const float* __restrict__ bb,
                                            __hip_bfloat16* __restrict__ o,
                                            const float* __restrict__ badd,
                                            float* __restrict__ oinit) {
  __shared__ float sb[4];
  const int t = threadIdx.x;
  const size_t base = (size_t)blockIdx.x * 1024 + t * 4;
  const int c = t * 4;
  float4 xv = *(const float4*)(x + base);
  if (y) {
    float4 yv = *(const float4*)(y + base);
    xv.x += yv.x; xv.y += yv.y; xv.z += yv.z; xv.w += yv.w;
    float4 ov;
    ov.x = xv.x + badd[c + 0]; ov.y = xv.y + badd[c + 1];
    ov.z = xv.z + badd[c + 2]; ov.w = xv.w + badd[c + 3];
    *(float4*)(oinit + base) = ov;
  }
  const float mu = block_sum(xv.x + xv.y + xv.z + xv.w, sb) * (1.f / 1024.f);
  const float dx = xv.x - mu, dy = xv.y - mu, dz = xv.z - mu, dw = xv.w - mu;
  const float var = block_sum(dx * dx + dy * dy + dz * dz + dw * dw, sb) * (1.f / 1024.f);
  const float rs = rsqrtf(var + 1e-5f);
  o[base + 0] = __float2bfloat16(dx * rs * g[c + 0] + bb[c + 0]);
  o[base + 1] = __float2bfloat16(dy * rs * g[c + 1] + bb[c + 1]);
  o[base + 2] = __float2bfloat16(dz * rs * g[c + 2] + bb[c + 2]);
  o[base + 3] = __float2bfloat16(dw * rs * g[c + 3] + bb[c + 3]);
}

// ---- QKV GEMM: h1[4096,1024] @ Wqkv_t[3072,1024]^T -> Q/K [hb][t][d], Vt [hb][d][t]
// Q is PRE-SCALED by 0.125*log2e so attention logits are base-2.
__global__ __launch_bounds__(256) void k_gemm_qkv(
    const __hip_bfloat16* __restrict__ h1, const __hip_bfloat16* __restrict__ Wt,
    const float* __restrict__ bqkv, __hip_bfloat16* __restrict__ Q,
    __hip_bfloat16* __restrict__ K, __hip_bfloat16* __restrict__ Vt) {
  __shared__ alignas(16) short smem[16896];   // la(8192) lb(8192) | lc(16896)
  short* la = smem;
  short* lb = smem + 8192;
  short* lc = smem;
  const int row0 = blockIdx.x * 128, col0 = blockIdx.y * 128;
  f32x4 acc[4][4] = {};
  gemm_core64<128, 128, 64, 64>(h1, 1024, Wt, 1024, 1024, row0, col0, acc, la, lb);
  const int tid = threadIdx.x, lane = tid & 63, wave = tid >> 6;
  const int wm = (wave >> 1) * 64, wn = (wave & 1) * 64, lr = lane & 15, lq = lane >> 4;
  const int which = col0 >> 10;                 // uniform: 0=Q 1=K 2=V
  const int h0 = (col0 & 1023) >> 6;
  const int b = row0 >> 10, t0 = row0 & 1023;
  if (which < 2) {
    const float qs = (which == 0) ? LOG2E_SCALE : 1.f;
    #pragma unroll
    for (int mi = 0; mi < 4; mi++)
      #pragma unroll
      for (int ni = 0; ni < 4; ni++)
        #pragma unroll
        for (int r = 0; r < 4; r++) {
          const int row = wm + mi * 16 + lq * 4 + r;
          const int col = wn + ni * 16 + lr;
          lc[row * 132 + col] = f2bf_s((acc[mi][ni][r] + bqkv[col0 + col]) * qs);
        }
    __syncthreads();
    __hip_bfloat16* O = which == 0 ? Q : K;
    #pragma unroll
    for (int c = 0; c < 8; c++) {
      const int f = tid + 256 * c;              // flat 16B-chunk id
      const int r = f >> 4, cc = f & 15;
      const int col = cc * 8;
      const int head = h0 + (col >> 6), d = col & 63;
      float4 vv = *(const float4*)(lc + r * 132 + col);
      *(float4*)(O + (((size_t)(b * 16 + head)) << 16) + (t0 + r) * 64 + d) = vv;
    }
  } else {
    // transposed epilogue: lc[col][row]
    #pragma unroll
    for (int mi = 0; mi < 4; mi++)
      #pragma unroll
      for (int ni = 0; ni < 4; ni++)
        #pragma unroll
        for (int r = 0; r < 4; r++) {
          const int row = wm + mi * 16 + lq * 4 + r;
          const int col = wn + ni * 16 + lr;
          lc[col * 132 + row] = f2bf_s(acc[mi][ni][r] + bqkv[col0 + col]);
        }
    __syncthreads();
    #pragma unroll
    for (int c = 0; c < 8; c++) {
      const int f = tid + 256 * c;
      const int dl = f >> 4, tc = f & 15;       // local d 0..127, t-chunk
      const int head = h0 + (dl >> 6), d = dl & 63;
      float4 vv = *(const float4*)(lc + dl * 132 + tc * 8);
      *(float4*)(Vt + (((size_t)(b * 16 + head)) << 16) + (size_t)d * 1024 +
                 t0 + tc * 8) = vv;
    }
  }
}

// ---- tail V sums: TV[hb][qt][d] = sum_{t >= (qt+1)*128} Vt[hb][d][t] ----
__global__ __launch_bounds__(256) void k_tailv(const __hip_bfloat16* __restrict__ Vt,
                                               float* __restrict__ TV) {
  __shared__ float ts[8][64];
  const int hb = blockIdx.x, tid = threadIdx.x;
  const __hip_bfloat16* Vh = Vt + ((size_t)hb << 16);
  for (int w = tid; w < 512; w += 256) {
    const int kt = w >> 6, d = w & 63;
    const short* p = (const short*)(Vh + (size_t)d * 1024 + kt * 128);
    float s = 0.f;
    for (int j = 0; j < 128; j += 8) {
      bf16x8 v = *(const bf16x8*)(p + j);
      #pragma unroll
      for (int e = 0; e < 8; e++) s += bf2f(v[e]);
    }
    ts[kt][d] = s;
  }
  __syncthreads();
  for (int w = tid; w < 512; w += 256) {
    const int qt = w >> 6, d = w & 63;
    float s = 0.f;
    for (int kt = qt + 1; kt < 8; kt++) s += ts[kt][d];
    TV[((size_t)hb * 8 + qt) * 64 + d] = s;
  }
}

// ---- fused attention: one block = (64 q-rows, one head); 1024 blocks ----
__global__ __launch_bounds__(256, 4) void k_attn(
    const __hip_bfloat16* __restrict__ Q, const __hip_bfloat16* __restrict__ K,
    const __hip_bfloat16* __restrict__ Vt, const float* __restrict__ TV,
    float* __restrict__ y) {
  __shared__ short lp[64 * 130];   // P-tile (padded)
  __shared__ short lkv[128 * 64];  // K-tile then V^T-tile, swizzled
  const int hb = blockIdx.y;
  const int j = (blockIdx.y & 32) ? (15 - (int)blockIdx.x) : (int)blockIdx.x;
  const int q0 = j * 64;
  const int nkt = (j >> 1) + 1;    // K-tiles (128 wide) to compute
  const int tid = threadIdx.x, lane = tid & 63, wave = tid >> 6;
  const int lr = lane & 15, lq = lane >> 4;
  const int wm = wave * 16;        // wave owns q-rows [q0+wm, q0+wm+16)
  const __hip_bfloat16* Qh = Q + ((size_t)hb << 16);
  const __hip_bfloat16* Kh = K + ((size_t)hb << 16);
  const __hip_bfloat16* Vh = Vt + ((size_t)hb << 16);

  // Q A-frags: direct global loads (rows q0+wm+lr, cols s*32+lq*8)
  bf16x8 qf[2];
  #pragma unroll
  for (int s = 0; s < 2; s++)
    qf[s] = *(const bf16x8*)((const short*)Qh +
                             (size_t)(q0 + wm + lr) * 64 + s * 32 + lq * 8);

  f32x4 oacc[4] = {};
  float mrow[4], lrow[4];
  #pragma unroll
  for (int r = 0; r < 4; r++) { mrow[r] = -1e30f; lrow[r] = 0.f; }

  for (int kt = 0; kt < nkt; kt++) {
    const int k0 = kt * 128;
    __syncthreads();  // prev PV frag reads (lp, lkv) done
    for (int c = tid; c < 1024; c += 256)
      stage16(Kh + (size_t)(k0 + (c >> 3)) * 64 + (((c & 7) ^ ((c >> 3) & 7)) << 3),
              lkv + c * 8);
    __syncthreads();  // K visible
    f32x4 sacc[8] = {};
    #pragma unroll
    for (int s = 0; s < 2; s++) {
      bf16x8 bf[8];
      #pragma unroll
      for (int ni = 0; ni < 8; ni++) {
        const int n = ni * 16 + lr;
        bf[ni] = *(const bf16x8*)(lkv + n * 64 + (((s * 4 + lq) ^ (n & 7)) << 3));
      }
      #pragma unroll
      for (int ni = 0; ni < 8; ni++)
        sacc[ni] = __builtin_amdgcn_mfma_f32_16x16x32_bf16(
            qf[s], bf[ni], sacc[ni], 0, 0, 0);
    }
    __syncthreads();  // K frag reads done; lkv free for V
    // V^T tile DMA (overlaps softmax VALU below)
    for (int c = tid; c < 1024; c += 256)
      stage16(Vh + (size_t)(c >> 4) * 1024 + k0 + (((c & 15) ^ ((c >> 4) & 15)) << 3),
              lkv + c * 8);
    // online softmax, base-2 domain
    const bool last = (kt == nkt - 1);
    #pragma unroll
    for (int r = 0; r < 4; r++) {
      const int grow = q0 + wm + lq * 4 + r;   // global q row
      float tmax = -1e30f;
      #pragma unroll
      for (int ni = 0; ni < 8; ni++) {
        float v = sacc[ni][r];
        if (last && (k0 + ni * 16 + lr) > grow) v = MASK2;
        sacc[ni][r] = v;
        tmax = fmaxf(tmax, v);
      }
      #pragma unroll
      for (int msk = 8; msk; msk >>= 1) tmax = fmaxf(tmax, __shfl_xor(tmax, msk));
      const float mn = fmaxf(mrow[r], tmax);
      const float al = __builtin_amdgcn_exp2f(mrow[r] - mn);
      float rs = 0.f;
      #pragma unroll
      for (int ni = 0; ni < 8; ni++) {
        const float pv = __builtin_amdgcn_exp2f(sacc[ni][r] - mn);
        sacc[ni][r] = pv;
        rs += pv;
      }
      #pragma unroll
      for (int msk = 8; msk; msk >>= 1) rs += __shfl_xor(rs, msk);
      mrow[r] = mn;
      lrow[r] = lrow[r] * al + rs;
      #pragma unroll
      for (int ni = 0; ni < 4; ni++) oacc[ni][r] *= al;
    }
    // P -> lp (padded pitch 130)
    #pragma unroll
    for (int r = 0; r < 4; r++) {
      const int row = wm + lq * 4 + r;
      #pragma unroll
      for (int ni = 0; ni < 8; ni++)
        lp[row * 130 + ni * 16 + lr] = f2bf_s(sacc[ni][r]);
    }
    __syncthreads();  // V staged + P written
    #pragma unroll
    for (int ks = 0; ks < 4; ks++) {
      bf16x8 pa, vb[4];
      pa = *(const bf16x8*)(lp + (wm + lr) * 130 + ks * 32 + lq * 8);
      #pragma unroll
      for (int ni = 0; ni < 4; ni++) {
        const int d = ni * 16 + lr;
        vb[ni] = *(const bf16x8*)(lkv + d * 128 + (((ks * 4 + lq) ^ (d & 15)) << 3));
      }
      #pragma unroll
      for (int ni = 0; ni < 4; ni++)
        oacc[ni] = __builtin_amdgcn_mfma_f32_16x16x32_bf16(
            pa, vb[ni], oacc[ni], 0, 0, 0);
    }
  }

  const int b = hb >> 4, h = hb & 15;
  const float cv = (float)(1024 - nkt * 128);
  const float* tv = TV + ((size_t)hb * 8 + (j >> 1)) * 64;
  #pragma unroll
  for (int r = 0; r < 4; r++) {
    const int t = q0 + wm + lq * 4 + r;
    const float tail = __builtin_amdgcn_exp2f(MASK2 - mrow[r]);
    const float inv = 1.f / (lrow[r] + cv * tail);
    #pragma unroll
    for (int ni = 0; ni < 4; ni++) {
      const int d = ni * 16 + lr;
      y[((size_t)(b * 1024 + t) << 10) + h * 64 + d] =
          (oacc[ni][r] + tail * tv[d]) * inv;
    }
  }
}

// ---- MLP1: h2 @ W1t^T + b1 -> exact gelu -> G bf16 [4096,4096] ----
// 128x128 tile, grid(32,32): 1024 blocks, AI=64 FLOP/B (qkv/m103 config).
__global__ __launch_bounds__(256) void k_gemm_mlp1(const __hip_bfloat16* __restrict__ h2,
                                                   const __hip_bfloat16* __restrict__ W1t,
                                                   const float* __restrict__ b1,
                                                   __hip_bfloat16* __restrict__ G) {
  __shared__ alignas(16) short smem[16896];   // la(8192)+lb(8192) | lc(128*132)
  short* la = smem;
  short* lb = smem + 8192;
  short* lc = smem;
  const int row0 = blockIdx.x * 128, col0 = blockIdx.y * 128;
  f32x4 acc[4][4] = {};
  gemm_core64<128, 128, 64, 64>(h2, 1024, W1t, 1024, 1024, row0, col0, acc, la, lb);
  const int tid = threadIdx.x, lane = tid & 63, wave = tid >> 6;
  const int wm = (wave >> 1) * 64, wn = (wave & 1) * 64, lr = lane & 15, lq = lane >> 4;
  #pragma unroll
  for (int mi = 0; mi < 4; mi++)
    #pragma unroll
    for (int ni = 0; ni < 4; ni++)
      #pragma unroll
      for (int r = 0; r < 4; r++) {
        const int row = wm + mi * 16 + lq * 4 + r;
        const int col = wn + ni * 16 + lr;
        float v = acc[mi][ni][r] + b1[col0 + col];
        v = 0.5f * v * (1.f + erff(v * 0.70710678118654752f));
        lc[row * 132 + col] = f2bf_s(v);
      }
  __syncthreads();
  #pragma unroll
  for (int c = 0; c < 8; c++) {                 // 2048 chunks of 16B (128x128 tile)
    const int f = tid + 256 * c;
    const int r = f >> 4, cc = f & 15;
    float4 vv = *(const float4*)(lc + r * 132 + cc * 8);
    *(float4*)(G + ((size_t)(row0 + r) << 12) + col0 + cc * 8) = vv;
  }
}

// ---- MLP2 split-K=4: out += G @ W2t^T (out pre-initialized with b2 + x2) ----
// 128x128 tile, grid(32,8,4): 1024 blocks = 4/CU, AI=64 FLOP/B, LDS 32KB.
__global__ __launch_bounds__(256) void k_gemm_mlp2(const __hip_bfloat16* __restrict__ G,
                                                   const __hip_bfloat16* __restrict__ W2t,
                                                   float* __restrict__ out) {
  __shared__ alignas(16) short smem[16384];
  short* la = smem;
  short* lb = smem + 8192;
  const int row0 = blockIdx.x * 128, col0 = blockIdx.y * 128;
  const int kOff = blockIdx.z * 1024;
  f32x4 acc[4][4] = {};
  gemm_core64<128, 128, 64, 64>(G + kOff, 4096, W2t + kOff, 4096, 1024,
                                row0, col0, acc, la, lb);
  const int lane = threadIdx.x & 63, wave = threadIdx.x >> 6;
  const int wm = (wave >> 1) * 64, wn = (wave & 1) * 64, lr = lane & 15, lq = lane >> 4;
  #pragma unroll
  for (int mi = 0; mi < 4; mi++)
    #pragma unroll
    for (int ni = 0; ni < 4; ni++)
      #pragma unroll
      for (int r = 0; r < 4; r++) {
        const int grow = row0 + wm + mi * 16 + lq * 4 + r;
        const int gcol = col0 + wn + ni * 16 + lr;
        atomicAdd(out + (((size_t)grow << 10) + gcol), acc[mi][ni][r]);
      }
}

extern "C" void kernel_launch(void* const* d_in, const int* in_sizes, int n_in,
                              void* d_out, int out_size, void* d_ws, size_t ws_size,
                              hipStream_t stream) {
  const float* x     = (const float*)d_in[0];
  const float* ln1_g = (const float*)d_in[1];
  const float* ln1_b = (const float*)d_in[2];
  const float* ln2_g = (const float*)d_in[3];
  const float* ln2_b = (const float*)d_in[4];
  const float* Wq    = (const float*)d_in[5];
  const float* bq    = (const float*)d_in[6];
  const float* Wk    = (const float*)d_in[7];
  const float* bk    = (const float*)d_in[8];
  const float* Wv    = (const float*)d_in[9];
  const float* bv    = (const float*)d_in[10];
  const float* W1    = (const float*)d_in[11];
  const float* b1    = (const float*)d_in[12];
  const float* W2    = (const float*)d_in[13];
  const float* b2    = (const float*)d_in[14];
  float* out = (float*)d_out;

  char* p = (char*)d_ws;
  auto alloc = [&](size_t bytes) { char* r = p; p += (bytes + 255) & ~(size_t)255; return r; };
  __hip_bfloat16* wqkv = (__hip_bfloat16*)alloc(3072 * 1024 * 2);
  __hip_bfloat16* w1t  = (__hip_bfloat16*)alloc(4096 * 1024 * 2);
  __hip_bfloat16* w2t  = (__hip_bfloat16*)alloc(1024 * 4096 * 2);
  float*          bqkv = (float*)alloc(3072 * 4);
  __hip_bfloat16* h1   = (__hip_bfloat16*)alloc(4096 * 1024 * 2);
  __hip_bfloat16* Qb   = (__hip_bfloat16*)alloc((size_t)64 * 65536 * 2);  // [64][1024][64]
  __hip_bfloat16* Kb   = (__hip_bfloat16*)alloc((size_t)64 * 65536 * 2);
  __hip_bfloat16* Vt   = (__hip_bfloat16*)alloc((size_t)64 * 65536 * 2);  // [64][64][1024]
  float*          TV   = (float*)alloc((size_t)64 * 8 * 64 * 4);
  float*          yb   = (float*)alloc((size_t)4096 * 1024 * 4);
  __hip_bfloat16* h2   = (__hip_bfloat16*)alloc(4096 * 1024 * 2);
  __hip_bfloat16* G    = (__hip_bfloat16*)alloc((size_t)4096 * 4096 * 2);
  (void)ws_size; (void)in_sizes; (void)n_in; (void)out_size;

  const dim3 b256(256), bt(32, 8);
  k_tcvt3<<<dim3(32, 32, 3), bt, 0, stream>>>(Wq, Wk, Wv, wqkv);
  k_tcvt<<<dim3(128, 32), bt, 0, stream>>>(W1, w1t, 1024, 4096, 0, 1024);
  k_tcvt<<<dim3(32, 128), bt, 0, stream>>>(W2, w2t, 4096, 1024, 0, 4096);
  k_pack_bias<<<12, b256, 0, stream>>>(bq, bk, bv, bqkv);

  k_ln<<<4096, b256, 0, stream>>>(x, nullptr, ln1_g, ln1_b, h1, nullptr, nullptr);
  k_gemm_qkv<<<dim3(32, 24), b256, 0, stream>>>(h1, wqkv, bqkv, Qb, Kb, Vt);
  k_tailv<<<64, b256, 0, stream>>>(Vt, TV);
  k_attn<<<dim3(16, 64), b256, 0, stream>>>(Qb, Kb, Vt, TV, yb);

  k_ln<<<4096, b256, 0, stream>>>(x, yb, ln2_g, ln2_b, h2, b2, out);
  k_gemm_mlp1<<<dim3(32, 32), b256, 0, stream>>>(h2, w1t, b1, G);
  k_gemm_mlp2<<<dim3(32, 8, 4), b256, 0, stream>>>(G, w2t, out);
}

// Round 3
// 336.880 us; speedup vs baseline: 1.0707x; 1.0707x over previous
//
#include <hip/hip_runtime.h>
#include <hip/hip_bf16.h>
#include <math.h>

// Transformer block (pre-LN attn + MLP), B=4 T=1024 H=1024 K=16 HD=64.
// GEMMs: bf16 MFMA 16x16x32, global_load_lds width=16 staging, BK=64 with
// xor-swizzled LDS chunk placement (0 bank conflicts, verified R8).
// R13: mlp2 REVERTED to the measured-best R10 config (128x64, split-K=2,
// grid(32,16,2)=1024 blocks, 60.3us). Session data R10-R12 shows every
// m97-family variant of mlp2 lands 60-76us with atomic count the only
// predictive counter -- structure is at its local optimum.
// k_attn restructured: separate lK/lV LDS buffers (49KB, 3 blocks/CU),
// 2 barriers/kt instead of 3, K(kt+1) DMA issued alongside V(kt) so the
// K load hides under softmax+PV; s_setprio(1) around MFMA clusters
// (m191: +4-7% attn A/B-verified).
// Attention math: flash-style, 64-row Q-tiles, exp2-domain softmax (scale
// folded into Q); masked logits FILLED with 1e-9; fully-masked K-tiles
// contribute exp(1e-9-m)*suffixV analytically (TV precomputed).

typedef __attribute__((ext_vector_type(8))) short bf16x8;
typedef __attribute__((ext_vector_type(4))) float f32x4;

#define DEVINL __device__ __forceinline__

#define LOG2E_SCALE 0.18033688f      /* 0.125 * log2(e) */
#define MASK2 1.4426950408889634e-9f /* 1e-9 * log2(e) */

DEVINL void stage16(const __hip_bfloat16* g, short* l) {
  __builtin_amdgcn_global_load_lds(
      (const __attribute__((address_space(1))) unsigned int*)g,
      (__attribute__((address_space(3))) unsigned int*)l, 16, 0, 0);
}

DEVINL float bf2f(short u) {
  unsigned x = ((unsigned)(unsigned short)u) << 16;
  float f; __builtin_memcpy(&f, &x, 4); return f;
}

DEVINL short f2bf_s(float f) {
  __hip_bfloat16 h = __float2bfloat16(f);
  short s; __builtin_memcpy(&s, &h, 2); return s;
}

DEVINL float block_sum(float v, float* sb) {
  #pragma unroll
  for (int o = 32; o; o >>= 1) v += __shfl_down(v, o);
  const int lane = threadIdx.x & 63, w = threadIdx.x >> 6;
  if (lane == 0) sb[w] = v;
  __syncthreads();
  float r = sb[0] + sb[1] + sb[2] + sb[3];
  __syncthreads();
  return r;
}

// ---- GEMM core BK=64: C[M,N] += A[M,Kd] * Bt[N,Kd]^T, 256 threads ----
template<int BM, int BN, int WM, int WN>
DEVINL void gemm_core64(const __hip_bfloat16* __restrict__ A, int lda,
                        const __hip_bfloat16* __restrict__ Bt, int ldb,
                        int Kd, int row0, int col0,
                        f32x4 (&acc)[WM/16][WN/16],
                        short* lds_a, short* lds_b) {
  constexpr int MI = WM / 16, NI = WN / 16, WNC = BN / WN;
  constexpr int CA = BM * 8, CB = BN * 8;  // 16B chunks per tile
  const int tid = threadIdx.x;
  const int lane = tid & 63, wave = tid >> 6;
  const int wm = (wave / WNC) * WM, wn = (wave % WNC) * WN;
  const int lr = lane & 15, lq = lane >> 4;
  for (int k0 = 0; k0 < Kd; k0 += 64) {
    #pragma unroll
    for (int c = tid; c < CA; c += 256) {
      const int r = c >> 3, kc = ((c & 7) ^ (r & 7)) << 3;
      stage16(A + (size_t)(row0 + r) * lda + k0 + kc, lds_a + c * 8);
    }
    #pragma unroll
    for (int c = tid; c < CB; c += 256) {
      const int r = c >> 3, kc = ((c & 7) ^ (r & 7)) << 3;
      stage16(Bt + (size_t)(col0 + r) * ldb + k0 + kc, lds_b + c * 8);
    }
    __syncthreads();
    #pragma unroll
    for (int s = 0; s < 2; s++) {
      bf16x8 af[MI], bfr[NI];
      #pragma unroll
      for (int mi = 0; mi < MI; mi++) {
        const int m = wm + mi * 16 + lr;
        af[mi] = *(const bf16x8*)(lds_a + m * 64 + (((s * 4 + lq) ^ (m & 7)) << 3));
      }
      #pragma unroll
      for (int ni = 0; ni < NI; ni++) {
        const int n = wn + ni * 16 + lr;
        bfr[ni] = *(const bf16x8*)(lds_b + n * 64 + (((s * 4 + lq) ^ (n & 7)) << 3));
      }
      #pragma unroll
      for (int mi = 0; mi < MI; mi++)
        #pragma unroll
        for (int ni = 0; ni < NI; ni++)
          acc[mi][ni] = __builtin_amdgcn_mfma_f32_16x16x32_bf16(
              af[mi], bfr[ni], acc[mi][ni], 0, 0, 0);
    }
    __syncthreads();
  }
}

// ---- transpose + f32->bf16: src[R][C] -> dst[(c+off)][r], dst pitch P ----
__global__ __launch_bounds__(256) void k_tcvt(const float* __restrict__ src,
                                              __hip_bfloat16* __restrict__ dst,
                                              int R, int C, int dstOff, int dstPitch) {
  __shared__ float tile[32][33];
  const int c0 = blockIdx.x * 32, r0 = blockIdx.y * 32;
  const int tx = threadIdx.x, ty = threadIdx.y;  // (32,8)
  #pragma unroll
  for (int i = 0; i < 32; i += 8)
    tile[ty + i][tx] = src[(size_t)(r0 + ty + i) * C + c0 + tx];
  __syncthreads();
  #pragma unroll
  for (int i = 0; i < 32; i += 8)
    dst[(size_t)(c0 + ty + i + dstOff) * dstPitch + r0 + tx] =
        __float2bfloat16(tile[tx][ty + i]);
}

// fused Wq/Wk/Wv transpose (z picks source; all 1024x1024, dst pitch 1024)
__global__ __launch_bounds__(256) void k_tcvt3(const float* __restrict__ Wq,
                                               const float* __restrict__ Wk,
                                               const float* __restrict__ Wv,
                                               __hip_bfloat16* __restrict__ dst) {
  __shared__ float tile[32][33];
  const float* src = blockIdx.z == 0 ? Wq : (blockIdx.z == 1 ? Wk : Wv);
  const int dstOff = blockIdx.z << 10;
  const int c0 = blockIdx.x * 32, r0 = blockIdx.y * 32;
  const int tx = threadIdx.x, ty = threadIdx.y;
  #pragma unroll
  for (int i = 0; i < 32; i += 8)
    tile[ty + i][tx] = src[(size_t)(r0 + ty + i) * 1024 + c0 + tx];
  __syncthreads();
  #pragma unroll
  for (int i = 0; i < 32; i += 8)
    dst[(size_t)(c0 + ty + i + dstOff) * 1024 + r0 + tx] =
        __float2bfloat16(tile[tx][ty + i]);
}

__global__ __launch_bounds__(256) void k_pack_bias(const float* __restrict__ bq,
                                                   const float* __restrict__ bk,
                                                   const float* __restrict__ bv,
                                                   float* __restrict__ o) {
  const int i = blockIdx.x * 256 + threadIdx.x;
  if (i < 3072)
    o[i] = i < 1024 ? bq[i] : (i < 2048 ? bk[i - 1024] : bv[i - 2048]);
}

// ---- LayerNorm (+residual add; optionally init out = x2 + b2) ----
__global__ __launch_bounds__(256) void k_ln(const float* __restrict__ x,
                                            const float* __restrict__ y,
                                            const float* __restrict__ g,
                                            const float* __restrict__ bb,
                                            __hip_bfloat16* __restrict__ o,
                                            const float* __restrict__ badd,
                                            float* __restrict__ oinit) {
  __shared__ float sb[4];
  const int t = threadIdx.x;
  const size_t base = (size_t)blockIdx.x * 1024 + t * 4;
  const int c = t * 4;
  float4 xv = *(const float4*)(x + base);
  if (y) {
    float4 yv = *(const float4*)(y + base);
    xv.x += yv.x; xv.y += yv.y; xv.z += yv.z; xv.w += yv.w;
    float4 ov;
    ov.x = xv.x + badd[c + 0]; ov.y = xv.y + badd[c + 1];
    ov.z = xv.z + badd[c + 2]; ov.w = xv.w + badd[c + 3];
    *(float4*)(oinit + base) = ov;
  }
  const float mu = block_sum(xv.x + xv.y + xv.z + xv.w, sb) * (1.f / 1024.f);
  const float dx = xv.x - mu, dy = xv.y - mu, dz = xv.z - mu, dw = xv.w - mu;
  const float var = block_sum(dx * dx + dy * dy + dz * dz + dw * dw, sb) * (1.f / 1024.f);
  const float rs = rsqrtf(var + 1e-5f);
  o[base + 0] = __float2bfloat16(dx * rs * g[c + 0] + bb[c + 0]);
  o[base + 1] = __float2bfloat16(dy * rs * g[c + 1] + bb[c + 1]);
  o[base + 2] = __float2bfloat16(dz * rs * g[c + 2] + bb[c + 2]);
  o[base + 3] = __float2bfloat16(dw * rs * g[c + 3] + bb[c + 3]);
}

// ---- QKV GEMM: h1[4096,1024] @ Wqkv_t[3072,1024]^T -> Q/K [hb][t][d], Vt [hb][d][t]
// Q is PRE-SCALED by 0.125*log2e so attention logits are base-2.
__global__ __launch_bounds__(256) void k_gemm_qkv(
    const __hip_bfloat16* __restrict__ h1, const __hip_bfloat16* __restrict__ Wt,
    const float* __restrict__ bqkv, __hip_bfloat16* __restrict__ Q,
    __hip_bfloat16* __restrict__ K, __hip_bfloat16* __restrict__ Vt) {
  __shared__ alignas(16) short smem[16896];   // la(8192) lb(8192) | lc(16896)
  short* la = smem;
  short* lb = smem + 8192;
  short* lc = smem;
  const int row0 = blockIdx.x * 128, col0 = blockIdx.y * 128;
  f32x4 acc[4][4] = {};
  gemm_core64<128, 128, 64, 64>(h1, 1024, Wt, 1024, 1024, row0, col0, acc, la, lb);
  const int tid = threadIdx.x, lane = tid & 63, wave = tid >> 6;
  const int wm = (wave >> 1) * 64, wn = (wave & 1) * 64, lr = lane & 15, lq = lane >> 4;
  const int which = col0 >> 10;                 // uniform: 0=Q 1=K 2=V
  const int h0 = (col0 & 1023) >> 6;
  const int b = row0 >> 10, t0 = row0 & 1023;
  if (which < 2) {
    const float qs = (which == 0) ? LOG2E_SCALE : 1.f;
    #pragma unroll
    for (int mi = 0; mi < 4; mi++)
      #pragma unroll
      for (int ni = 0; ni < 4; ni++)
        #pragma unroll
        for (int r = 0; r < 4; r++) {
          const int row = wm + mi * 16 + lq * 4 + r;
          const int col = wn + ni * 16 + lr;
          lc[row * 132 + col] = f2bf_s((acc[mi][ni][r] + bqkv[col0 + col]) * qs);
        }
    __syncthreads();
    __hip_bfloat16* O = which == 0 ? Q : K;
    #pragma unroll
    for (int c = 0; c < 8; c++) {
      const int f = tid + 256 * c;              // flat 16B-chunk id
      const int r = f >> 4, cc = f & 15;
      const int col = cc * 8;
      const int head = h0 + (col >> 6), d = col & 63;
      float4 vv = *(const float4*)(lc + r * 132 + col);
      *(float4*)(O + (((size_t)(b * 16 + head)) << 16) + (t0 + r) * 64 + d) = vv;
    }
  } else {
    // transposed epilogue: lc[col][row]
    #pragma unroll
    for (int mi = 0; mi < 4; mi++)
      #pragma unroll
      for (int ni = 0; ni < 4; ni++)
        #pragma unroll
        for (int r = 0; r < 4; r++) {
          const int row = wm + mi * 16 + lq * 4 + r;
          const int col = wn + ni * 16 + lr;
          lc[col * 132 + row] = f2bf_s(acc[mi][ni][r] + bqkv[col0 + col]);
        }
    __syncthreads();
    #pragma unroll
    for (int c = 0; c < 8; c++) {
      const int f = tid + 256 * c;
      const int dl = f >> 4, tc = f & 15;       // local d 0..127, t-chunk
      const int head = h0 + (dl >> 6), d = dl & 63;
      float4 vv = *(const float4*)(lc + dl * 132 + tc * 8);
      *(float4*)(Vt + (((size_t)(b * 16 + head)) << 16) + (size_t)d * 1024 +
                 t0 + tc * 8) = vv;
    }
  }
}

// ---- tail V sums: TV[hb][qt][d] = sum_{t >= (qt+1)*128} Vt[hb][d][t] ----
__global__ __launch_bounds__(256) void k_tailv(const __hip_bfloat16* __restrict__ Vt,
                                               float* __restrict__ TV) {
  __shared__ float ts[8][64];
  const int hb = blockIdx.x, tid = threadIdx.x;
  const __hip_bfloat16* Vh = Vt + ((size_t)hb << 16);
  for (int w = tid; w < 512; w += 256) {
    const int kt = w >> 6, d = w & 63;
    const short* p = (const short*)(Vh + (size_t)d * 1024 + kt * 128);
    float s = 0.f;
    for (int j = 0; j < 128; j += 8) {
      bf16x8 v = *(const bf16x8*)(p + j);
      #pragma unroll
      for (int e = 0; e < 8; e++) s += bf2f(v[e]);
    }
    ts[kt][d] = s;
  }
  __syncthreads();
  for (int w = tid; w < 512; w += 256) {
    const int qt = w >> 6, d = w & 63;
    float s = 0.f;
    for (int kt = qt + 1; kt < 8; kt++) s += ts[kt][d];
    TV[((size_t)hb * 8 + qt) * 64 + d] = s;
  }
}

// ---- fused attention: one block = (64 q-rows, one head); 1024 blocks ----
// R13: separate lK/lV buffers; 2 barriers per kt; K(kt+1) prefetched
// alongside V(kt) so its latency hides under softmax+PV; setprio on MFMA.
__global__ __launch_bounds__(256, 3) void k_attn(
    const __hip_bfloat16* __restrict__ Q, const __hip_bfloat16* __restrict__ K,
    const __hip_bfloat16* __restrict__ Vt, const float* __restrict__ TV,
    float* __restrict__ y) {
  __shared__ short lp[64 * 130];   // P-tile (padded)
  __shared__ short lK[128 * 64];   // K-tile, swizzled
  __shared__ short lV[128 * 64];   // V^T-tile, swizzled
  const int hb = blockIdx.y;
  const int j = (blockIdx.y & 32) ? (15 - (int)blockIdx.x) : (int)blockIdx.x;
  const int q0 = j * 64;
  const int nkt = (j >> 1) + 1;    // K-tiles (128 wide) to compute
  const int tid = threadIdx.x, lane = tid & 63, wave = tid >> 6;
  const int lr = lane & 15, lq = lane >> 4;
  const int wm = wave * 16;        // wave owns q-rows [q0+wm, q0+wm+16)
  const __hip_bfloat16* Qh = Q + ((size_t)hb << 16);
  const __hip_bfloat16* Kh = K + ((size_t)hb << 16);
  const __hip_bfloat16* Vh = Vt + ((size_t)hb << 16);

  // Q A-frags: direct global loads (rows q0+wm+lr, cols s*32+lq*8)
  bf16x8 qf[2];
  #pragma unroll
  for (int s = 0; s < 2; s++)
    qf[s] = *(const bf16x8*)((const short*)Qh +
                             (size_t)(q0 + wm + lr) * 64 + s * 32 + lq * 8);

  f32x4 oacc[4] = {};
  float mrow[4], lrow[4];
  #pragma unroll
  for (int r = 0; r < 4; r++) { mrow[r] = -1e30f; lrow[r] = 0.f; }

  // prologue: stage K(0)
  for (int c = tid; c < 1024; c += 256)
    stage16(Kh + (size_t)(c >> 3) * 64 + (((c & 7) ^ ((c >> 3) & 7)) << 3),
            lK + c * 8);
  __syncthreads();  // K(0) visible

  for (int kt = 0; kt < nkt; kt++) {
    const int k0 = kt * 128;
    // ---- QK^T from lK ----
    f32x4 sacc[8] = {};
    __builtin_amdgcn_s_setprio(1);
    #pragma unroll
    for (int s = 0; s < 2; s++) {
      bf16x8 bf[8];
      #pragma unroll
      for (int ni = 0; ni < 8; ni++) {
        const int n = ni * 16 + lr;
        bf[ni] = *(const bf16x8*)(lK + n * 64 + (((s * 4 + lq) ^ (n & 7)) << 3));
      }
      #pragma unroll
      for (int ni = 0; ni < 8; ni++)
        sacc[ni] = __builtin_amdgcn_mfma_f32_16x16x32_bf16(
            qf[s], bf[ni], sacc[ni], 0, 0, 0);
    }
    __builtin_amdgcn_s_setprio(0);
    __syncthreads();  // barA: lK frag reads + prev PV's lp/lV reads done
    // ---- V(kt) + K(kt+1) DMA (latency hides under softmax below) ----
    for (int c = tid; c < 1024; c += 256)
      stage16(Vh + (size_t)(c >> 4) * 1024 + k0 + (((c & 15) ^ ((c >> 4) & 15)) << 3),
              lV + c * 8);
    if (kt + 1 < nkt) {
      const int k1 = k0 + 128;
      for (int c = tid; c < 1024; c += 256)
        stage16(Kh + (size_t)(k1 + (c >> 3)) * 64 + (((c & 7) ^ ((c >> 3) & 7)) << 3),
                lK + c * 8);
    }
    // ---- online softmax, base-2 domain ----
    const bool last = (kt == nkt - 1);
    #pragma unroll
    for (int r = 0; r < 4; r++) {
      const int grow = q0 + wm + lq * 4 + r;   // global q row
      float tmax = -1e30f;
      #pragma unroll
      for (int ni = 0; ni < 8; ni++) {
        float v = sacc[ni][r];
        if (last && (k0 + ni * 16 + lr) > grow) v = MASK2;
        sacc[ni][r] = v;
        tmax = fmaxf(tmax, v);
      }
      #pragma unroll
      for (int msk = 8; msk; msk >>= 1) tmax = fmaxf(tmax, __shfl_xor(tmax, msk));
      const float mn = fmaxf(mrow[r], tmax);
      const float al = __builtin_amdgcn_exp2f(mrow[r] - mn);
      float rs = 0.f;
      #pragma unroll
      for (int ni = 0; ni < 8; ni++) {
        const float pv = __builtin_amdgcn_exp2f(sacc[ni][r] - mn);
        sacc[ni][r] = pv;
        rs += pv;
      }
      #pragma unroll
      for (int msk = 8; msk; msk >>= 1) rs += __shfl_xor(rs, msk);
      mrow[r] = mn;
      lrow[r] = lrow[r] * al + rs;
      #pragma unroll
      for (int ni = 0; ni < 4; ni++) oacc[ni][r] *= al;
    }
    // P -> lp (padded pitch 130)
    #pragma unroll
    for (int r = 0; r < 4; r++) {
      const int row = wm + lq * 4 + r;
      #pragma unroll
      for (int ni = 0; ni < 8; ni++)
        lp[row * 130 + ni * 16 + lr] = f2bf_s(sacc[ni][r]);
    }
    __syncthreads();  // barB: V(kt)+K(kt+1) landed (vmcnt drain) + P visible
    // ---- PV from lp, lV ----
    __builtin_amdgcn_s_setprio(1);
    #pragma unroll
    for (int ks = 0; ks < 4; ks++) {
      bf16x8 pa, vb[4];
      pa = *(const bf16x8*)(lp + (wm + lr) * 130 + ks * 32 + lq * 8);
      #pragma unroll
      for (int ni = 0; ni < 4; ni++) {
        const int d = ni * 16 + lr;
        vb[ni] = *(const bf16x8*)(lV + d * 128 + (((ks * 4 + lq) ^ (d & 15)) << 3));
      }
      #pragma unroll
      for (int ni = 0; ni < 4; ni++)
        oacc[ni] = __builtin_amdgcn_mfma_f32_16x16x32_bf16(
            pa, vb[ni], oacc[ni], 0, 0, 0);
    }
    __builtin_amdgcn_s_setprio(0);
    // no barrier here: next QK reads lK (disjoint from lp/lV); barA covers reuse
  }

  const int b = hb >> 4, h = hb & 15;
  const float cv = (float)(1024 - nkt * 128);
  const float* tv = TV + ((size_t)hb * 8 + (j >> 1)) * 64;
  #pragma unroll
  for (int r = 0; r < 4; r++) {
    const int t = q0 + wm + lq * 4 + r;
    const float tail = __builtin_amdgcn_exp2f(MASK2 - mrow[r]);
    const float inv = 1.f / (lrow[r] + cv * tail);
    #pragma unroll
    for (int ni = 0; ni < 4; ni++) {
      const int d = ni * 16 + lr;
      y[((size_t)(b * 1024 + t) << 10) + h * 64 + d] =
          (oacc[ni][r] + tail * tv[d]) * inv;
    }
  }
}

// ---- MLP1: h2 @ W1t^T + b1 -> exact gelu -> G bf16 [4096,4096] ----
// 128x128 tile, grid(32,32): 1024 blocks, AI=64 FLOP/B (qkv/m103 config).
__global__ __launch_bounds__(256) void k_gemm_mlp1(const __hip_bfloat16* __restrict__ h2,
                                                   const __hip_bfloat16* __restrict__ W1t,
                                                   const float* __restrict__ b1,
                                                   __hip_bfloat16* __restrict__ G) {
  __shared__ alignas(16) short smem[16896];   // la(8192)+lb(8192) | lc(128*132)
  short* la = smem;
  short* lb = smem + 8192;
  short* lc = smem;
  const int row0 = blockIdx.x * 128, col0 = blockIdx.y * 128;
  f32x4 acc[4][4] = {};
  gemm_core64<128, 128, 64, 64>(h2, 1024, W1t, 1024, 1024, row0, col0, acc, la, lb);
  const int tid = threadIdx.x, lane = tid & 63, wave = tid >> 6;
  const int wm = (wave >> 1) * 64, wn = (wave & 1) * 64, lr = lane & 15, lq = lane >> 4;
  #pragma unroll
  for (int mi = 0; mi < 4; mi++)
    #pragma unroll
    for (int ni = 0; ni < 4; ni++)
      #pragma unroll
      for (int r = 0; r < 4; r++) {
        const int row = wm + mi * 16 + lq * 4 + r;
        const int col = wn + ni * 16 + lr;
        float v = acc[mi][ni][r] + b1[col0 + col];
        v = 0.5f * v * (1.f + erff(v * 0.70710678118654752f));
        lc[row * 132 + col] = f2bf_s(v);
      }
  __syncthreads();
  #pragma unroll
  for (int c = 0; c < 8; c++) {                 // 2048 chunks of 16B (128x128 tile)
    const int f = tid + 256 * c;
    const int r = f >> 4, cc = f & 15;
    float4 vv = *(const float4*)(lc + r * 132 + cc * 8);
    *(float4*)(G + ((size_t)(row0 + r) << 12) + col0 + cc * 8) = vv;
  }
}

// ---- MLP2 split-K=2: out += G @ W2t^T (out pre-initialized with b2 + x2) ----
// 128x64 tile, grid(32,16,2): 1024 blocks, LDS 24KB. (R10 measured-best.)
__global__ __launch_bounds__(256) void k_gemm_mlp2(const __hip_bfloat16* __restrict__ G,
                                                   const __hip_bfloat16* __restrict__ W2t,
                                                   float* __restrict__ out) {
  __shared__ alignas(16) short smem[12288];
  short* la = smem;
  short* lb = smem + 8192;
  const int row0 = blockIdx.x * 128, col0 = blockIdx.y * 64;
  const int kOff = blockIdx.z * 2048;
  f32x4 acc[4][2] = {};
  gemm_core64<128, 64, 64, 32>(G + kOff, 4096, W2t + kOff, 4096, 2048,
                               row0, col0, acc, la, lb);
  const int lane = threadIdx.x & 63, wave = threadIdx.x >> 6;
  const int wm = (wave >> 1) * 64, wn = (wave & 1) * 32, lr = lane & 15, lq = lane >> 4;
  #pragma unroll
  for (int mi = 0; mi < 4; mi++)
    #pragma unroll
    for (int ni = 0; ni < 2; ni++)
      #pragma unroll
      for (int r = 0; r < 4; r++) {
        const int grow = row0 + wm + mi * 16 + lq * 4 + r;
        const int gcol = col0 + wn + ni * 16 + lr;
        atomicAdd(out + (((size_t)grow << 10) + gcol), acc[mi][ni][r]);
      }
}

extern "C" void kernel_launch(void* const* d_in, const int* in_sizes, int n_in,
                              void* d_out, int out_size, void* d_ws, size_t ws_size,
                              hipStream_t stream) {
  const float* x     = (const float*)d_in[0];
  const float* ln1_g = (const float*)d_in[1];
  const float* ln1_b = (const float*)d_in[2];
  const float* ln2_g = (const float*)d_in[3];
  const float* ln2_b = (const float*)d_in[4];
  const float* Wq    = (const float*)d_in[5];
  const float* bq    = (const float*)d_in[6];
  const float* Wk    = (const float*)d_in[7];
  const float* bk    = (const float*)d_in[8];
  const float* Wv    = (const float*)d_in[9];
  const float* bv    = (const float*)d_in[10];
  const float* W1    = (const float*)d_in[11];
  const float* b1    = (const float*)d_in[12];
  const float* W2    = (const float*)d_in[13];
  const float* b2    = (const float*)d_in[14];
  float* out = (float*)d_out;

  char* p = (char*)d_ws;
  auto alloc = [&](size_t bytes) { char* r = p; p += (bytes + 255) & ~(size_t)255; return r; };
  __hip_bfloat16* wqkv = (__hip_bfloat16*)alloc(3072 * 1024 * 2);
  __hip_bfloat16* w1t  = (__hip_bfloat16*)alloc(4096 * 1024 * 2);
  __hip_bfloat16* w2t  = (__hip_bfloat16*)alloc(1024 * 4096 * 2);
  float*          bqkv = (float*)alloc(3072 * 4);
  __hip_bfloat16* h1   = (__hip_bfloat16*)alloc(4096 * 1024 * 2);
  __hip_bfloat16* Qb   = (__hip_bfloat16*)alloc((size_t)64 * 65536 * 2);  // [64][1024][64]
  __hip_bfloat16* Kb   = (__hip_bfloat16*)alloc((size_t)64 * 65536 * 2);
  __hip_bfloat16* Vt   = (__hip_bfloat16*)alloc((size_t)64 * 65536 * 2);  // [64][64][1024]
  float*          TV   = (float*)alloc((size_t)64 * 8 * 64 * 4);
  float*          yb   = (float*)alloc((size_t)4096 * 1024 * 4);
  __hip_bfloat16* h2   = (__hip_bfloat16*)alloc(4096 * 1024 * 2);
  __hip_bfloat16* G    = (__hip_bfloat16*)alloc((size_t)4096 * 4096 * 2);
  (void)ws_size; (void)in_sizes; (void)n_in; (void)out_size;

  const dim3 b256(256), bt(32, 8);
  k_tcvt3<<<dim3(32, 32, 3), bt, 0, stream>>>(Wq, Wk, Wv, wqkv);
  k_tcvt<<<dim3(128, 32), bt, 0, stream>>>(W1, w1t, 1024, 4096, 0, 1024);
  k_tcvt<<<dim3(32, 128), bt, 0, stream>>>(W2, w2t, 4096, 1024, 0, 4096);
  k_pack_bias<<<12, b256, 0, stream>>>(bq, bk, bv, bqkv);

  k_ln<<<4096, b256, 0, stream>>>(x, nullptr, ln1_g, ln1_b, h1, nullptr, nullptr);
  k_gemm_qkv<<<dim3(32, 24), b256, 0, stream>>>(h1, wqkv, bqkv, Qb, Kb, Vt);
  k_tailv<<<64, b256, 0, stream>>>(Vt, TV);
  k_attn<<<dim3(16, 64), b256, 0, stream>>>(Qb, Kb, Vt, TV, yb);

  k_ln<<<4096, b256, 0, stream>>>(x, yb, ln2_g, ln2_b, h2, b2, out);
  k_gemm_mlp1<<<dim3(32, 32), b256, 0, stream>>>(h2, w1t, b1, G);
  k_gemm_mlp2<<<dim3(32, 16, 2), b256, 0, stream>>>(G, w2t, out);
}

// Round 5
// 334.265 us; speedup vs baseline: 1.0791x; 1.0078x over previous
//
#include <hip/hip_runtime.h>
#include <hip/hip_bf16.h>
#include <math.h>

// Transformer block (pre-LN attn + MLP), B=4 T=1024 H=1024 K=16 HD=64.
// GEMMs: bf16 MFMA 16x16x32, global_load_lds width=16 staging, BK=64 with
// xor-swizzled LDS chunk placement (0 bank conflicts, verified R8).
// R15 == R14 resubmit (R14 hit an infra failure, never ran):
// mlp1's exact-erf GELU epilogue replaced with tanh-form GELU in exp2
// domain: gelu(v) = v*e/(e+1), e = exp2(v*(2.3022079 + 0.1029434*v^2)).
// R13 counters showed mlp1 = 96us with VALUBusy(23%) > MfmaUtil(14%):
// 64x erff/thread (~35-40 branchy VALU ops each, ~4000 cyc/wave) exceeded
// the entire MFMA main loop (~2560 cyc/wave). tanh-GELU is ~8 branch-free
// ops (HW exp2 + rcp); approx error ~3e-4 << bf16 quantization of G.
// mlp2: R10 measured-best config (128x64, split-K=2, 1024 blocks, ~60us).
// Attention: fused flash-style, 64-row Q-tiles, separate lK/lV, 2 barriers
// per kt, K(kt+1) prefetch hidden under softmax, setprio on MFMA clusters;
// masked logits FILLED with 1e-9; fully-masked K-tiles contribute
// exp(1e-9-m)*suffixV analytically (TV precomputed).

typedef __attribute__((ext_vector_type(8))) short bf16x8;
typedef __attribute__((ext_vector_type(4))) float f32x4;

#define DEVINL __device__ __forceinline__

#define LOG2E_SCALE 0.18033688f      /* 0.125 * log2(e) */
#define MASK2 1.4426950408889634e-9f /* 1e-9 * log2(e) */

DEVINL void stage16(const __hip_bfloat16* g, short* l) {
  __builtin_amdgcn_global_load_lds(
      (const __attribute__((address_space(1))) unsigned int*)g,
      (__attribute__((address_space(3))) unsigned int*)l, 16, 0, 0);
}

DEVINL float bf2f(short u) {
  unsigned x = ((unsigned)(unsigned short)u) << 16;
  float f; __builtin_memcpy(&f, &x, 4); return f;
}

DEVINL short f2bf_s(float f) {
  __hip_bfloat16 h = __float2bfloat16(f);
  short s; __builtin_memcpy(&s, &h, 2); return s;
}

DEVINL float block_sum(float v, float* sb) {
  #pragma unroll
  for (int o = 32; o; o >>= 1) v += __shfl_down(v, o);
  const int lane = threadIdx.x & 63, w = threadIdx.x >> 6;
  if (lane == 0) sb[w] = v;
  __syncthreads();
  float r = sb[0] + sb[1] + sb[2] + sb[3];
  __syncthreads();
  return r;
}

// ---- GEMM core BK=64: C[M,N] += A[M,Kd] * Bt[N,Kd]^T, 256 threads ----
template<int BM, int BN, int WM, int WN>
DEVINL void gemm_core64(const __hip_bfloat16* __restrict__ A, int lda,
                        const __hip_bfloat16* __restrict__ Bt, int ldb,
                        int Kd, int row0, int col0,
                        f32x4 (&acc)[WM/16][WN/16],
                        short* lds_a, short* lds_b) {
  constexpr int MI = WM / 16, NI = WN / 16, WNC = BN / WN;
  constexpr int CA = BM * 8, CB = BN * 8;  // 16B chunks per tile
  const int tid = threadIdx.x;
  const int lane = tid & 63, wave = tid >> 6;
  const int wm = (wave / WNC) * WM, wn = (wave % WNC) * WN;
  const int lr = lane & 15, lq = lane >> 4;
  for (int k0 = 0; k0 < Kd; k0 += 64) {
    #pragma unroll
    for (int c = tid; c < CA; c += 256) {
      const int r = c >> 3, kc = ((c & 7) ^ (r & 7)) << 3;
      stage16(A + (size_t)(row0 + r) * lda + k0 + kc, lds_a + c * 8);
    }
    #pragma unroll
    for (int c = tid; c < CB; c += 256) {
      const int r = c >> 3, kc = ((c & 7) ^ (r & 7)) << 3;
      stage16(Bt + (size_t)(col0 + r) * ldb + k0 + kc, lds_b + c * 8);
    }
    __syncthreads();
    #pragma unroll
    for (int s = 0; s < 2; s++) {
      bf16x8 af[MI], bfr[NI];
      #pragma unroll
      for (int mi = 0; mi < MI; mi++) {
        const int m = wm + mi * 16 + lr;
        af[mi] = *(const bf16x8*)(lds_a + m * 64 + (((s * 4 + lq) ^ (m & 7)) << 3));
      }
      #pragma unroll
      for (int ni = 0; ni < NI; ni++) {
        const int n = wn + ni * 16 + lr;
        bfr[ni] = *(const bf16x8*)(lds_b + n * 64 + (((s * 4 + lq) ^ (n & 7)) << 3));
      }
      #pragma unroll
      for (int mi = 0; mi < MI; mi++)
        #pragma unroll
        for (int ni = 0; ni < NI; ni++)
          acc[mi][ni] = __builtin_amdgcn_mfma_f32_16x16x32_bf16(
              af[mi], bfr[ni], acc[mi][ni], 0, 0, 0);
    }
    __syncthreads();
  }
}

// ---- transpose + f32->bf16: src[R][C] -> dst[(c+off)][r], dst pitch P ----
__global__ __launch_bounds__(256) void k_tcvt(const float* __restrict__ src,
                                              __hip_bfloat16* __restrict__ dst,
                                              int R, int C, int dstOff, int dstPitch) {
  __shared__ float tile[32][33];
  const int c0 = blockIdx.x * 32, r0 = blockIdx.y * 32;
  const int tx = threadIdx.x, ty = threadIdx.y;  // (32,8)
  #pragma unroll
  for (int i = 0; i < 32; i += 8)
    tile[ty + i][tx] = src[(size_t)(r0 + ty + i) * C + c0 + tx];
  __syncthreads();
  #pragma unroll
  for (int i = 0; i < 32; i += 8)
    dst[(size_t)(c0 + ty + i + dstOff) * dstPitch + r0 + tx] =
        __float2bfloat16(tile[tx][ty + i]);
}

// fused Wq/Wk/Wv transpose (z picks source; all 1024x1024, dst pitch 1024)
__global__ __launch_bounds__(256) void k_tcvt3(const float* __restrict__ Wq,
                                               const float* __restrict__ Wk,
                                               const float* __restrict__ Wv,
                                               __hip_bfloat16* __restrict__ dst) {
  __shared__ float tile[32][33];
  const float* src = blockIdx.z == 0 ? Wq : (blockIdx.z == 1 ? Wk : Wv);
  const int dstOff = blockIdx.z << 10;
  const int c0 = blockIdx.x * 32, r0 = blockIdx.y * 32;
  const int tx = threadIdx.x, ty = threadIdx.y;
  #pragma unroll
  for (int i = 0; i < 32; i += 8)
    tile[ty + i][tx] = src[(size_t)(r0 + ty + i) * 1024 + c0 + tx];
  __syncthreads();
  #pragma unroll
  for (int i = 0; i < 32; i += 8)
    dst[(size_t)(c0 + ty + i + dstOff) * 1024 + r0 + tx] =
        __float2bfloat16(tile[tx][ty + i]);
}

__global__ __launch_bounds__(256) void k_pack_bias(const float* __restrict__ bq,
                                                   const float* __restrict__ bk,
                                                   const float* __restrict__ bv,
                                                   float* __restrict__ o) {
  const int i = blockIdx.x * 256 + threadIdx.x;
  if (i < 3072)
    o[i] = i < 1024 ? bq[i] : (i < 2048 ? bk[i - 1024] : bv[i - 2048]);
}

// ---- LayerNorm (+residual add; optionally init out = x2 + b2) ----
__global__ __launch_bounds__(256) void k_ln(const float* __restrict__ x,
                                            const float* __restrict__ y,
                                            const float* __restrict__ g,
                                            const float* __restrict__ bb,
                                            __hip_bfloat16* __restrict__ o,
                                            const float* __restrict__ badd,
                                            float* __restrict__ oinit) {
  __shared__ float sb[4];
  const int t = threadIdx.x;
  const size_t base = (size_t)blockIdx.x * 1024 + t * 4;
  const int c = t * 4;
  float4 xv = *(const float4*)(x + base);
  if (y) {
    float4 yv = *(const float4*)(y + base);
    xv.x += yv.x; xv.y += yv.y; xv.z += yv.z; xv.w += yv.w;
    float4 ov;
    ov.x = xv.x + badd[c + 0]; ov.y = xv.y + badd[c + 1];
    ov.z = xv.z + badd[c + 2]; ov.w = xv.w + badd[c + 3];
    *(float4*)(oinit + base) = ov;
  }
  const float mu = block_sum(xv.x + xv.y + xv.z + xv.w, sb) * (1.f / 1024.f);
  const float dx = xv.x - mu, dy = xv.y - mu, dz = xv.z - mu, dw = xv.w - mu;
  const float var = block_sum(dx * dx + dy * dy + dz * dz + dw * dw, sb) * (1.f / 1024.f);
  const float rs = rsqrtf(var + 1e-5f);
  o[base + 0] = __float2bfloat16(dx * rs * g[c + 0] + bb[c + 0]);
  o[base + 1] = __float2bfloat16(dy * rs * g[c + 1] + bb[c + 1]);
  o[base + 2] = __float2bfloat16(dz * rs * g[c + 2] + bb[c + 2]);
  o[base + 3] = __float2bfloat16(dw * rs * g[c + 3] + bb[c + 3]);
}

// ---- QKV GEMM: h1[4096,1024] @ Wqkv_t[3072,1024]^T -> Q/K [hb][t][d], Vt [hb][d][t]
// Q is PRE-SCALED by 0.125*log2e so attention logits are base-2.
__global__ __launch_bounds__(256) void k_gemm_qkv(
    const __hip_bfloat16* __restrict__ h1, const __hip_bfloat16* __restrict__ Wt,
    const float* __restrict__ bqkv, __hip_bfloat16* __restrict__ Q,
    __hip_bfloat16* __restrict__ K, __hip_bfloat16* __restrict__ Vt) {
  __shared__ alignas(16) short smem[16896];   // la(8192) lb(8192) | lc(16896)
  short* la = smem;
  short* lb = smem + 8192;
  short* lc = smem;
  const int row0 = blockIdx.x * 128, col0 = blockIdx.y * 128;
  f32x4 acc[4][4] = {};
  gemm_core64<128, 128, 64, 64>(h1, 1024, Wt, 1024, 1024, row0, col0, acc, la, lb);
  const int tid = threadIdx.x, lane = tid & 63, wave = tid >> 6;
  const int wm = (wave >> 1) * 64, wn = (wave & 1) * 64, lr = lane & 15, lq = lane >> 4;
  const int which = col0 >> 10;                 // uniform: 0=Q 1=K 2=V
  const int h0 = (col0 & 1023) >> 6;
  const int b = row0 >> 10, t0 = row0 & 1023;
  if (which < 2) {
    const float qs = (which == 0) ? LOG2E_SCALE : 1.f;
    #pragma unroll
    for (int mi = 0; mi < 4; mi++)
      #pragma unroll
      for (int ni = 0; ni < 4; ni++)
        #pragma unroll
        for (int r = 0; r < 4; r++) {
          const int row = wm + mi * 16 + lq * 4 + r;
          const int col = wn + ni * 16 + lr;
          lc[row * 132 + col] = f2bf_s((acc[mi][ni][r] + bqkv[col0 + col]) * qs);
        }
    __syncthreads();
    __hip_bfloat16* O = which == 0 ? Q : K;
    #pragma unroll
    for (int c = 0; c < 8; c++) {
      const int f = tid + 256 * c;              // flat 16B-chunk id
      const int r = f >> 4, cc = f & 15;
      const int col = cc * 8;
      const int head = h0 + (col >> 6), d = col & 63;
      float4 vv = *(const float4*)(lc + r * 132 + col);
      *(float4*)(O + (((size_t)(b * 16 + head)) << 16) + (t0 + r) * 64 + d) = vv;
    }
  } else {
    // transposed epilogue: lc[col][row]
    #pragma unroll
    for (int mi = 0; mi < 4; mi++)
      #pragma unroll
      for (int ni = 0; ni < 4; ni++)
        #pragma unroll
        for (int r = 0; r < 4; r++) {
          const int row = wm + mi * 16 + lq * 4 + r;
          const int col = wn + ni * 16 + lr;
          lc[col * 132 + row] = f2bf_s(acc[mi][ni][r] + bqkv[col0 + col]);
        }
    __syncthreads();
    #pragma unroll
    for (int c = 0; c < 8; c++) {
      const int f = tid + 256 * c;
      const int dl = f >> 4, tc = f & 15;       // local d 0..127, t-chunk
      const int head = h0 + (dl >> 6), d = dl & 63;
      float4 vv = *(const float4*)(lc + dl * 132 + tc * 8);
      *(float4*)(Vt + (((size_t)(b * 16 + head)) << 16) + (size_t)d * 1024 +
                 t0 + tc * 8) = vv;
    }
  }
}

// ---- tail V sums: TV[hb][qt][d] = sum_{t >= (qt+1)*128} Vt[hb][d][t] ----
__global__ __launch_bounds__(256) void k_tailv(const __hip_bfloat16* __restrict__ Vt,
                                               float* __restrict__ TV) {
  __shared__ float ts[8][64];
  const int hb = blockIdx.x, tid = threadIdx.x;
  const __hip_bfloat16* Vh = Vt + ((size_t)hb << 16);
  for (int w = tid; w < 512; w += 256) {
    const int kt = w >> 6, d = w & 63;
    const short* p = (const short*)(Vh + (size_t)d * 1024 + kt * 128);
    float s = 0.f;
    for (int j = 0; j < 128; j += 8) {
      bf16x8 v = *(const bf16x8*)(p + j);
      #pragma unroll
      for (int e = 0; e < 8; e++) s += bf2f(v[e]);
    }
    ts[kt][d] = s;
  }
  __syncthreads();
  for (int w = tid; w < 512; w += 256) {
    const int qt = w >> 6, d = w & 63;
    float s = 0.f;
    for (int kt = qt + 1; kt < 8; kt++) s += ts[kt][d];
    TV[((size_t)hb * 8 + qt) * 64 + d] = s;
  }
}

// ---- fused attention: one block = (64 q-rows, one head); 1024 blocks ----
// Separate lK/lV buffers; 2 barriers per kt; K(kt+1) prefetched alongside
// V(kt) so its latency hides under softmax+PV; setprio on MFMA clusters.
__global__ __launch_bounds__(256, 3) void k_attn(
    const __hip_bfloat16* __restrict__ Q, const __hip_bfloat16* __restrict__ K,
    const __hip_bfloat16* __restrict__ Vt, const float* __restrict__ TV,
    float* __restrict__ y) {
  __shared__ short lp[64 * 130];   // P-tile (padded)
  __shared__ short lK[128 * 64];   // K-tile, swizzled
  __shared__ short lV[128 * 64];   // V^T-tile, swizzled
  const int hb = blockIdx.y;
  const int j = (blockIdx.y & 32) ? (15 - (int)blockIdx.x) : (int)blockIdx.x;
  const int q0 = j * 64;
  const int nkt = (j >> 1) + 1;    // K-tiles (128 wide) to compute
  const int tid = threadIdx.x, lane = tid & 63, wave = tid >> 6;
  const int lr = lane & 15, lq = lane >> 4;
  const int wm = wave * 16;        // wave owns q-rows [q0+wm, q0+wm+16)
  const __hip_bfloat16* Qh = Q + ((size_t)hb << 16);
  const __hip_bfloat16* Kh = K + ((size_t)hb << 16);
  const __hip_bfloat16* Vh = Vt + ((size_t)hb << 16);

  // Q A-frags: direct global loads (rows q0+wm+lr, cols s*32+lq*8)
  bf16x8 qf[2];
  #pragma unroll
  for (int s = 0; s < 2; s++)
    qf[s] = *(const bf16x8*)((const short*)Qh +
                             (size_t)(q0 + wm + lr) * 64 + s * 32 + lq * 8);

  f32x4 oacc[4] = {};
  float mrow[4], lrow[4];
  #pragma unroll
  for (int r = 0; r < 4; r++) { mrow[r] = -1e30f; lrow[r] = 0.f; }

  // prologue: stage K(0)
  for (int c = tid; c < 1024; c += 256)
    stage16(Kh + (size_t)(c >> 3) * 64 + (((c & 7) ^ ((c >> 3) & 7)) << 3),
            lK + c * 8);
  __syncthreads();  // K(0) visible

  for (int kt = 0; kt < nkt; kt++) {
    const int k0 = kt * 128;
    // ---- QK^T from lK ----
    f32x4 sacc[8] = {};
    __builtin_amdgcn_s_setprio(1);
    #pragma unroll
    for (int s = 0; s < 2; s++) {
      bf16x8 bf[8];
      #pragma unroll
      for (int ni = 0; ni < 8; ni++) {
        const int n = ni * 16 + lr;
        bf[ni] = *(const bf16x8*)(lK + n * 64 + (((s * 4 + lq) ^ (n & 7)) << 3));
      }
      #pragma unroll
      for (int ni = 0; ni < 8; ni++)
        sacc[ni] = __builtin_amdgcn_mfma_f32_16x16x32_bf16(
            qf[s], bf[ni], sacc[ni], 0, 0, 0);
    }
    __builtin_amdgcn_s_setprio(0);
    __syncthreads();  // barA: lK frag reads + prev PV's lp/lV reads done
    // ---- V(kt) + K(kt+1) DMA (latency hides under softmax below) ----
    for (int c = tid; c < 1024; c += 256)
      stage16(Vh + (size_t)(c >> 4) * 1024 + k0 + (((c & 15) ^ ((c >> 4) & 15)) << 3),
              lV + c * 8);
    if (kt + 1 < nkt) {
      const int k1 = k0 + 128;
      for (int c = tid; c < 1024; c += 256)
        stage16(Kh + (size_t)(k1 + (c >> 3)) * 64 + (((c & 7) ^ ((c >> 3) & 7)) << 3),
                lK + c * 8);
    }
    // ---- online softmax, base-2 domain ----
    const bool last = (kt == nkt - 1);
    #pragma unroll
    for (int r = 0; r < 4; r++) {
      const int grow = q0 + wm + lq * 4 + r;   // global q row
      float tmax = -1e30f;
      #pragma unroll
      for (int ni = 0; ni < 8; ni++) {
        float v = sacc[ni][r];
        if (last && (k0 + ni * 16 + lr) > grow) v = MASK2;
        sacc[ni][r] = v;
        tmax = fmaxf(tmax, v);
      }
      #pragma unroll
      for (int msk = 8; msk; msk >>= 1) tmax = fmaxf(tmax, __shfl_xor(tmax, msk));
      const float mn = fmaxf(mrow[r], tmax);
      const float al = __builtin_amdgcn_exp2f(mrow[r] - mn);
      float rs = 0.f;
      #pragma unroll
      for (int ni = 0; ni < 8; ni++) {
        const float pv = __builtin_amdgcn_exp2f(sacc[ni][r] - mn);
        sacc[ni][r] = pv;
        rs += pv;
      }
      #pragma unroll
      for (int msk = 8; msk; msk >>= 1) rs += __shfl_xor(rs, msk);
      mrow[r] = mn;
      lrow[r] = lrow[r] * al + rs;
      #pragma unroll
      for (int ni = 0; ni < 4; ni++) oacc[ni][r] *= al;
    }
    // P -> lp (padded pitch 130)
    #pragma unroll
    for (int r = 0; r < 4; r++) {
      const int row = wm + lq * 4 + r;
      #pragma unroll
      for (int ni = 0; ni < 8; ni++)
        lp[row * 130 + ni * 16 + lr] = f2bf_s(sacc[ni][r]);
    }
    __syncthreads();  // barB: V(kt)+K(kt+1) landed (vmcnt drain) + P visible
    // ---- PV from lp, lV ----
    __builtin_amdgcn_s_setprio(1);
    #pragma unroll
    for (int ks = 0; ks < 4; ks++) {
      bf16x8 pa, vb[4];
      pa = *(const bf16x8*)(lp + (wm + lr) * 130 + ks * 32 + lq * 8);
      #pragma unroll
      for (int ni = 0; ni < 4; ni++) {
        const int d = ni * 16 + lr;
        vb[ni] = *(const bf16x8*)(lV + d * 128 + (((ks * 4 + lq) ^ (d & 15)) << 3));
      }
      #pragma unroll
      for (int ni = 0; ni < 4; ni++)
        oacc[ni] = __builtin_amdgcn_mfma_f32_16x16x32_bf16(
            pa, vb[ni], oacc[ni], 0, 0, 0);
    }
    __builtin_amdgcn_s_setprio(0);
    // no barrier here: next QK reads lK (disjoint from lp/lV); barA covers reuse
  }

  const int b = hb >> 4, h = hb & 15;
  const float cv = (float)(1024 - nkt * 128);
  const float* tv = TV + ((size_t)hb * 8 + (j >> 1)) * 64;
  #pragma unroll
  for (int r = 0; r < 4; r++) {
    const int t = q0 + wm + lq * 4 + r;
    const float tail = __builtin_amdgcn_exp2f(MASK2 - mrow[r]);
    const float inv = 1.f / (lrow[r] + cv * tail);
    #pragma unroll
    for (int ni = 0; ni < 4; ni++) {
      const int d = ni * 16 + lr;
      y[((size_t)(b * 1024 + t) << 10) + h * 64 + d] =
          (oacc[ni][r] + tail * tv[d]) * inv;
    }
  }
}

// ---- MLP1: h2 @ W1t^T + b1 -> tanh-GELU -> G bf16 [4096,4096] ----
// 128x128 tile, grid(32,32): 1024 blocks.
// GELU: v*e/(e+1), e = exp2(v*(2.3022079 + 0.1029434 v^2))  [constants
// pre-folded with 2*log2e]; clamp arg at 80 to avoid inf/inf. ~8 VALU ops
// vs erff's ~35-40 branchy ones; |err| ~3e-4 << bf16 rounding of G.
__global__ __launch_bounds__(256) void k_gemm_mlp1(const __hip_bfloat16* __restrict__ h2,
                                                   const __hip_bfloat16* __restrict__ W1t,
                                                   const float* __restrict__ b1,
                                                   __hip_bfloat16* __restrict__ G) {
  __shared__ alignas(16) short smem[16896];   // la(8192)+lb(8192) | lc(128*132)
  short* la = smem;
  short* lb = smem + 8192;
  short* lc = smem;
  const int row0 = blockIdx.x * 128, col0 = blockIdx.y * 128;
  f32x4 acc[4][4] = {};
  gemm_core64<128, 128, 64, 64>(h2, 1024, W1t, 1024, 1024, row0, col0, acc, la, lb);
  const int tid = threadIdx.x, lane = tid & 63, wave = tid >> 6;
  const int wm = (wave >> 1) * 64, wn = (wave & 1) * 64, lr = lane & 15, lq = lane >> 4;
  #pragma unroll
  for (int mi = 0; mi < 4; mi++)
    #pragma unroll
    for (int ni = 0; ni < 4; ni++)
      #pragma unroll
      for (int r = 0; r < 4; r++) {
        const int row = wm + mi * 16 + lq * 4 + r;
        const int col = wn + ni * 16 + lr;
        float v = acc[mi][ni][r] + b1[col0 + col];
        const float u = fminf(v * (2.3022079f + 0.1029434f * v * v), 80.f);
        const float e = __builtin_amdgcn_exp2f(u);
        v = v * e * __builtin_amdgcn_rcpf(e + 1.f);
        lc[row * 132 + col] = f2bf_s(v);
      }
  __syncthreads();
  #pragma unroll
  for (int c = 0; c < 8; c++) {                 // 2048 chunks of 16B (128x128 tile)
    const int f = tid + 256 * c;
    const int r = f >> 4, cc = f & 15;
    float4 vv = *(const float4*)(lc + r * 132 + cc * 8);
    *(float4*)(G + ((size_t)(row0 + r) << 12) + col0 + cc * 8) = vv;
  }
}

// ---- MLP2 split-K=2: out += G @ W2t^T (out pre-initialized with b2 + x2) ----
// 128x64 tile, grid(32,16,2): 1024 blocks, LDS 24KB. (R10 measured-best.)
__global__ __launch_bounds__(256) void k_gemm_mlp2(const __hip_bfloat16* __restrict__ G,
                                                   const __hip_bfloat16* __restrict__ W2t,
                                                   float* __restrict__ out) {
  __shared__ alignas(16) short smem[12288];
  short* la = smem;
  short* lb = smem + 8192;
  const int row0 = blockIdx.x * 128, col0 = blockIdx.y * 64;
  const int kOff = blockIdx.z * 2048;
  f32x4 acc[4][2] = {};
  gemm_core64<128, 64, 64, 32>(G + kOff, 4096, W2t + kOff, 4096, 2048,
                               row0, col0, acc, la, lb);
  const int lane = threadIdx.x & 63, wave = threadIdx.x >> 6;
  const int wm = (wave >> 1) * 64, wn = (wave & 1) * 32, lr = lane & 15, lq = lane >> 4;
  #pragma unroll
  for (int mi = 0; mi < 4; mi++)
    #pragma unroll
    for (int ni = 0; ni < 2; ni++)
      #pragma unroll
      for (int r = 0; r < 4; r++) {
        const int grow = row0 + wm + mi * 16 + lq * 4 + r;
        const int gcol = col0 + wn + ni * 16 + lr;
        atomicAdd(out + (((size_t)grow << 10) + gcol), acc[mi][ni][r]);
      }
}

extern "C" void kernel_launch(void* const* d_in, const int* in_sizes, int n_in,
                              void* d_out, int out_size, void* d_ws, size_t ws_size,
                              hipStream_t stream) {
  const float* x     = (const float*)d_in[0];
  const float* ln1_g = (const float*)d_in[1];
  const float* ln1_b = (const float*)d_in[2];
  const float* ln2_g = (const float*)d_in[3];
  const float* ln2_b = (const float*)d_in[4];
  const float* Wq    = (const float*)d_in[5];
  const float* bq    = (const float*)d_in[6];
  const float* Wk    = (const float*)d_in[7];
  const float* bk    = (const float*)d_in[8];
  const float* Wv    = (const float*)d_in[9];
  const float* bv    = (const float*)d_in[10];
  const float* W1    = (const float*)d_in[11];
  const float* b1    = (const float*)d_in[12];
  const float* W2    = (const float*)d_in[13];
  const float* b2    = (const float*)d_in[14];
  float* out = (float*)d_out;

  char* p = (char*)d_ws;
  auto alloc = [&](size_t bytes) { char* r = p; p += (bytes + 255) & ~(size_t)255; return r; };
  __hip_bfloat16* wqkv = (__hip_bfloat16*)alloc(3072 * 1024 * 2);
  __hip_bfloat16* w1t  = (__hip_bfloat16*)alloc(4096 * 1024 * 2);
  __hip_bfloat16* w2t  = (__hip_bfloat16*)alloc(1024 * 4096 * 2);
  float*          bqkv = (float*)alloc(3072 * 4);
  __hip_bfloat16* h1   = (__hip_bfloat16*)alloc(4096 * 1024 * 2);
  __hip_bfloat16* Qb   = (__hip_bfloat16*)alloc((size_t)64 * 65536 * 2);  // [64][1024][64]
  __hip_bfloat16* Kb   = (__hip_bfloat16*)alloc((size_t)64 * 65536 * 2);
  __hip_bfloat16* Vt   = (__hip_bfloat16*)alloc((size_t)64 * 65536 * 2);  // [64][64][1024]
  float*          TV   = (float*)alloc((size_t)64 * 8 * 64 * 4);
  float*          yb   = (float*)alloc((size_t)4096 * 1024 * 4);
  __hip_bfloat16* h2   = (__hip_bfloat16*)alloc(4096 * 1024 * 2);
  __hip_bfloat16* G    = (__hip_bfloat16*)alloc((size_t)4096 * 4096 * 2);
  (void)ws_size; (void)in_sizes; (void)n_in; (void)out_size;

  const dim3 b256(256), bt(32, 8);
  k_tcvt3<<<dim3(32, 32, 3), bt, 0, stream>>>(Wq, Wk, Wv, wqkv);
  k_tcvt<<<dim3(128, 32), bt, 0, stream>>>(W1, w1t, 1024, 4096, 0, 1024);
  k_tcvt<<<dim3(32, 128), bt, 0, stream>>>(W2, w2t, 4096, 1024, 0, 4096);
  k_pack_bias<<<12, b256, 0, stream>>>(bq, bk, bv, bqkv);

  k_ln<<<4096, b256, 0, stream>>>(x, nullptr, ln1_g, ln1_b, h1, nullptr, nullptr);
  k_gemm_qkv<<<dim3(32, 24), b256, 0, stream>>>(h1, wqkv, bqkv, Qb, Kb, Vt);
  k_tailv<<<64, b256, 0, stream>>>(Vt, TV);
  k_attn<<<dim3(16, 64), b256, 0, stream>>>(Qb, Kb, Vt, TV, yb);

  k_ln<<<4096, b256, 0, stream>>>(x, yb, ln2_g, ln2_b, h2, b2, out);
  k_gemm_mlp1<<<dim3(32, 32), b256, 0, stream>>>(h2, w1t, b1, G);
  k_gemm_mlp2<<<dim3(32, 16, 2), b256, 0, stream>>>(G, w2t, out);
}

// Round 7
// 332.800 us; speedup vs baseline: 1.0839x; 1.0044x over previous
//
#include <hip/hip_runtime.h>
#include <hip/hip_bf16.h>
#include <math.h>

// Transformer block (pre-LN attn + MLP), B=4 T=1024 H=1024 K=16 HD=64.
// R17 == R16 with the LDS unit-stride bug fixed: STAGE writes 64-short
// units (chunk f -> shorts f*8), reads previously used (r>>1)*128 (128-short
// stride) -> OOB for r>=128, absmax 17.2. Now (r>>1)*64. Swizzle/pipeline
// unchanged (audited correct: vmcnt(4) drains t-1's loads; buffer reuse
// protected by closing barrier; 2-way max bank aliasing).
// mlp1: 256x256 tile, 512 threads (8 waves 2Mx4N), BK=32 dbuf in 64KB LDS,
// counted vmcnt(4) (never 0 in loop), raw barriers, setprio on MFMA.
// Epilogue: tanh-GELU via 4x 64-row lc passes, coalesced float4 stores.
// All other kernels unchanged (m97-family at measured local optima).
// Attention: fused flash-style, 64-row Q-tiles, separate lK/lV, 2 barriers
// per kt, K(kt+1) prefetch hidden under softmax, setprio on MFMA clusters;
// masked logits FILLED with 1e-9; fully-masked K-tiles contribute
// exp(1e-9-m)*suffixV analytically (TV precomputed).

typedef __attribute__((ext_vector_type(8))) short bf16x8;
typedef __attribute__((ext_vector_type(4))) float f32x4;

#define DEVINL __device__ __forceinline__

#define LOG2E_SCALE 0.18033688f      /* 0.125 * log2(e) */
#define MASK2 1.4426950408889634e-9f /* 1e-9 * log2(e) */

DEVINL void stage16(const __hip_bfloat16* g, short* l) {
  __builtin_amdgcn_global_load_lds(
      (const __attribute__((address_space(1))) unsigned int*)g,
      (__attribute__((address_space(3))) unsigned int*)l, 16, 0, 0);
}

DEVINL float bf2f(short u) {
  unsigned x = ((unsigned)(unsigned short)u) << 16;
  float f; __builtin_memcpy(&f, &x, 4); return f;
}

DEVINL short f2bf_s(float f) {
  __hip_bfloat16 h = __float2bfloat16(f);
  short s; __builtin_memcpy(&s, &h, 2); return s;
}

DEVINL float block_sum(float v, float* sb) {
  #pragma unroll
  for (int o = 32; o; o >>= 1) v += __shfl_down(v, o);
  const int lane = threadIdx.x & 63, w = threadIdx.x >> 6;
  if (lane == 0) sb[w] = v;
  __syncthreads();
  float r = sb[0] + sb[1] + sb[2] + sb[3];
  __syncthreads();
  return r;
}

// ---- GEMM core BK=64: C[M,N] += A[M,Kd] * Bt[N,Kd]^T, 256 threads ----
template<int BM, int BN, int WM, int WN>
DEVINL void gemm_core64(const __hip_bfloat16* __restrict__ A, int lda,
                        const __hip_bfloat16* __restrict__ Bt, int ldb,
                        int Kd, int row0, int col0,
                        f32x4 (&acc)[WM/16][WN/16],
                        short* lds_a, short* lds_b) {
  constexpr int MI = WM / 16, NI = WN / 16, WNC = BN / WN;
  constexpr int CA = BM * 8, CB = BN * 8;  // 16B chunks per tile
  const int tid = threadIdx.x;
  const int lane = tid & 63, wave = tid >> 6;
  const int wm = (wave / WNC) * WM, wn = (wave % WNC) * WN;
  const int lr = lane & 15, lq = lane >> 4;
  for (int k0 = 0; k0 < Kd; k0 += 64) {
    #pragma unroll
    for (int c = tid; c < CA; c += 256) {
      const int r = c >> 3, kc = ((c & 7) ^ (r & 7)) << 3;
      stage16(A + (size_t)(row0 + r) * lda + k0 + kc, lds_a + c * 8);
    }
    #pragma unroll
    for (int c = tid; c < CB; c += 256) {
      const int r = c >> 3, kc = ((c & 7) ^ (r & 7)) << 3;
      stage16(Bt + (size_t)(col0 + r) * ldb + k0 + kc, lds_b + c * 8);
    }
    __syncthreads();
    #pragma unroll
    for (int s = 0; s < 2; s++) {
      bf16x8 af[MI], bfr[NI];
      #pragma unroll
      for (int mi = 0; mi < MI; mi++) {
        const int m = wm + mi * 16 + lr;
        af[mi] = *(const bf16x8*)(lds_a + m * 64 + (((s * 4 + lq) ^ (m & 7)) << 3));
      }
      #pragma unroll
      for (int ni = 0; ni < NI; ni++) {
        const int n = wn + ni * 16 + lr;
        bfr[ni] = *(const bf16x8*)(lds_b + n * 64 + (((s * 4 + lq) ^ (n & 7)) << 3));
      }
      #pragma unroll
      for (int mi = 0; mi < MI; mi++)
        #pragma unroll
        for (int ni = 0; ni < NI; ni++)
          acc[mi][ni] = __builtin_amdgcn_mfma_f32_16x16x32_bf16(
              af[mi], bfr[ni], acc[mi][ni], 0, 0, 0);
    }
    __syncthreads();
  }
}

// ---- transpose + f32->bf16: src[R][C] -> dst[(c+off)][r], dst pitch P ----
__global__ __launch_bounds__(256) void k_tcvt(const float* __restrict__ src,
                                              __hip_bfloat16* __restrict__ dst,
                                              int R, int C, int dstOff, int dstPitch) {
  __shared__ float tile[32][33];
  const int c0 = blockIdx.x * 32, r0 = blockIdx.y * 32;
  const int tx = threadIdx.x, ty = threadIdx.y;  // (32,8)
  #pragma unroll
  for (int i = 0; i < 32; i += 8)
    tile[ty + i][tx] = src[(size_t)(r0 + ty + i) * C + c0 + tx];
  __syncthreads();
  #pragma unroll
  for (int i = 0; i < 32; i += 8)
    dst[(size_t)(c0 + ty + i + dstOff) * dstPitch + r0 + tx] =
        __float2bfloat16(tile[tx][ty + i]);
}

// fused Wq/Wk/Wv transpose (z picks source; all 1024x1024, dst pitch 1024)
__global__ __launch_bounds__(256) void k_tcvt3(const float* __restrict__ Wq,
                                               const float* __restrict__ Wk,
                                               const float* __restrict__ Wv,
                                               __hip_bfloat16* __restrict__ dst) {
  __shared__ float tile[32][33];
  const float* src = blockIdx.z == 0 ? Wq : (blockIdx.z == 1 ? Wk : Wv);
  const int dstOff = blockIdx.z << 10;
  const int c0 = blockIdx.x * 32, r0 = blockIdx.y * 32;
  const int tx = threadIdx.x, ty = threadIdx.y;
  #pragma unroll
  for (int i = 0; i < 32; i += 8)
    tile[ty + i][tx] = src[(size_t)(r0 + ty + i) * 1024 + c0 + tx];
  __syncthreads();
  #pragma unroll
  for (int i = 0; i < 32; i += 8)
    dst[(size_t)(c0 + ty + i + dstOff) * 1024 + r0 + tx] =
        __float2bfloat16(tile[tx][ty + i]);
}

__global__ __launch_bounds__(256) void k_pack_bias(const float* __restrict__ bq,
                                                   const float* __restrict__ bk,
                                                   const float* __restrict__ bv,
                                                   float* __restrict__ o) {
  const int i = blockIdx.x * 256 + threadIdx.x;
  if (i < 3072)
    o[i] = i < 1024 ? bq[i] : (i < 2048 ? bk[i - 1024] : bv[i - 2048]);
}

// ---- LayerNorm (+residual add; optionally init out = x2 + b2) ----
__global__ __launch_bounds__(256) void k_ln(const float* __restrict__ x,
                                            const float* __restrict__ y,
                                            const float* __restrict__ g,
                                            const float* __restrict__ bb,
                                            __hip_bfloat16* __restrict__ o,
                                            const float* __restrict__ badd,
                                            float* __restrict__ oinit) {
  __shared__ float sb[4];
  const int t = threadIdx.x;
  const size_t base = (size_t)blockIdx.x * 1024 + t * 4;
  const int c = t * 4;
  float4 xv = *(const float4*)(x + base);
  if (y) {
    float4 yv = *(const float4*)(y + base);
    xv.x += yv.x; xv.y += yv.y; xv.z += yv.z; xv.w += yv.w;
    float4 ov;
    ov.x = xv.x + badd[c + 0]; ov.y = xv.y + badd[c + 1];
    ov.z = xv.z + badd[c + 2]; ov.w = xv.w + badd[c + 3];
    *(float4*)(oinit + base) = ov;
  }
  const float mu = block_sum(xv.x + xv.y + xv.z + xv.w, sb) * (1.f / 1024.f);
  const float dx = xv.x - mu, dy = xv.y - mu, dz = xv.z - mu, dw = xv.w - mu;
  const float var = block_sum(dx * dx + dy * dy + dz * dz + dw * dw, sb) * (1.f / 1024.f);
  const float rs = rsqrtf(var + 1e-5f);
  o[base + 0] = __float2bfloat16(dx * rs * g[c + 0] + bb[c + 0]);
  o[base + 1] = __float2bfloat16(dy * rs * g[c + 1] + bb[c + 1]);
  o[base + 2] = __float2bfloat16(dz * rs * g[c + 2] + bb[c + 2]);
  o[base + 3] = __float2bfloat16(dw * rs * g[c + 3] + bb[c + 3]);
}

// ---- QKV GEMM: h1[4096,1024] @ Wqkv_t[3072,1024]^T -> Q/K [hb][t][d], Vt [hb][d][t]
// Q is PRE-SCALED by 0.125*log2e so attention logits are base-2.
__global__ __launch_bounds__(256) void k_gemm_qkv(
    const __hip_bfloat16* __restrict__ h1, const __hip_bfloat16* __restrict__ Wt,
    const float* __restrict__ bqkv, __hip_bfloat16* __restrict__ Q,
    __hip_bfloat16* __restrict__ K, __hip_bfloat16* __restrict__ Vt) {
  __shared__ alignas(16) short smem[16896];   // la(8192) lb(8192) | lc(16896)
  short* la = smem;
  short* lb = smem + 8192;
  short* lc = smem;
  const int row0 = blockIdx.x * 128, col0 = blockIdx.y * 128;
  f32x4 acc[4][4] = {};
  gemm_core64<128, 128, 64, 64>(h1, 1024, Wt, 1024, 1024, row0, col0, acc, la, lb);
  const int tid = threadIdx.x, lane = tid & 63, wave = tid >> 6;
  const int wm = (wave >> 1) * 64, wn = (wave & 1) * 64, lr = lane & 15, lq = lane >> 4;
  const int which = col0 >> 10;                 // uniform: 0=Q 1=K 2=V
  const int h0 = (col0 & 1023) >> 6;
  const int b = row0 >> 10, t0 = row0 & 1023;
  if (which < 2) {
    const float qs = (which == 0) ? LOG2E_SCALE : 1.f;
    #pragma unroll
    for (int mi = 0; mi < 4; mi++)
      #pragma unroll
      for (int ni = 0; ni < 4; ni++)
        #pragma unroll
        for (int r = 0; r < 4; r++) {
          const int row = wm + mi * 16 + lq * 4 + r;
          const int col = wn + ni * 16 + lr;
          lc[row * 132 + col] = f2bf_s((acc[mi][ni][r] + bqkv[col0 + col]) * qs);
        }
    __syncthreads();
    __hip_bfloat16* O = which == 0 ? Q : K;
    #pragma unroll
    for (int c = 0; c < 8; c++) {
      const int f = tid + 256 * c;              // flat 16B-chunk id
      const int r = f >> 4, cc = f & 15;
      const int col = cc * 8;
      const int head = h0 + (col >> 6), d = col & 63;
      float4 vv = *(const float4*)(lc + r * 132 + col);
      *(float4*)(O + (((size_t)(b * 16 + head)) << 16) + (t0 + r) * 64 + d) = vv;
    }
  } else {
    // transposed epilogue: lc[col][row]
    #pragma unroll
    for (int mi = 0; mi < 4; mi++)
      #pragma unroll
      for (int ni = 0; ni < 4; ni++)
        #pragma unroll
        for (int r = 0; r < 4; r++) {
          const int row = wm + mi * 16 + lq * 4 + r;
          const int col = wn + ni * 16 + lr;
          lc[col * 132 + row] = f2bf_s(acc[mi][ni][r] + bqkv[col0 + col]);
        }
    __syncthreads();
    #pragma unroll
    for (int c = 0; c < 8; c++) {
      const int f = tid + 256 * c;
      const int dl = f >> 4, tc = f & 15;       // local d 0..127, t-chunk
      const int head = h0 + (dl >> 6), d = dl & 63;
      float4 vv = *(const float4*)(lc + dl * 132 + tc * 8);
      *(float4*)(Vt + (((size_t)(b * 16 + head)) << 16) + (size_t)d * 1024 +
                 t0 + tc * 8) = vv;
    }
  }
}

// ---- tail V sums: TV[hb][qt][d] = sum_{t >= (qt+1)*128} Vt[hb][d][t] ----
__global__ __launch_bounds__(256) void k_tailv(const __hip_bfloat16* __restrict__ Vt,
                                               float* __restrict__ TV) {
  __shared__ float ts[8][64];
  const int hb = blockIdx.x, tid = threadIdx.x;
  const __hip_bfloat16* Vh = Vt + ((size_t)hb << 16);
  for (int w = tid; w < 512; w += 256) {
    const int kt = w >> 6, d = w & 63;
    const short* p = (const short*)(Vh + (size_t)d * 1024 + kt * 128);
    float s = 0.f;
    for (int j = 0; j < 128; j += 8) {
      bf16x8 v = *(const bf16x8*)(p + j);
      #pragma unroll
      for (int e = 0; e < 8; e++) s += bf2f(v[e]);
    }
    ts[kt][d] = s;
  }
  __syncthreads();
  for (int w = tid; w < 512; w += 256) {
    const int qt = w >> 6, d = w & 63;
    float s = 0.f;
    for (int kt = qt + 1; kt < 8; kt++) s += ts[kt][d];
    TV[((size_t)hb * 8 + qt) * 64 + d] = s;
  }
}

// ---- fused attention: one block = (64 q-rows, one head); 1024 blocks ----
// Separate lK/lV buffers; 2 barriers per kt; K(kt+1) prefetched alongside
// V(kt) so its latency hides under softmax+PV; setprio on MFMA clusters.
__global__ __launch_bounds__(256, 3) void k_attn(
    const __hip_bfloat16* __restrict__ Q, const __hip_bfloat16* __restrict__ K,
    const __hip_bfloat16* __restrict__ Vt, const float* __restrict__ TV,
    float* __restrict__ y) {
  __shared__ short lp[64 * 130];   // P-tile (padded)
  __shared__ short lK[128 * 64];   // K-tile, swizzled
  __shared__ short lV[128 * 64];   // V^T-tile, swizzled
  const int hb = blockIdx.y;
  const int j = (blockIdx.y & 32) ? (15 - (int)blockIdx.x) : (int)blockIdx.x;
  const int q0 = j * 64;
  const int nkt = (j >> 1) + 1;    // K-tiles (128 wide) to compute
  const int tid = threadIdx.x, lane = tid & 63, wave = tid >> 6;
  const int lr = lane & 15, lq = lane >> 4;
  const int wm = wave * 16;        // wave owns q-rows [q0+wm, q0+wm+16)
  const __hip_bfloat16* Qh = Q + ((size_t)hb << 16);
  const __hip_bfloat16* Kh = K + ((size_t)hb << 16);
  const __hip_bfloat16* Vh = Vt + ((size_t)hb << 16);

  // Q A-frags: direct global loads (rows q0+wm+lr, cols s*32+lq*8)
  bf16x8 qf[2];
  #pragma unroll
  for (int s = 0; s < 2; s++)
    qf[s] = *(const bf16x8*)((const short*)Qh +
                             (size_t)(q0 + wm + lr) * 64 + s * 32 + lq * 8);

  f32x4 oacc[4] = {};
  float mrow[4], lrow[4];
  #pragma unroll
  for (int r = 0; r < 4; r++) { mrow[r] = -1e30f; lrow[r] = 0.f; }

  // prologue: stage K(0)
  for (int c = tid; c < 1024; c += 256)
    stage16(Kh + (size_t)(c >> 3) * 64 + (((c & 7) ^ ((c >> 3) & 7)) << 3),
            lK + c * 8);
  __syncthreads();  // K(0) visible

  for (int kt = 0; kt < nkt; kt++) {
    const int k0 = kt * 128;
    // ---- QK^T from lK ----
    f32x4 sacc[8] = {};
    __builtin_amdgcn_s_setprio(1);
    #pragma unroll
    for (int s = 0; s < 2; s++) {
      bf16x8 bf[8];
      #pragma unroll
      for (int ni = 0; ni < 8; ni++) {
        const int n = ni * 16 + lr;
        bf[ni] = *(const bf16x8*)(lK + n * 64 + (((s * 4 + lq) ^ (n & 7)) << 3));
      }
      #pragma unroll
      for (int ni = 0; ni < 8; ni++)
        sacc[ni] = __builtin_amdgcn_mfma_f32_16x16x32_bf16(
            qf[s], bf[ni], sacc[ni], 0, 0, 0);
    }
    __builtin_amdgcn_s_setprio(0);
    __syncthreads();  // barA: lK frag reads + prev PV's lp/lV reads done
    // ---- V(kt) + K(kt+1) DMA (latency hides under softmax below) ----
    for (int c = tid; c < 1024; c += 256)
      stage16(Vh + (size_t)(c >> 4) * 1024 + k0 + (((c & 15) ^ ((c >> 4) & 15)) << 3),
              lV + c * 8);
    if (kt + 1 < nkt) {
      const int k1 = k0 + 128;
      for (int c = tid; c < 1024; c += 256)
        stage16(Kh + (size_t)(k1 + (c >> 3)) * 64 + (((c & 7) ^ ((c >> 3) & 7)) << 3),
                lK + c * 8);
    }
    // ---- online softmax, base-2 domain ----
    const bool last = (kt == nkt - 1);
    #pragma unroll
    for (int r = 0; r < 4; r++) {
      const int grow = q0 + wm + lq * 4 + r;   // global q row
      float tmax = -1e30f;
      #pragma unroll
      for (int ni = 0; ni < 8; ni++) {
        float v = sacc[ni][r];
        if (last && (k0 + ni * 16 + lr) > grow) v = MASK2;
        sacc[ni][r] = v;
        tmax = fmaxf(tmax, v);
      }
      #pragma unroll
      for (int msk = 8; msk; msk >>= 1) tmax = fmaxf(tmax, __shfl_xor(tmax, msk));
      const float mn = fmaxf(mrow[r], tmax);
      const float al = __builtin_amdgcn_exp2f(mrow[r] - mn);
      float rs = 0.f;
      #pragma unroll
      for (int ni = 0; ni < 8; ni++) {
        const float pv = __builtin_amdgcn_exp2f(sacc[ni][r] - mn);
        sacc[ni][r] = pv;
        rs += pv;
      }
      #pragma unroll
      for (int msk = 8; msk; msk >>= 1) rs += __shfl_xor(rs, msk);
      mrow[r] = mn;
      lrow[r] = lrow[r] * al + rs;
      #pragma unroll
      for (int ni = 0; ni < 4; ni++) oacc[ni][r] *= al;
    }
    // P -> lp (padded pitch 130)
    #pragma unroll
    for (int r = 0; r < 4; r++) {
      const int row = wm + lq * 4 + r;
      #pragma unroll
      for (int ni = 0; ni < 8; ni++)
        lp[row * 130 + ni * 16 + lr] = f2bf_s(sacc[ni][r]);
    }
    __syncthreads();  // barB: V(kt)+K(kt+1) landed (vmcnt drain) + P visible
    // ---- PV from lp, lV ----
    __builtin_amdgcn_s_setprio(1);
    #pragma unroll
    for (int ks = 0; ks < 4; ks++) {
      bf16x8 pa, vb[4];
      pa = *(const bf16x8*)(lp + (wm + lr) * 130 + ks * 32 + lq * 8);
      #pragma unroll
      for (int ni = 0; ni < 4; ni++) {
        const int d = ni * 16 + lr;
        vb[ni] = *(const bf16x8*)(lV + d * 128 + (((ks * 4 + lq) ^ (d & 15)) << 3));
      }
      #pragma unroll
      for (int ni = 0; ni < 4; ni++)
        oacc[ni] = __builtin_amdgcn_mfma_f32_16x16x32_bf16(
            pa, vb[ni], oacc[ni], 0, 0, 0);
    }
    __builtin_amdgcn_s_setprio(0);
    // no barrier here: next QK reads lK (disjoint from lp/lV); barA covers reuse
  }

  const int b = hb >> 4, h = hb & 15;
  const float cv = (float)(1024 - nkt * 128);
  const float* tv = TV + ((size_t)hb * 8 + (j >> 1)) * 64;
  #pragma unroll
  for (int r = 0; r < 4; r++) {
    const int t = q0 + wm + lq * 4 + r;
    const float tail = __builtin_amdgcn_exp2f(MASK2 - mrow[r]);
    const float inv = 1.f / (lrow[r] + cv * tail);
    #pragma unroll
    for (int ni = 0; ni < 4; ni++) {
      const int d = ni * 16 + lr;
      y[((size_t)(b * 1024 + t) << 10) + h * 64 + d] =
          (oacc[ni][r] + tail * tv[d]) * inv;
    }
  }
}

// ---- MLP1: h2[4096,1024] @ W1t[4096,1024]^T + b1 -> tanh-GELU -> G bf16 ----
// 256x256 tile, 512 threads (8 waves 2Mx4N, 128x64 each), BK=32 dbuf,
// counted vmcnt(4) (never 0 in loop), raw barriers, setprio on MFMA.
// LDS 64KB static: A0 A1 B0 B1 x 8192 shorts. Swizzle: 64-short row-pair
// unit u holds rows 2u,2u+1 as 8 16B chunks; logical chunk G=(r&1)*4+g
// stored at P=G^(u&7); same involution on stage-source and ds_read.
__global__ __launch_bounds__(512, 2) void k_gemm_mlp1(const __hip_bfloat16* __restrict__ h2,
                                                      const __hip_bfloat16* __restrict__ W1t,
                                                      const float* __restrict__ b1,
                                                      __hip_bfloat16* __restrict__ G) {
  __shared__ alignas(16) short smem[32768];   // 64KB
  const int row0 = blockIdx.x * 256, col0 = blockIdx.y * 256;
  const int tid = threadIdx.x, lane = tid & 63, wid = tid >> 6;
  const int lr = lane & 15, lq = lane >> 4;
  const int wm = (wid >> 2) * 128, wn = (wid & 3) * 64;
  const __hip_bfloat16* A = h2 + (size_t)row0 * 1024;
  const __hip_bfloat16* Bt = W1t + (size_t)col0 * 1024;

  // stage one 256x32 bf16 tile (swizzled) at ks [k0,k0+32) into dst
  auto STAGE = [&](const __hip_bfloat16* src, int k0, short* dst) {
    #pragma unroll
    for (int i = 0; i < 2; i++) {
      const int f = tid + i * 512;
      const int u = f >> 3, P = f & 7, Gc = P ^ (u & 7);
      const int r = u * 2 + (Gc >> 2), g = Gc & 3;
      stage16(src + (size_t)r * 1024 + k0 + g * 8, dst + f * 8);
    }
  };

  f32x4 acc[8][4] = {};
  STAGE(A, 0, smem);                 // A0
  STAGE(Bt, 0, smem + 16384);        // B0
  for (int t = 0; t < 32; ++t) {
    const int cur = t & 1;
    short* pa = smem + cur * 8192;
    short* pb = smem + 16384 + cur * 8192;
    if (t + 1 < 32) {
      short* na = smem + (cur ^ 1) * 8192;
      short* nb = smem + 16384 + (cur ^ 1) * 8192;
      STAGE(A, (t + 1) * 32, na);
      STAGE(Bt, (t + 1) * 32, nb);
      asm volatile("s_waitcnt vmcnt(4)" ::: "memory");
    } else {
      asm volatile("s_waitcnt vmcnt(0)" ::: "memory");
    }
    asm volatile("s_barrier" ::: "memory");
    bf16x8 af[8], bfr[4];
    #pragma unroll
    for (int mi = 0; mi < 8; mi++) {
      const int r = wm + mi * 16 + lr;
      af[mi] = *(const bf16x8*)(pa + (r >> 1) * 64 +
                ((((((r & 1) << 2) | lq)) ^ ((r >> 1) & 7)) << 3));
    }
    #pragma unroll
    for (int ni = 0; ni < 4; ni++) {
      const int n = wn + ni * 16 + lr;
      bfr[ni] = *(const bf16x8*)(pb + (n >> 1) * 64 +
                ((((((n & 1) << 2) | lq)) ^ ((n >> 1) & 7)) << 3));
    }
    __builtin_amdgcn_s_setprio(1);
    #pragma unroll
    for (int mi = 0; mi < 8; mi++)
      #pragma unroll
      for (int ni = 0; ni < 4; ni++)
        acc[mi][ni] = __builtin_amdgcn_mfma_f32_16x16x32_bf16(
            af[mi], bfr[ni], acc[mi][ni], 0, 0, 0);
    __builtin_amdgcn_s_setprio(0);
    asm volatile("s_barrier" ::: "memory");
  }

  // epilogue: tanh-GELU -> bf16 via 4x 64-row lc passes (lc = smem)
  short* lc = smem;
  #pragma unroll
  for (int pr = 0; pr < 4; pr++) {
    if ((wid >> 2) == (pr >> 1)) {
      const int mib = (pr & 1) * 4;
      #pragma unroll
      for (int mi2 = 0; mi2 < 4; mi2++)
        #pragma unroll
        for (int ni = 0; ni < 4; ni++)
          #pragma unroll
          for (int rr = 0; rr < 4; rr++) {
            const int rloc = mi2 * 16 + lq * 4 + rr;
            const int col = wn + ni * 16 + lr;
            float v = acc[mib + mi2][ni][rr] + b1[col0 + col];
            const float u2 = fminf(v * (2.3022079f + 0.1029434f * v * v), 80.f);
            const float e = __builtin_amdgcn_exp2f(u2);
            v = v * e * __builtin_amdgcn_rcpf(e + 1.f);
            lc[rloc * 264 + col] = f2bf_s(v);
          }
    }
    __syncthreads();
    #pragma unroll
    for (int c = 0; c < 4; c++) {
      const int f = tid + 512 * c;       // 2048 chunks: 64 rows x 32 chunks
      const int r = f >> 5, cc = f & 31;
      float4 vv = *(const float4*)(lc + r * 264 + cc * 8);
      *(float4*)(G + ((size_t)(row0 + pr * 64 + r) << 12) + col0 + cc * 8) = vv;
    }
    __syncthreads();
  }
}

// ---- MLP2 split-K=2: out += G @ W2t^T (out pre-initialized with b2 + x2) ----
// 128x64 tile, grid(32,16,2): 1024 blocks, LDS 24KB. (R10 measured-best.)
__global__ __launch_bounds__(256) void k_gemm_mlp2(const __hip_bfloat16* __restrict__ G,
                                                   const __hip_bfloat16* __restrict__ W2t,
                                                   float* __restrict__ out) {
  __shared__ alignas(16) short smem[12288];
  short* la = smem;
  short* lb = smem + 8192;
  const int row0 = blockIdx.x * 128, col0 = blockIdx.y * 64;
  const int kOff = blockIdx.z * 2048;
  f32x4 acc[4][2] = {};
  gemm_core64<128, 64, 64, 32>(G + kOff, 4096, W2t + kOff, 4096, 2048,
                               row0, col0, acc, la, lb);
  const int lane = threadIdx.x & 63, wave = threadIdx.x >> 6;
  const int wm = (wave >> 1) * 64, wn = (wave & 1) * 32, lr = lane & 15, lq = lane >> 4;
  #pragma unroll
  for (int mi = 0; mi < 4; mi++)
    #pragma unroll
    for (int ni = 0; ni < 2; ni++)
      #pragma unroll
      for (int r = 0; r < 4; r++) {
        const int grow = row0 + wm + mi * 16 + lq * 4 + r;
        const int gcol = col0 + wn + ni * 16 + lr;
        atomicAdd(out + (((size_t)grow << 10) + gcol), acc[mi][ni][r]);
      }
}

extern "C" void kernel_launch(void* const* d_in, const int* in_sizes, int n_in,
                              void* d_out, int out_size, void* d_ws, size_t ws_size,
                              hipStream_t stream) {
  const float* x     = (const float*)d_in[0];
  const float* ln1_g = (const float*)d_in[1];
  const float* ln1_b = (const float*)d_in[2];
  const float* ln2_g = (const float*)d_in[3];
  const float* ln2_b = (const float*)d_in[4];
  const float* Wq    = (const float*)d_in[5];
  const float* bq    = (const float*)d_in[6];
  const float* Wk    = (const float*)d_in[7];
  const float* bk    = (const float*)d_in[8];
  const float* Wv    = (const float*)d_in[9];
  const float* bv    = (const float*)d_in[10];
  const float* W1    = (const float*)d_in[11];
  const float* b1    = (const float*)d_in[12];
  const float* W2    = (const float*)d_in[13];
  const float* b2    = (const float*)d_in[14];
  float* out = (float*)d_out;

  char* p = (char*)d_ws;
  auto alloc = [&](size_t bytes) { char* r = p; p += (bytes + 255) & ~(size_t)255; return r; };
  __hip_bfloat16* wqkv = (__hip_bfloat16*)alloc(3072 * 1024 * 2);
  __hip_bfloat16* w1t  = (__hip_bfloat16*)alloc(4096 * 1024 * 2);
  __hip_bfloat16* w2t  = (__hip_bfloat16*)alloc(1024 * 4096 * 2);
  float*          bqkv = (float*)alloc(3072 * 4);
  __hip_bfloat16* h1   = (__hip_bfloat16*)alloc(4096 * 1024 * 2);
  __hip_bfloat16* Qb   = (__hip_bfloat16*)alloc((size_t)64 * 65536 * 2);  // [64][1024][64]
  __hip_bfloat16* Kb   = (__hip_bfloat16*)alloc((size_t)64 * 65536 * 2);
  __hip_bfloat16* Vt   = (__hip_bfloat16*)alloc((size_t)64 * 65536 * 2);  // [64][64][1024]
  float*          TV   = (float*)alloc((size_t)64 * 8 * 64 * 4);
  float*          yb   = (float*)alloc((size_t)4096 * 1024 * 4);
  __hip_bfloat16* h2   = (__hip_bfloat16*)alloc(4096 * 1024 * 2);
  __hip_bfloat16* G    = (__hip_bfloat16*)alloc((size_t)4096 * 4096 * 2);
  (void)ws_size; (void)in_sizes; (void)n_in; (void)out_size;

  const dim3 b256(256), bt(32, 8);
  k_tcvt3<<<dim3(32, 32, 3), bt, 0, stream>>>(Wq, Wk, Wv, wqkv);
  k_tcvt<<<dim3(128, 32), bt, 0, stream>>>(W1, w1t, 1024, 4096, 0, 1024);
  k_tcvt<<<dim3(32, 128), bt, 0, stream>>>(W2, w2t, 4096, 1024, 0, 4096);
  k_pack_bias<<<12, b256, 0, stream>>>(bq, bk, bv, bqkv);

  k_ln<<<4096, b256, 0, stream>>>(x, nullptr, ln1_g, ln1_b, h1, nullptr, nullptr);
  k_gemm_qkv<<<dim3(32, 24), b256, 0, stream>>>(h1, wqkv, bqkv, Qb, Kb, Vt);
  k_tailv<<<64, b256, 0, stream>>>(Vt, TV);
  k_attn<<<dim3(16, 64), b256, 0, stream>>>(Qb, Kb, Vt, TV, yb);

  k_ln<<<4096, b256, 0, stream>>>(x, yb, ln2_g, ln2_b, h2, b2, out);
  k_gemm_mlp1<<<dim3(16, 16), dim3(512), 0, stream>>>(h2, w1t, b1, G);
  k_gemm_mlp2<<<dim3(32, 16, 2), b256, 0, stream>>>(G, w2t, out);
}

// Round 9
// 329.643 us; speedup vs baseline: 1.0943x; 1.0096x over previous
//
#include <hip/hip_runtime.h>
#include <hip/hip_bf16.h>
#include <math.h>

// Transformer block (pre-LN attn + MLP), B=4 T=1024 H=1024 K=16 HD=64.
// R19 == R18 resubmit (R18 hit an infra failure, never ran):
// mlp1 upgraded from monophase counted-vmcnt (R17, ~600 TF) to the
// genuine 8-phase schedule (T3+T4+T5): BK=64, 2 K-tiles/iter, per phase
// {quadrant ds_reads -> 1 part stage -> [vmcnt(4) ph3/ph7] -> bar ->
// lgkm0+schedbar -> 16 MFMA setprio -> bar}. Staging ledger (verified):
//   A-part h = rows bit6==h (read only at mh==h phases; af reg-cached
//   across nh). B-part h = rows bit5==h. Stage targets a region whose
//   last read retired 1 phase earlier:
//   ph0:O_i.A1 ph1:O_i.B1 ph2:E'.A0 ph3:E'.B0+vmcnt ph4:E'.A1 ph5:E'.B1
//   ph6:O'.A0 ph7:O'.B0+vmcnt.  vmcnt(4) leaves exactly the 2 newest
//   parts in flight; FIFO retire => all parts read in the next 4 phases
//   landed. Tail (i==7): ph3 vmcnt(0), stages with k>=1024 skipped.
// LDS 128KB (Ae,Ao,Be,Bo x 16384 shorts), 1 block/CU, 512 thr (8 waves
// 2Mx4N, 128x64 out each). Swizzle: row r (64 shorts) chunk g stored at
// P=g^(r&7); same involution on stage source and ds_read (rule #21).
// All other kernels unchanged from R17.
// Attention: fused flash-style, 64-row Q-tiles, separate lK/lV, 2 barriers
// per kt, K(kt+1) prefetch hidden under softmax, setprio on MFMA clusters;
// masked logits FILLED with 1e-9; fully-masked K-tiles contribute
// exp(1e-9-m)*suffixV analytically (TV precomputed).

typedef __attribute__((ext_vector_type(8))) short bf16x8;
typedef __attribute__((ext_vector_type(4))) float f32x4;

#define DEVINL __device__ __forceinline__

#define LOG2E_SCALE 0.18033688f      /* 0.125 * log2(e) */
#define MASK2 1.4426950408889634e-9f /* 1e-9 * log2(e) */

DEVINL void stage16(const __hip_bfloat16* g, short* l) {
  __builtin_amdgcn_global_load_lds(
      (const __attribute__((address_space(1))) unsigned int*)g,
      (__attribute__((address_space(3))) unsigned int*)l, 16, 0, 0);
}

DEVINL float bf2f(short u) {
  unsigned x = ((unsigned)(unsigned short)u) << 16;
  float f; __builtin_memcpy(&f, &x, 4); return f;
}

DEVINL short f2bf_s(float f) {
  __hip_bfloat16 h = __float2bfloat16(f);
  short s; __builtin_memcpy(&s, &h, 2); return s;
}

DEVINL float block_sum(float v, float* sb) {
  #pragma unroll
  for (int o = 32; o; o >>= 1) v += __shfl_down(v, o);
  const int lane = threadIdx.x & 63, w = threadIdx.x >> 6;
  if (lane == 0) sb[w] = v;
  __syncthreads();
  float r = sb[0] + sb[1] + sb[2] + sb[3];
  __syncthreads();
  return r;
}

// ---- GEMM core BK=64: C[M,N] += A[M,Kd] * Bt[N,Kd]^T, 256 threads ----
template<int BM, int BN, int WM, int WN>
DEVINL void gemm_core64(const __hip_bfloat16* __restrict__ A, int lda,
                        const __hip_bfloat16* __restrict__ Bt, int ldb,
                        int Kd, int row0, int col0,
                        f32x4 (&acc)[WM/16][WN/16],
                        short* lds_a, short* lds_b) {
  constexpr int MI = WM / 16, NI = WN / 16, WNC = BN / WN;
  constexpr int CA = BM * 8, CB = BN * 8;  // 16B chunks per tile
  const int tid = threadIdx.x;
  const int lane = tid & 63, wave = tid >> 6;
  const int wm = (wave / WNC) * WM, wn = (wave % WNC) * WN;
  const int lr = lane & 15, lq = lane >> 4;
  for (int k0 = 0; k0 < Kd; k0 += 64) {
    #pragma unroll
    for (int c = tid; c < CA; c += 256) {
      const int r = c >> 3, kc = ((c & 7) ^ (r & 7)) << 3;
      stage16(A + (size_t)(row0 + r) * lda + k0 + kc, lds_a + c * 8);
    }
    #pragma unroll
    for (int c = tid; c < CB; c += 256) {
      const int r = c >> 3, kc = ((c & 7) ^ (r & 7)) << 3;
      stage16(Bt + (size_t)(col0 + r) * ldb + k0 + kc, lds_b + c * 8);
    }
    __syncthreads();
    #pragma unroll
    for (int s = 0; s < 2; s++) {
      bf16x8 af[MI], bfr[NI];
      #pragma unroll
      for (int mi = 0; mi < MI; mi++) {
        const int m = wm + mi * 16 + lr;
        af[mi] = *(const bf16x8*)(lds_a + m * 64 + (((s * 4 + lq) ^ (m & 7)) << 3));
      }
      #pragma unroll
      for (int ni = 0; ni < NI; ni++) {
        const int n = wn + ni * 16 + lr;
        bfr[ni] = *(const bf16x8*)(lds_b + n * 64 + (((s * 4 + lq) ^ (n & 7)) << 3));
      }
      #pragma unroll
      for (int mi = 0; mi < MI; mi++)
        #pragma unroll
        for (int ni = 0; ni < NI; ni++)
          acc[mi][ni] = __builtin_amdgcn_mfma_f32_16x16x32_bf16(
              af[mi], bfr[ni], acc[mi][ni], 0, 0, 0);
    }
    __syncthreads();
  }
}

// ---- transpose + f32->bf16: src[R][C] -> dst[(c+off)][r], dst pitch P ----
__global__ __launch_bounds__(256) void k_tcvt(const float* __restrict__ src,
                                              __hip_bfloat16* __restrict__ dst,
                                              int R, int C, int dstOff, int dstPitch) {
  __shared__ float tile[32][33];
  const int c0 = blockIdx.x * 32, r0 = blockIdx.y * 32;
  const int tx = threadIdx.x, ty = threadIdx.y;  // (32,8)
  #pragma unroll
  for (int i = 0; i < 32; i += 8)
    tile[ty + i][tx] = src[(size_t)(r0 + ty + i) * C + c0 + tx];
  __syncthreads();
  #pragma unroll
  for (int i = 0; i < 32; i += 8)
    dst[(size_t)(c0 + ty + i + dstOff) * dstPitch + r0 + tx] =
        __float2bfloat16(tile[tx][ty + i]);
}

// fused Wq/Wk/Wv transpose (z picks source; all 1024x1024, dst pitch 1024)
__global__ __launch_bounds__(256) void k_tcvt3(const float* __restrict__ Wq,
                                               const float* __restrict__ Wk,
                                               const float* __restrict__ Wv,
                                               __hip_bfloat16* __restrict__ dst) {
  __shared__ float tile[32][33];
  const float* src = blockIdx.z == 0 ? Wq : (blockIdx.z == 1 ? Wk : Wv);
  const int dstOff = blockIdx.z << 10;
  const int c0 = blockIdx.x * 32, r0 = blockIdx.y * 32;
  const int tx = threadIdx.x, ty = threadIdx.y;
  #pragma unroll
  for (int i = 0; i < 32; i += 8)
    tile[ty + i][tx] = src[(size_t)(r0 + ty + i) * 1024 + c0 + tx];
  __syncthreads();
  #pragma unroll
  for (int i = 0; i < 32; i += 8)
    dst[(size_t)(c0 + ty + i + dstOff) * 1024 + r0 + tx] =
        __float2bfloat16(tile[tx][ty + i]);
}

__global__ __launch_bounds__(256) void k_pack_bias(const float* __restrict__ bq,
                                                   const float* __restrict__ bk,
                                                   const float* __restrict__ bv,
                                                   float* __restrict__ o) {
  const int i = blockIdx.x * 256 + threadIdx.x;
  if (i < 3072)
    o[i] = i < 1024 ? bq[i] : (i < 2048 ? bk[i - 1024] : bv[i - 2048]);
}

// ---- LayerNorm (+residual add; optionally init out = x2 + b2) ----
__global__ __launch_bounds__(256) void k_ln(const float* __restrict__ x,
                                            const float* __restrict__ y,
                                            const float* __restrict__ g,
                                            const float* __restrict__ bb,
                                            __hip_bfloat16* __restrict__ o,
                                            const float* __restrict__ badd,
                                            float* __restrict__ oinit) {
  __shared__ float sb[4];
  const int t = threadIdx.x;
  const size_t base = (size_t)blockIdx.x * 1024 + t * 4;
  const int c = t * 4;
  float4 xv = *(const float4*)(x + base);
  if (y) {
    float4 yv = *(const float4*)(y + base);
    xv.x += yv.x; xv.y += yv.y; xv.z += yv.z; xv.w += yv.w;
    float4 ov;
    ov.x = xv.x + badd[c + 0]; ov.y = xv.y + badd[c + 1];
    ov.z = xv.z + badd[c + 2]; ov.w = xv.w + badd[c + 3];
    *(float4*)(oinit + base) = ov;
  }
  const float mu = block_sum(xv.x + xv.y + xv.z + xv.w, sb) * (1.f / 1024.f);
  const float dx = xv.x - mu, dy = xv.y - mu, dz = xv.z - mu, dw = xv.w - mu;
  const float var = block_sum(dx * dx + dy * dy + dz * dz + dw * dw, sb) * (1.f / 1024.f);
  const float rs = rsqrtf(var + 1e-5f);
  o[base + 0] = __float2bfloat16(dx * rs * g[c + 0] + bb[c + 0]);
  o[base + 1] = __float2bfloat16(dy * rs * g[c + 1] + bb[c + 1]);
  o[base + 2] = __float2bfloat16(dz * rs * g[c + 2] + bb[c + 2]);
  o[base + 3] = __float2bfloat16(dw * rs * g[c + 3] + bb[c + 3]);
}

// ---- QKV GEMM: h1[4096,1024] @ Wqkv_t[3072,1024]^T -> Q/K [hb][t][d], Vt [hb][d][t]
// Q is PRE-SCALED by 0.125*log2e so attention logits are base-2.
__global__ __launch_bounds__(256) void k_gemm_qkv(
    const __hip_bfloat16* __restrict__ h1, const __hip_bfloat16* __restrict__ Wt,
    const float* __restrict__ bqkv, __hip_bfloat16* __restrict__ Q,
    __hip_bfloat16* __restrict__ K, __hip_bfloat16* __restrict__ Vt) {
  __shared__ alignas(16) short smem[16896];   // la(8192) lb(8192) | lc(16896)
  short* la = smem;
  short* lb = smem + 8192;
  short* lc = smem;
  const int row0 = blockIdx.x * 128, col0 = blockIdx.y * 128;
  f32x4 acc[4][4] = {};
  gemm_core64<128, 128, 64, 64>(h1, 1024, Wt, 1024, 1024, row0, col0, acc, la, lb);
  const int tid = threadIdx.x, lane = tid & 63, wave = tid >> 6;
  const int wm = (wave >> 1) * 64, wn = (wave & 1) * 64, lr = lane & 15, lq = lane >> 4;
  const int which = col0 >> 10;                 // uniform: 0=Q 1=K 2=V
  const int h0 = (col0 & 1023) >> 6;
  const int b = row0 >> 10, t0 = row0 & 1023;
  if (which < 2) {
    const float qs = (which == 0) ? LOG2E_SCALE : 1.f;
    #pragma unroll
    for (int mi = 0; mi < 4; mi++)
      #pragma unroll
      for (int ni = 0; ni < 4; ni++)
        #pragma unroll
        for (int r = 0; r < 4; r++) {
          const int row = wm + mi * 16 + lq * 4 + r;
          const int col = wn + ni * 16 + lr;
          lc[row * 132 + col] = f2bf_s((acc[mi][ni][r] + bqkv[col0 + col]) * qs);
        }
    __syncthreads();
    __hip_bfloat16* O = which == 0 ? Q : K;
    #pragma unroll
    for (int c = 0; c < 8; c++) {
      const int f = tid + 256 * c;              // flat 16B-chunk id
      const int r = f >> 4, cc = f & 15;
      const int col = cc * 8;
      const int head = h0 + (col >> 6), d = col & 63;
      float4 vv = *(const float4*)(lc + r * 132 + col);
      *(float4*)(O + (((size_t)(b * 16 + head)) << 16) + (t0 + r) * 64 + d) = vv;
    }
  } else {
    // transposed epilogue: lc[col][row]
    #pragma unroll
    for (int mi = 0; mi < 4; mi++)
      #pragma unroll
      for (int ni = 0; ni < 4; ni++)
        #pragma unroll
        for (int r = 0; r < 4; r++) {
          const int row = wm + mi * 16 + lq * 4 + r;
          const int col = wn + ni * 16 + lr;
          lc[col * 132 + row] = f2bf_s(acc[mi][ni][r] + bqkv[col0 + col]);
        }
    __syncthreads();
    #pragma unroll
    for (int c = 0; c < 8; c++) {
      const int f = tid + 256 * c;
      const int dl = f >> 4, tc = f & 15;       // local d 0..127, t-chunk
      const int head = h0 + (dl >> 6), d = dl & 63;
      float4 vv = *(const float4*)(lc + dl * 132 + tc * 8);
      *(float4*)(Vt + (((size_t)(b * 16 + head)) << 16) + (size_t)d * 1024 +
                 t0 + tc * 8) = vv;
    }
  }
}

// ---- tail V sums: TV[hb][qt][d] = sum_{t >= (qt+1)*128} Vt[hb][d][t] ----
__global__ __launch_bounds__(256) void k_tailv(const __hip_bfloat16* __restrict__ Vt,
                                               float* __restrict__ TV) {
  __shared__ float ts[8][64];
  const int hb = blockIdx.x, tid = threadIdx.x;
  const __hip_bfloat16* Vh = Vt + ((size_t)hb << 16);
  for (int w = tid; w < 512; w += 256) {
    const int kt = w >> 6, d = w & 63;
    const short* p = (const short*)(Vh + (size_t)d * 1024 + kt * 128);
    float s = 0.f;
    for (int j = 0; j < 128; j += 8) {
      bf16x8 v = *(const bf16x8*)(p + j);
      #pragma unroll
      for (int e = 0; e < 8; e++) s += bf2f(v[e]);
    }
    ts[kt][d] = s;
  }
  __syncthreads();
  for (int w = tid; w < 512; w += 256) {
    const int qt = w >> 6, d = w & 63;
    float s = 0.f;
    for (int kt = qt + 1; kt < 8; kt++) s += ts[kt][d];
    TV[((size_t)hb * 8 + qt) * 64 + d] = s;
  }
}

// ---- fused attention: one block = (64 q-rows, one head); 1024 blocks ----
// Separate lK/lV buffers; 2 barriers per kt; K(kt+1) prefetched alongside
// V(kt) so its latency hides under softmax+PV; setprio on MFMA clusters.
__global__ __launch_bounds__(256, 3) void k_attn(
    const __hip_bfloat16* __restrict__ Q, const __hip_bfloat16* __restrict__ K,
    const __hip_bfloat16* __restrict__ Vt, const float* __restrict__ TV,
    float* __restrict__ y) {
  __shared__ short lp[64 * 130];   // P-tile (padded)
  __shared__ short lK[128 * 64];   // K-tile, swizzled
  __shared__ short lV[128 * 64];   // V^T-tile, swizzled
  const int hb = blockIdx.y;
  const int j = (blockIdx.y & 32) ? (15 - (int)blockIdx.x) : (int)blockIdx.x;
  const int q0 = j * 64;
  const int nkt = (j >> 1) + 1;    // K-tiles (128 wide) to compute
  const int tid = threadIdx.x, lane = tid & 63, wave = tid >> 6;
  const int lr = lane & 15, lq = lane >> 4;
  const int wm = wave * 16;        // wave owns q-rows [q0+wm, q0+wm+16)
  const __hip_bfloat16* Qh = Q + ((size_t)hb << 16);
  const __hip_bfloat16* Kh = K + ((size_t)hb << 16);
  const __hip_bfloat16* Vh = Vt + ((size_t)hb << 16);

  // Q A-frags: direct global loads (rows q0+wm+lr, cols s*32+lq*8)
  bf16x8 qf[2];
  #pragma unroll
  for (int s = 0; s < 2; s++)
    qf[s] = *(const bf16x8*)((const short*)Qh +
                             (size_t)(q0 + wm + lr) * 64 + s * 32 + lq * 8);

  f32x4 oacc[4] = {};
  float mrow[4], lrow[4];
  #pragma unroll
  for (int r = 0; r < 4; r++) { mrow[r] = -1e30f; lrow[r] = 0.f; }

  // prologue: stage K(0)
  for (int c = tid; c < 1024; c += 256)
    stage16(Kh + (size_t)(c >> 3) * 64 + (((c & 7) ^ ((c >> 3) & 7)) << 3),
            lK + c * 8);
  __syncthreads();  // K(0) visible

  for (int kt = 0; kt < nkt; kt++) {
    const int k0 = kt * 128;
    // ---- QK^T from lK ----
    f32x4 sacc[8] = {};
    __builtin_amdgcn_s_setprio(1);
    #pragma unroll
    for (int s = 0; s < 2; s++) {
      bf16x8 bf[8];
      #pragma unroll
      for (int ni = 0; ni < 8; ni++) {
        const int n = ni * 16 + lr;
        bf[ni] = *(const bf16x8*)(lK + n * 64 + (((s * 4 + lq) ^ (n & 7)) << 3));
      }
      #pragma unroll
      for (int ni = 0; ni < 8; ni++)
        sacc[ni] = __builtin_amdgcn_mfma_f32_16x16x32_bf16(
            qf[s], bf[ni], sacc[ni], 0, 0, 0);
    }
    __builtin_amdgcn_s_setprio(0);
    __syncthreads();  // barA: lK frag reads + prev PV's lp/lV reads done
    // ---- V(kt) + K(kt+1) DMA (latency hides under softmax below) ----
    for (int c = tid; c < 1024; c += 256)
      stage16(Vh + (size_t)(c >> 4) * 1024 + k0 + (((c & 15) ^ ((c >> 4) & 15)) << 3),
              lV + c * 8);
    if (kt + 1 < nkt) {
      const int k1 = k0 + 128;
      for (int c = tid; c < 1024; c += 256)
        stage16(Kh + (size_t)(k1 + (c >> 3)) * 64 + (((c & 7) ^ ((c >> 3) & 7)) << 3),
                lK + c * 8);
    }
    // ---- online softmax, base-2 domain ----
    const bool last = (kt == nkt - 1);
    #pragma unroll
    for (int r = 0; r < 4; r++) {
      const int grow = q0 + wm + lq * 4 + r;   // global q row
      float tmax = -1e30f;
      #pragma unroll
      for (int ni = 0; ni < 8; ni++) {
        float v = sacc[ni][r];
        if (last && (k0 + ni * 16 + lr) > grow) v = MASK2;
        sacc[ni][r] = v;
        tmax = fmaxf(tmax, v);
      }
      #pragma unroll
      for (int msk = 8; msk; msk >>= 1) tmax = fmaxf(tmax, __shfl_xor(tmax, msk));
      const float mn = fmaxf(mrow[r], tmax);
      const float al = __builtin_amdgcn_exp2f(mrow[r] - mn);
      float rs = 0.f;
      #pragma unroll
      for (int ni = 0; ni < 8; ni++) {
        const float pv = __builtin_amdgcn_exp2f(sacc[ni][r] - mn);
        sacc[ni][r] = pv;
        rs += pv;
      }
      #pragma unroll
      for (int msk = 8; msk; msk >>= 1) rs += __shfl_xor(rs, msk);
      mrow[r] = mn;
      lrow[r] = lrow[r] * al + rs;
      #pragma unroll
      for (int ni = 0; ni < 4; ni++) oacc[ni][r] *= al;
    }
    // P -> lp (padded pitch 130)
    #pragma unroll
    for (int r = 0; r < 4; r++) {
      const int row = wm + lq * 4 + r;
      #pragma unroll
      for (int ni = 0; ni < 8; ni++)
        lp[row * 130 + ni * 16 + lr] = f2bf_s(sacc[ni][r]);
    }
    __syncthreads();  // barB: V(kt)+K(kt+1) landed (vmcnt drain) + P visible
    // ---- PV from lp, lV ----
    __builtin_amdgcn_s_setprio(1);
    #pragma unroll
    for (int ks = 0; ks < 4; ks++) {
      bf16x8 pa, vb[4];
      pa = *(const bf16x8*)(lp + (wm + lr) * 130 + ks * 32 + lq * 8);
      #pragma unroll
      for (int ni = 0; ni < 4; ni++) {
        const int d = ni * 16 + lr;
        vb[ni] = *(const bf16x8*)(lV + d * 128 + (((ks * 4 + lq) ^ (d & 15)) << 3));
      }
      #pragma unroll
      for (int ni = 0; ni < 4; ni++)
        oacc[ni] = __builtin_amdgcn_mfma_f32_16x16x32_bf16(
            pa, vb[ni], oacc[ni], 0, 0, 0);
    }
    __builtin_amdgcn_s_setprio(0);
    // no barrier here: next QK reads lK (disjoint from lp/lV); barA covers reuse
  }

  const int b = hb >> 4, h = hb & 15;
  const float cv = (float)(1024 - nkt * 128);
  const float* tv = TV + ((size_t)hb * 8 + (j >> 1)) * 64;
  #pragma unroll
  for (int r = 0; r < 4; r++) {
    const int t = q0 + wm + lq * 4 + r;
    const float tail = __builtin_amdgcn_exp2f(MASK2 - mrow[r]);
    const float inv = 1.f / (lrow[r] + cv * tail);
    #pragma unroll
    for (int ni = 0; ni < 4; ni++) {
      const int d = ni * 16 + lr;
      y[((size_t)(b * 1024 + t) << 10) + h * 64 + d] =
          (oacc[ni][r] + tail * tv[d]) * inv;
    }
  }
}

// ======== 8-phase mlp1 helpers ========
template<int MH, int NH>
DEVINL void ph_read(const short* pa, const short* pb, int wr, int wc,
                    int lr, int lq, bf16x8 (&af)[4][2], bf16x8 (&bf)[2][2]) {
  if (NH == 0) {
    #pragma unroll
    for (int mi2 = 0; mi2 < 4; mi2++)
      #pragma unroll
      for (int ks = 0; ks < 2; ks++) {
        const int r = wr * 128 + MH * 64 + mi2 * 16 + lr;
        af[mi2][ks] = *(const bf16x8*)(pa + r * 64 + (((ks * 4 + lq) ^ (r & 7)) << 3));
      }
  }
  #pragma unroll
  for (int ni2 = 0; ni2 < 2; ni2++)
    #pragma unroll
    for (int ks = 0; ks < 2; ks++) {
      const int n = wc * 64 + NH * 32 + ni2 * 16 + lr;
      bf[ni2][ks] = *(const bf16x8*)(pb + n * 64 + (((ks * 4 + lq) ^ (n & 7)) << 3));
    }
}

DEVINL void ph_sync() {
  __builtin_amdgcn_s_barrier();
  asm volatile("s_waitcnt lgkmcnt(0)" ::: "memory");
  __builtin_amdgcn_sched_barrier(0);
}

template<int MH, int NH>
DEVINL void ph_mfma(f32x4 (&acc)[8][4], bf16x8 (&af)[4][2], bf16x8 (&bf)[2][2]) {
  __builtin_amdgcn_s_setprio(1);
  #pragma unroll
  for (int mi2 = 0; mi2 < 4; mi2++)
    #pragma unroll
    for (int ni2 = 0; ni2 < 2; ni2++)
      #pragma unroll
      for (int ks = 0; ks < 2; ks++)
        acc[MH * 4 + mi2][NH * 2 + ni2] = __builtin_amdgcn_mfma_f32_16x16x32_bf16(
            af[mi2][ks], bf[ni2][ks], acc[MH * 4 + mi2][NH * 2 + ni2], 0, 0, 0);
  __builtin_amdgcn_s_setprio(0);
  __builtin_amdgcn_s_barrier();
}

// ---- MLP1: h2[4096,1024] @ W1t[4096,1024]^T + b1 -> tanh-GELU -> G bf16 ----
// 256x256 tile, 512 thr, BK=64, 2 K-tiles/iter, 8-phase counted-vmcnt.
__global__ __launch_bounds__(512, 2) void k_gemm_mlp1(const __hip_bfloat16* __restrict__ h2,
                                                      const __hip_bfloat16* __restrict__ W1t,
                                                      const float* __restrict__ b1,
                                                      __hip_bfloat16* __restrict__ G) {
  __shared__ alignas(16) short smem[65536];  // 128KB: Ae Ao Be Bo x 16384
  short* Ae = smem;
  short* Ao = smem + 16384;
  short* Be = smem + 32768;
  short* Bo = smem + 49152;
  const int row0 = blockIdx.x * 256, col0 = blockIdx.y * 256;
  const int tid = threadIdx.x, lane = tid & 63, wid = tid >> 6;
  const int lr = lane & 15, lq = lane >> 4;
  const int wr = wid >> 2, wc = wid & 3;
  const __hip_bfloat16* A = h2 + (size_t)row0 * 1024;
  const __hip_bfloat16* Bt = W1t + (size_t)col0 * 1024;

  // stage one part (128 rows x 64 cols bf16) of a K-tile into dst buffer.
  // part h = rows with ((r>>SH)&1)==h (A: SH=6, B: SH=5). 2 loads/thread,
  // LDS dst linear in lane (base + lane*16B) as gload_lds requires.
  auto STG = [&](const __hip_bfloat16* src, int k0, int h, short* dst, int SH) {
    #pragma unroll
    for (int ii = 0; ii < 2; ii++) {
      const int f = tid + ii * 512;
      const int rp = f >> 3, P = f & 7;
      const int r = ((rp >> SH) << (SH + 1)) | (h << SH) | (rp & ((1 << SH) - 1));
      const int g = P ^ (r & 7);
      stage16(src + (size_t)r * 1024 + k0 + g * 8, dst + r * 64 + P * 8);
    }
  };

  f32x4 acc[8][4] = {};
  bf16x8 af[4][2], bf[2][2];

  // prologue: E0 (4 parts) + O0.A0, O0.B0; vmcnt(4) retires E0 (FIFO).
  STG(A, 0, 0, Ae, 6);  STG(Bt, 0, 0, Be, 5);
  STG(A, 0, 1, Ae, 6);  STG(Bt, 0, 1, Be, 5);
  STG(A, 64, 0, Ao, 6); STG(Bt, 64, 0, Bo, 5);
  asm volatile("s_waitcnt vmcnt(4)" ::: "memory");
  __syncthreads();

  for (int i = 0; i < 8; ++i) {
    const int kE1 = (i + 1) * 128;       // next even K-tile
    const int kO0 = i * 128 + 64;        // this iter's odd K-tile
    const int kO1 = kE1 + 64;            // next odd K-tile
    const bool more = (i + 1 < 8);
    // ph0: E q(0,0); stage O_i.A1
    ph_read<0, 0>(Ae, Be, wr, wc, lr, lq, af, bf);
    STG(A, kO0, 1, Ao, 6);
    ph_sync();
    ph_mfma<0, 0>(acc, af, bf);
    // ph1: E q(0,1); stage O_i.B1
    ph_read<0, 1>(Ae, Be, wr, wc, lr, lq, af, bf);
    STG(Bt, kO0, 1, Bo, 5);
    ph_sync();
    ph_mfma<0, 1>(acc, af, bf);
    // ph2: E q(1,0); stage E'.A0
    ph_read<1, 0>(Ae, Be, wr, wc, lr, lq, af, bf);
    if (more) STG(A, kE1, 0, Ae, 6);
    ph_sync();
    ph_mfma<1, 0>(acc, af, bf);
    // ph3: E q(1,1); stage E'.B0; vmcnt retires all O_i parts
    ph_read<1, 1>(Ae, Be, wr, wc, lr, lq, af, bf);
    if (more) {
      STG(Bt, kE1, 0, Be, 5);
      asm volatile("s_waitcnt vmcnt(4)" ::: "memory");
    } else {
      asm volatile("s_waitcnt vmcnt(0)" ::: "memory");
    }
    ph_sync();
    ph_mfma<1, 1>(acc, af, bf);
    // ph4: O q(0,0); stage E'.A1
    ph_read<0, 0>(Ao, Bo, wr, wc, lr, lq, af, bf);
    if (more) STG(A, kE1, 1, Ae, 6);
    ph_sync();
    ph_mfma<0, 0>(acc, af, bf);
    // ph5: O q(0,1); stage E'.B1
    ph_read<0, 1>(Ao, Bo, wr, wc, lr, lq, af, bf);
    if (more) STG(Bt, kE1, 1, Be, 5);
    ph_sync();
    ph_mfma<0, 1>(acc, af, bf);
    // ph6: O q(1,0); stage O'.A0
    ph_read<1, 0>(Ao, Bo, wr, wc, lr, lq, af, bf);
    if (more) STG(A, kO1, 0, Ao, 6);
    ph_sync();
    ph_mfma<1, 0>(acc, af, bf);
    // ph7: O q(1,1); stage O'.B0; vmcnt retires all E' parts
    ph_read<1, 1>(Ao, Bo, wr, wc, lr, lq, af, bf);
    if (more) {
      STG(Bt, kO1, 0, Bo, 5);
      asm volatile("s_waitcnt vmcnt(4)" ::: "memory");
    }
    ph_sync();
    ph_mfma<1, 1>(acc, af, bf);
  }

  // epilogue: tanh-GELU -> bf16 via 4x 64-row lc passes (lc = smem)
  short* lc = smem;
  #pragma unroll
  for (int pr = 0; pr < 4; pr++) {
    if ((wid >> 2) == (pr >> 1)) {
      const int mib = (pr & 1) * 4;
      #pragma unroll
      for (int mi2 = 0; mi2 < 4; mi2++)
        #pragma unroll
        for (int ni = 0; ni < 4; ni++)
          #pragma unroll
          for (int rr = 0; rr < 4; rr++) {
            const int rloc = mi2 * 16 + lq * 4 + rr;
            const int col = (wid & 3) * 64 + ni * 16 + lr;
            float v = acc[mib + mi2][ni][rr] + b1[col0 + col];
            const float u2 = fminf(v * (2.3022079f + 0.1029434f * v * v), 80.f);
            const float e = __builtin_amdgcn_exp2f(u2);
            v = v * e * __builtin_amdgcn_rcpf(e + 1.f);
            lc[rloc * 264 + col] = f2bf_s(v);
          }
    }
    __syncthreads();
    #pragma unroll
    for (int c = 0; c < 4; c++) {
      const int f = tid + 512 * c;       // 2048 chunks: 64 rows x 32 chunks
      const int r = f >> 5, cc = f & 31;
      float4 vv = *(const float4*)(lc + r * 264 + cc * 8);
      *(float4*)(G + ((size_t)(row0 + pr * 64 + r) << 12) + col0 + cc * 8) = vv;
    }
    __syncthreads();
  }
}

// ---- MLP2 split-K=2: out += G @ W2t^T (out pre-initialized with b2 + x2) ----
// 128x64 tile, grid(32,16,2): 1024 blocks, LDS 24KB. (R10 measured-best.)
__global__ __launch_bounds__(256) void k_gemm_mlp2(const __hip_bfloat16* __restrict__ G,
                                                   const __hip_bfloat16* __restrict__ W2t,
                                                   float* __restrict__ out) {
  __shared__ alignas(16) short smem[12288];
  short* la = smem;
  short* lb = smem + 8192;
  const int row0 = blockIdx.x * 128, col0 = blockIdx.y * 64;
  const int kOff = blockIdx.z * 2048;
  f32x4 acc[4][2] = {};
  gemm_core64<128, 64, 64, 32>(G + kOff, 4096, W2t + kOff, 4096, 2048,
                               row0, col0, acc, la, lb);
  const int lane = threadIdx.x & 63, wave = threadIdx.x >> 6;
  const int wm = (wave >> 1) * 64, wn = (wave & 1) * 32, lr = lane & 15, lq = lane >> 4;
  #pragma unroll
  for (int mi = 0; mi < 4; mi++)
    #pragma unroll
    for (int ni = 0; ni < 2; ni++)
      #pragma unroll
      for (int r = 0; r < 4; r++) {
        const int grow = row0 + wm + mi * 16 + lq * 4 + r;
        const int gcol = col0 + wn + ni * 16 + lr;
        atomicAdd(out + (((size_t)grow << 10) + gcol), acc[mi][ni][r]);
      }
}

extern "C" void kernel_launch(void* const* d_in, const int* in_sizes, int n_in,
                              void* d_out, int out_size, void* d_ws, size_t ws_size,
                              hipStream_t stream) {
  const float* x     = (const float*)d_in[0];
  const float* ln1_g = (const float*)d_in[1];
  const float* ln1_b = (const float*)d_in[2];
  const float* ln2_g = (const float*)d_in[3];
  const float* ln2_b = (const float*)d_in[4];
  const float* Wq    = (const float*)d_in[5];
  const float* bq    = (const float*)d_in[6];
  const float* Wk    = (const float*)d_in[7];
  const float* bk    = (const float*)d_in[8];
  const float* Wv    = (const float*)d_in[9];
  const float* bv    = (const float*)d_in[10];
  const float* W1    = (const float*)d_in[11];
  const float* b1    = (const float*)d_in[12];
  const float* W2    = (const float*)d_in[13];
  const float* b2    = (const float*)d_in[14];
  float* out = (float*)d_out;

  char* p = (char*)d_ws;
  auto alloc = [&](size_t bytes) { char* r = p; p += (bytes + 255) & ~(size_t)255; return r; };
  __hip_bfloat16* wqkv = (__hip_bfloat16*)alloc(3072 * 1024 * 2);
  __hip_bfloat16* w1t  = (__hip_bfloat16*)alloc(4096 * 1024 * 2);
  __hip_bfloat16* w2t  = (__hip_bfloat16*)alloc(1024 * 4096 * 2);
  float*          bqkv = (float*)alloc(3072 * 4);
  __hip_bfloat16* h1   = (__hip_bfloat16*)alloc(4096 * 1024 * 2);
  __hip_bfloat16* Qb   = (__hip_bfloat16*)alloc((size_t)64 * 65536 * 2);  // [64][1024][64]
  __hip_bfloat16* Kb   = (__hip_bfloat16*)alloc((size_t)64 * 65536 * 2);
  __hip_bfloat16* Vt   = (__hip_bfloat16*)alloc((size_t)64 * 65536 * 2);  // [64][64][1024]
  float*          TV   = (float*)alloc((size_t)64 * 8 * 64 * 4);
  float*          yb   = (float*)alloc((size_t)4096 * 1024 * 4);
  __hip_bfloat16* h2   = (__hip_bfloat16*)alloc(4096 * 1024 * 2);
  __hip_bfloat16* G    = (__hip_bfloat16*)alloc((size_t)4096 * 4096 * 2);
  (void)ws_size; (void)in_sizes; (void)n_in; (void)out_size;

  const dim3 b256(256), bt(32, 8);
  k_tcvt3<<<dim3(32, 32, 3), bt, 0, stream>>>(Wq, Wk, Wv, wqkv);
  k_tcvt<<<dim3(128, 32), bt, 0, stream>>>(W1, w1t, 1024, 4096, 0, 1024);
  k_tcvt<<<dim3(32, 128), bt, 0, stream>>>(W2, w2t, 4096, 1024, 0, 4096);
  k_pack_bias<<<12, b256, 0, stream>>>(bq, bk, bv, bqkv);

  k_ln<<<4096, b256, 0, stream>>>(x, nullptr, ln1_g, ln1_b, h1, nullptr, nullptr);
  k_gemm_qkv<<<dim3(32, 24), b256, 0, stream>>>(h1, wqkv, bqkv, Qb, Kb, Vt);
  k_tailv<<<64, b256, 0, stream>>>(Vt, TV);
  k_attn<<<dim3(16, 64), b256, 0, stream>>>(Qb, Kb, Vt, TV, yb);

  k_ln<<<4096, b256, 0, stream>>>(x, yb, ln2_g, ln2_b, h2, b2, out);
  k_gemm_mlp1<<<dim3(16, 16), dim3(512), 0, stream>>>(h2, w1t, b1, G);
  k_gemm_mlp2<<<dim3(32, 16, 2), b256, 0, stream>>>(G, w2t, out);
}

// Round 10
// 328.394 us; speedup vs baseline: 1.0984x; 1.0038x over previous
//
#include <hip/hip_runtime.h>
#include <hip/hip_bf16.h>
#include <math.h>

// Transformer block (pre-LN attn + MLP), B=4 T=1024 H=1024 K=16 HD=64.
// R20: mlp2 ported to the session-validated counted-vmcnt phase schedule
// (R19 proved it on mlp1: +6-10%, 660 TF-equiv). mlp2 geometry: 256x128
// tile, split-K=2, grid(16,8,2)=256 blocks=1/CU, 512 thr (8 waves 4Mx2N,
// 64x64 out each), BK=64, 2 K-tiles/iter, 4 phases/iter x 16 MFMA.
// B-frags read once per K-tile (cached across MH phases).
// Staging ledger (FIFO-audited):
//   A-half h = rows bit5==h (MH0 reads lo, MH1 reads hi). B unsplit.
//   phE0: read E.MH0+B; stage Ao_i.hi;       vmcnt(2)
//   phE1: read E.MH1;   stage Be',Ae'.lo;    --
//   phO0: read O.MH0+B; stage Ae'.hi;        vmcnt(6)
//   phO1: read O.MH1;   stage Bo',Ao'.lo;    vmcnt(4)
//   Steady-state in-flight at each vmcnt: 6/8/10 -> retire counts leave
//   exactly the newest stages flying; prologue replicates the FIFO
//   [Be,Ae.lo][Ae.hi][Bo,Ao.lo] + vmcnt(4) so loop constants are uniform;
//   tail iters guard stages and use more?N:0. WAR guarded by each phase's
//   closing barrier (issues only after all waves' lgkmcnt(0) retired reads).
// mlp1: R19 8-phase 256x256 (unchanged). All other kernels unchanged.
// Attention: fused flash-style, 64-row Q-tiles, separate lK/lV, 2 barriers
// per kt, K(kt+1) prefetch hidden under softmax, setprio on MFMA clusters;
// masked logits FILLED with 1e-9; fully-masked K-tiles contribute
// exp(1e-9-m)*suffixV analytically (TV precomputed).

typedef __attribute__((ext_vector_type(8))) short bf16x8;
typedef __attribute__((ext_vector_type(4))) float f32x4;

#define DEVINL __device__ __forceinline__

#define LOG2E_SCALE 0.18033688f      /* 0.125 * log2(e) */
#define MASK2 1.4426950408889634e-9f /* 1e-9 * log2(e) */

DEVINL void stage16(const __hip_bfloat16* g, short* l) {
  __builtin_amdgcn_global_load_lds(
      (const __attribute__((address_space(1))) unsigned int*)g,
      (__attribute__((address_space(3))) unsigned int*)l, 16, 0, 0);
}

DEVINL float bf2f(short u) {
  unsigned x = ((unsigned)(unsigned short)u) << 16;
  float f; __builtin_memcpy(&f, &x, 4); return f;
}

DEVINL short f2bf_s(float f) {
  __hip_bfloat16 h = __float2bfloat16(f);
  short s; __builtin_memcpy(&s, &h, 2); return s;
}

DEVINL float block_sum(float v, float* sb) {
  #pragma unroll
  for (int o = 32; o; o >>= 1) v += __shfl_down(v, o);
  const int lane = threadIdx.x & 63, w = threadIdx.x >> 6;
  if (lane == 0) sb[w] = v;
  __syncthreads();
  float r = sb[0] + sb[1] + sb[2] + sb[3];
  __syncthreads();
  return r;
}

// ---- GEMM core BK=64: C[M,N] += A[M,Kd] * Bt[N,Kd]^T, 256 threads ----
template<int BM, int BN, int WM, int WN>
DEVINL void gemm_core64(const __hip_bfloat16* __restrict__ A, int lda,
                        const __hip_bfloat16* __restrict__ Bt, int ldb,
                        int Kd, int row0, int col0,
                        f32x4 (&acc)[WM/16][WN/16],
                        short* lds_a, short* lds_b) {
  constexpr int MI = WM / 16, NI = WN / 16, WNC = BN / WN;
  constexpr int CA = BM * 8, CB = BN * 8;  // 16B chunks per tile
  const int tid = threadIdx.x;
  const int lane = tid & 63, wave = tid >> 6;
  const int wm = (wave / WNC) * WM, wn = (wave % WNC) * WN;
  const int lr = lane & 15, lq = lane >> 4;
  for (int k0 = 0; k0 < Kd; k0 += 64) {
    #pragma unroll
    for (int c = tid; c < CA; c += 256) {
      const int r = c >> 3, kc = ((c & 7) ^ (r & 7)) << 3;
      stage16(A + (size_t)(row0 + r) * lda + k0 + kc, lds_a + c * 8);
    }
    #pragma unroll
    for (int c = tid; c < CB; c += 256) {
      const int r = c >> 3, kc = ((c & 7) ^ (r & 7)) << 3;
      stage16(Bt + (size_t)(col0 + r) * ldb + k0 + kc, lds_b + c * 8);
    }
    __syncthreads();
    #pragma unroll
    for (int s = 0; s < 2; s++) {
      bf16x8 af[MI], bfr[NI];
      #pragma unroll
      for (int mi = 0; mi < MI; mi++) {
        const int m = wm + mi * 16 + lr;
        af[mi] = *(const bf16x8*)(lds_a + m * 64 + (((s * 4 + lq) ^ (m & 7)) << 3));
      }
      #pragma unroll
      for (int ni = 0; ni < NI; ni++) {
        const int n = wn + ni * 16 + lr;
        bfr[ni] = *(const bf16x8*)(lds_b + n * 64 + (((s * 4 + lq) ^ (n & 7)) << 3));
      }
      #pragma unroll
      for (int mi = 0; mi < MI; mi++)
        #pragma unroll
        for (int ni = 0; ni < NI; ni++)
          acc[mi][ni] = __builtin_amdgcn_mfma_f32_16x16x32_bf16(
              af[mi], bfr[ni], acc[mi][ni], 0, 0, 0);
    }
    __syncthreads();
  }
}

// ---- transpose + f32->bf16: src[R][C] -> dst[(c+off)][r], dst pitch P ----
__global__ __launch_bounds__(256) void k_tcvt(const float* __restrict__ src,
                                              __hip_bfloat16* __restrict__ dst,
                                              int R, int C, int dstOff, int dstPitch) {
  __shared__ float tile[32][33];
  const int c0 = blockIdx.x * 32, r0 = blockIdx.y * 32;
  const int tx = threadIdx.x, ty = threadIdx.y;  // (32,8)
  #pragma unroll
  for (int i = 0; i < 32; i += 8)
    tile[ty + i][tx] = src[(size_t)(r0 + ty + i) * C + c0 + tx];
  __syncthreads();
  #pragma unroll
  for (int i = 0; i < 32; i += 8)
    dst[(size_t)(c0 + ty + i + dstOff) * dstPitch + r0 + tx] =
        __float2bfloat16(tile[tx][ty + i]);
}

// fused Wq/Wk/Wv transpose (z picks source; all 1024x1024, dst pitch 1024)
__global__ __launch_bounds__(256) void k_tcvt3(const float* __restrict__ Wq,
                                               const float* __restrict__ Wk,
                                               const float* __restrict__ Wv,
                                               __hip_bfloat16* __restrict__ dst) {
  __shared__ float tile[32][33];
  const float* src = blockIdx.z == 0 ? Wq : (blockIdx.z == 1 ? Wk : Wv);
  const int dstOff = blockIdx.z << 10;
  const int c0 = blockIdx.x * 32, r0 = blockIdx.y * 32;
  const int tx = threadIdx.x, ty = threadIdx.y;
  #pragma unroll
  for (int i = 0; i < 32; i += 8)
    tile[ty + i][tx] = src[(size_t)(r0 + ty + i) * 1024 + c0 + tx];
  __syncthreads();
  #pragma unroll
  for (int i = 0; i < 32; i += 8)
    dst[(size_t)(c0 + ty + i + dstOff) * 1024 + r0 + tx] =
        __float2bfloat16(tile[tx][ty + i]);
}

__global__ __launch_bounds__(256) void k_pack_bias(const float* __restrict__ bq,
                                                   const float* __restrict__ bk,
                                                   const float* __restrict__ bv,
                                                   float* __restrict__ o) {
  const int i = blockIdx.x * 256 + threadIdx.x;
  if (i < 3072)
    o[i] = i < 1024 ? bq[i] : (i < 2048 ? bk[i - 1024] : bv[i - 2048]);
}

// ---- LayerNorm (+residual add; optionally init out = x2 + b2) ----
__global__ __launch_bounds__(256) void k_ln(const float* __restrict__ x,
                                            const float* __restrict__ y,
                                            const float* __restrict__ g,
                                            const float* __restrict__ bb,
                                            __hip_bfloat16* __restrict__ o,
                                            const float* __restrict__ badd,
                                            float* __restrict__ oinit) {
  __shared__ float sb[4];
  const int t = threadIdx.x;
  const size_t base = (size_t)blockIdx.x * 1024 + t * 4;
  const int c = t * 4;
  float4 xv = *(const float4*)(x + base);
  if (y) {
    float4 yv = *(const float4*)(y + base);
    xv.x += yv.x; xv.y += yv.y; xv.z += yv.z; xv.w += yv.w;
    float4 ov;
    ov.x = xv.x + badd[c + 0]; ov.y = xv.y + badd[c + 1];
    ov.z = xv.z + badd[c + 2]; ov.w = xv.w + badd[c + 3];
    *(float4*)(oinit + base) = ov;
  }
  const float mu = block_sum(xv.x + xv.y + xv.z + xv.w, sb) * (1.f / 1024.f);
  const float dx = xv.x - mu, dy = xv.y - mu, dz = xv.z - mu, dw = xv.w - mu;
  const float var = block_sum(dx * dx + dy * dy + dz * dz + dw * dw, sb) * (1.f / 1024.f);
  const float rs = rsqrtf(var + 1e-5f);
  o[base + 0] = __float2bfloat16(dx * rs * g[c + 0] + bb[c + 0]);
  o[base + 1] = __float2bfloat16(dy * rs * g[c + 1] + bb[c + 1]);
  o[base + 2] = __float2bfloat16(dz * rs * g[c + 2] + bb[c + 2]);
  o[base + 3] = __float2bfloat16(dw * rs * g[c + 3] + bb[c + 3]);
}

// ---- QKV GEMM: h1[4096,1024] @ Wqkv_t[3072,1024]^T -> Q/K [hb][t][d], Vt [hb][d][t]
// Q is PRE-SCALED by 0.125*log2e so attention logits are base-2.
__global__ __launch_bounds__(256) void k_gemm_qkv(
    const __hip_bfloat16* __restrict__ h1, const __hip_bfloat16* __restrict__ Wt,
    const float* __restrict__ bqkv, __hip_bfloat16* __restrict__ Q,
    __hip_bfloat16* __restrict__ K, __hip_bfloat16* __restrict__ Vt) {
  __shared__ alignas(16) short smem[16896];   // la(8192) lb(8192) | lc(16896)
  short* la = smem;
  short* lb = smem + 8192;
  short* lc = smem;
  const int row0 = blockIdx.x * 128, col0 = blockIdx.y * 128;
  f32x4 acc[4][4] = {};
  gemm_core64<128, 128, 64, 64>(h1, 1024, Wt, 1024, 1024, row0, col0, acc, la, lb);
  const int tid = threadIdx.x, lane = tid & 63, wave = tid >> 6;
  const int wm = (wave >> 1) * 64, wn = (wave & 1) * 64, lr = lane & 15, lq = lane >> 4;
  const int which = col0 >> 10;                 // uniform: 0=Q 1=K 2=V
  const int h0 = (col0 & 1023) >> 6;
  const int b = row0 >> 10, t0 = row0 & 1023;
  if (which < 2) {
    const float qs = (which == 0) ? LOG2E_SCALE : 1.f;
    #pragma unroll
    for (int mi = 0; mi < 4; mi++)
      #pragma unroll
      for (int ni = 0; ni < 4; ni++)
        #pragma unroll
        for (int r = 0; r < 4; r++) {
          const int row = wm + mi * 16 + lq * 4 + r;
          const int col = wn + ni * 16 + lr;
          lc[row * 132 + col] = f2bf_s((acc[mi][ni][r] + bqkv[col0 + col]) * qs);
        }
    __syncthreads();
    __hip_bfloat16* O = which == 0 ? Q : K;
    #pragma unroll
    for (int c = 0; c < 8; c++) {
      const int f = tid + 256 * c;              // flat 16B-chunk id
      const int r = f >> 4, cc = f & 15;
      const int col = cc * 8;
      const int head = h0 + (col >> 6), d = col & 63;
      float4 vv = *(const float4*)(lc + r * 132 + col);
      *(float4*)(O + (((size_t)(b * 16 + head)) << 16) + (t0 + r) * 64 + d) = vv;
    }
  } else {
    // transposed epilogue: lc[col][row]
    #pragma unroll
    for (int mi = 0; mi < 4; mi++)
      #pragma unroll
      for (int ni = 0; ni < 4; ni++)
        #pragma unroll
        for (int r = 0; r < 4; r++) {
          const int row = wm + mi * 16 + lq * 4 + r;
          const int col = wn + ni * 16 + lr;
          lc[col * 132 + row] = f2bf_s(acc[mi][ni][r] + bqkv[col0 + col]);
        }
    __syncthreads();
    #pragma unroll
    for (int c = 0; c < 8; c++) {
      const int f = tid + 256 * c;
      const int dl = f >> 4, tc = f & 15;       // local d 0..127, t-chunk
      const int head = h0 + (dl >> 6), d = dl & 63;
      float4 vv = *(const float4*)(lc + dl * 132 + tc * 8);
      *(float4*)(Vt + (((size_t)(b * 16 + head)) << 16) + (size_t)d * 1024 +
                 t0 + tc * 8) = vv;
    }
  }
}

// ---- tail V sums: TV[hb][qt][d] = sum_{t >= (qt+1)*128} Vt[hb][d][t] ----
__global__ __launch_bounds__(256) void k_tailv(const __hip_bfloat16* __restrict__ Vt,
                                               float* __restrict__ TV) {
  __shared__ float ts[8][64];
  const int hb = blockIdx.x, tid = threadIdx.x;
  const __hip_bfloat16* Vh = Vt + ((size_t)hb << 16);
  for (int w = tid; w < 512; w += 256) {
    const int kt = w >> 6, d = w & 63;
    const short* p = (const short*)(Vh + (size_t)d * 1024 + kt * 128);
    float s = 0.f;
    for (int j = 0; j < 128; j += 8) {
      bf16x8 v = *(const bf16x8*)(p + j);
      #pragma unroll
      for (int e = 0; e < 8; e++) s += bf2f(v[e]);
    }
    ts[kt][d] = s;
  }
  __syncthreads();
  for (int w = tid; w < 512; w += 256) {
    const int qt = w >> 6, d = w & 63;
    float s = 0.f;
    for (int kt = qt + 1; kt < 8; kt++) s += ts[kt][d];
    TV[((size_t)hb * 8 + qt) * 64 + d] = s;
  }
}

// ---- fused attention: one block = (64 q-rows, one head); 1024 blocks ----
// Separate lK/lV buffers; 2 barriers per kt; K(kt+1) prefetched alongside
// V(kt) so its latency hides under softmax+PV; setprio on MFMA clusters.
__global__ __launch_bounds__(256, 3) void k_attn(
    const __hip_bfloat16* __restrict__ Q, const __hip_bfloat16* __restrict__ K,
    const __hip_bfloat16* __restrict__ Vt, const float* __restrict__ TV,
    float* __restrict__ y) {
  __shared__ short lp[64 * 130];   // P-tile (padded)
  __shared__ short lK[128 * 64];   // K-tile, swizzled
  __shared__ short lV[128 * 64];   // V^T-tile, swizzled
  const int hb = blockIdx.y;
  const int j = (blockIdx.y & 32) ? (15 - (int)blockIdx.x) : (int)blockIdx.x;
  const int q0 = j * 64;
  const int nkt = (j >> 1) + 1;    // K-tiles (128 wide) to compute
  const int tid = threadIdx.x, lane = tid & 63, wave = tid >> 6;
  const int lr = lane & 15, lq = lane >> 4;
  const int wm = wave * 16;        // wave owns q-rows [q0+wm, q0+wm+16)
  const __hip_bfloat16* Qh = Q + ((size_t)hb << 16);
  const __hip_bfloat16* Kh = K + ((size_t)hb << 16);
  const __hip_bfloat16* Vh = Vt + ((size_t)hb << 16);

  // Q A-frags: direct global loads (rows q0+wm+lr, cols s*32+lq*8)
  bf16x8 qf[2];
  #pragma unroll
  for (int s = 0; s < 2; s++)
    qf[s] = *(const bf16x8*)((const short*)Qh +
                             (size_t)(q0 + wm + lr) * 64 + s * 32 + lq * 8);

  f32x4 oacc[4] = {};
  float mrow[4], lrow[4];
  #pragma unroll
  for (int r = 0; r < 4; r++) { mrow[r] = -1e30f; lrow[r] = 0.f; }

  // prologue: stage K(0)
  for (int c = tid; c < 1024; c += 256)
    stage16(Kh + (size_t)(c >> 3) * 64 + (((c & 7) ^ ((c >> 3) & 7)) << 3),
            lK + c * 8);
  __syncthreads();  // K(0) visible

  for (int kt = 0; kt < nkt; kt++) {
    const int k0 = kt * 128;
    // ---- QK^T from lK ----
    f32x4 sacc[8] = {};
    __builtin_amdgcn_s_setprio(1);
    #pragma unroll
    for (int s = 0; s < 2; s++) {
      bf16x8 bf[8];
      #pragma unroll
      for (int ni = 0; ni < 8; ni++) {
        const int n = ni * 16 + lr;
        bf[ni] = *(const bf16x8*)(lK + n * 64 + (((s * 4 + lq) ^ (n & 7)) << 3));
      }
      #pragma unroll
      for (int ni = 0; ni < 8; ni++)
        sacc[ni] = __builtin_amdgcn_mfma_f32_16x16x32_bf16(
            qf[s], bf[ni], sacc[ni], 0, 0, 0);
    }
    __builtin_amdgcn_s_setprio(0);
    __syncthreads();  // barA: lK frag reads + prev PV's lp/lV reads done
    // ---- V(kt) + K(kt+1) DMA (latency hides under softmax below) ----
    for (int c = tid; c < 1024; c += 256)
      stage16(Vh + (size_t)(c >> 4) * 1024 + k0 + (((c & 15) ^ ((c >> 4) & 15)) << 3),
              lV + c * 8);
    if (kt + 1 < nkt) {
      const int k1 = k0 + 128;
      for (int c = tid; c < 1024; c += 256)
        stage16(Kh + (size_t)(k1 + (c >> 3)) * 64 + (((c & 7) ^ ((c >> 3) & 7)) << 3),
                lK + c * 8);
    }
    // ---- online softmax, base-2 domain ----
    const bool last = (kt == nkt - 1);
    #pragma unroll
    for (int r = 0; r < 4; r++) {
      const int grow = q0 + wm + lq * 4 + r;   // global q row
      float tmax = -1e30f;
      #pragma unroll
      for (int ni = 0; ni < 8; ni++) {
        float v = sacc[ni][r];
        if (last && (k0 + ni * 16 + lr) > grow) v = MASK2;
        sacc[ni][r] = v;
        tmax = fmaxf(tmax, v);
      }
      #pragma unroll
      for (int msk = 8; msk; msk >>= 1) tmax = fmaxf(tmax, __shfl_xor(tmax, msk));
      const float mn = fmaxf(mrow[r], tmax);
      const float al = __builtin_amdgcn_exp2f(mrow[r] - mn);
      float rs = 0.f;
      #pragma unroll
      for (int ni = 0; ni < 8; ni++) {
        const float pv = __builtin_amdgcn_exp2f(sacc[ni][r] - mn);
        sacc[ni][r] = pv;
        rs += pv;
      }
      #pragma unroll
      for (int msk = 8; msk; msk >>= 1) rs += __shfl_xor(rs, msk);
      mrow[r] = mn;
      lrow[r] = lrow[r] * al + rs;
      #pragma unroll
      for (int ni = 0; ni < 4; ni++) oacc[ni][r] *= al;
    }
    // P -> lp (padded pitch 130)
    #pragma unroll
    for (int r = 0; r < 4; r++) {
      const int row = wm + lq * 4 + r;
      #pragma unroll
      for (int ni = 0; ni < 8; ni++)
        lp[row * 130 + ni * 16 + lr] = f2bf_s(sacc[ni][r]);
    }
    __syncthreads();  // barB: V(kt)+K(kt+1) landed (vmcnt drain) + P visible
    // ---- PV from lp, lV ----
    __builtin_amdgcn_s_setprio(1);
    #pragma unroll
    for (int ks = 0; ks < 4; ks++) {
      bf16x8 pa, vb[4];
      pa = *(const bf16x8*)(lp + (wm + lr) * 130 + ks * 32 + lq * 8);
      #pragma unroll
      for (int ni = 0; ni < 4; ni++) {
        const int d = ni * 16 + lr;
        vb[ni] = *(const bf16x8*)(lV + d * 128 + (((ks * 4 + lq) ^ (d & 15)) << 3));
      }
      #pragma unroll
      for (int ni = 0; ni < 4; ni++)
        oacc[ni] = __builtin_amdgcn_mfma_f32_16x16x32_bf16(
            pa, vb[ni], oacc[ni], 0, 0, 0);
    }
    __builtin_amdgcn_s_setprio(0);
    // no barrier here: next QK reads lK (disjoint from lp/lV); barA covers reuse
  }

  const int b = hb >> 4, h = hb & 15;
  const float cv = (float)(1024 - nkt * 128);
  const float* tv = TV + ((size_t)hb * 8 + (j >> 1)) * 64;
  #pragma unroll
  for (int r = 0; r < 4; r++) {
    const int t = q0 + wm + lq * 4 + r;
    const float tail = __builtin_amdgcn_exp2f(MASK2 - mrow[r]);
    const float inv = 1.f / (lrow[r] + cv * tail);
    #pragma unroll
    for (int ni = 0; ni < 4; ni++) {
      const int d = ni * 16 + lr;
      y[((size_t)(b * 1024 + t) << 10) + h * 64 + d] =
          (oacc[ni][r] + tail * tv[d]) * inv;
    }
  }
}

// ======== 8-phase mlp1 helpers ========
template<int MH, int NH>
DEVINL void ph_read(const short* pa, const short* pb, int wr, int wc,
                    int lr, int lq, bf16x8 (&af)[4][2], bf16x8 (&bf)[2][2]) {
  if (NH == 0) {
    #pragma unroll
    for (int mi2 = 0; mi2 < 4; mi2++)
      #pragma unroll
      for (int ks = 0; ks < 2; ks++) {
        const int r = wr * 128 + MH * 64 + mi2 * 16 + lr;
        af[mi2][ks] = *(const bf16x8*)(pa + r * 64 + (((ks * 4 + lq) ^ (r & 7)) << 3));
      }
  }
  #pragma unroll
  for (int ni2 = 0; ni2 < 2; ni2++)
    #pragma unroll
    for (int ks = 0; ks < 2; ks++) {
      const int n = wc * 64 + NH * 32 + ni2 * 16 + lr;
      bf[ni2][ks] = *(const bf16x8*)(pb + n * 64 + (((ks * 4 + lq) ^ (n & 7)) << 3));
    }
}

DEVINL void ph_sync() {
  __builtin_amdgcn_s_barrier();
  asm volatile("s_waitcnt lgkmcnt(0)" ::: "memory");
  __builtin_amdgcn_sched_barrier(0);
}

template<int MH, int NH>
DEVINL void ph_mfma(f32x4 (&acc)[8][4], bf16x8 (&af)[4][2], bf16x8 (&bf)[2][2]) {
  __builtin_amdgcn_s_setprio(1);
  #pragma unroll
  for (int mi2 = 0; mi2 < 4; mi2++)
    #pragma unroll
    for (int ni2 = 0; ni2 < 2; ni2++)
      #pragma unroll
      for (int ks = 0; ks < 2; ks++)
        acc[MH * 4 + mi2][NH * 2 + ni2] = __builtin_amdgcn_mfma_f32_16x16x32_bf16(
            af[mi2][ks], bf[ni2][ks], acc[MH * 4 + mi2][NH * 2 + ni2], 0, 0, 0);
  __builtin_amdgcn_s_setprio(0);
  __builtin_amdgcn_s_barrier();
}

// ---- MLP1: h2[4096,1024] @ W1t[4096,1024]^T + b1 -> tanh-GELU -> G bf16 ----
// 256x256 tile, 512 thr, BK=64, 2 K-tiles/iter, 8-phase counted-vmcnt.
__global__ __launch_bounds__(512, 2) void k_gemm_mlp1(const __hip_bfloat16* __restrict__ h2,
                                                      const __hip_bfloat16* __restrict__ W1t,
                                                      const float* __restrict__ b1,
                                                      __hip_bfloat16* __restrict__ G) {
  __shared__ alignas(16) short smem[65536];  // 128KB: Ae Ao Be Bo x 16384
  short* Ae = smem;
  short* Ao = smem + 16384;
  short* Be = smem + 32768;
  short* Bo = smem + 49152;
  const int row0 = blockIdx.x * 256, col0 = blockIdx.y * 256;
  const int tid = threadIdx.x, lane = tid & 63, wid = tid >> 6;
  const int lr = lane & 15, lq = lane >> 4;
  const int wr = wid >> 2, wc = wid & 3;
  const __hip_bfloat16* A = h2 + (size_t)row0 * 1024;
  const __hip_bfloat16* Bt = W1t + (size_t)col0 * 1024;

  // stage one part (128 rows x 64 cols bf16) of a K-tile into dst buffer.
  // part h = rows with ((r>>SH)&1)==h (A: SH=6, B: SH=5). 2 loads/thread,
  // LDS dst linear in lane (base + lane*16B) as gload_lds requires.
  auto STG = [&](const __hip_bfloat16* src, int k0, int h, short* dst, int SH) {
    #pragma unroll
    for (int ii = 0; ii < 2; ii++) {
      const int f = tid + ii * 512;
      const int rp = f >> 3, P = f & 7;
      const int r = ((rp >> SH) << (SH + 1)) | (h << SH) | (rp & ((1 << SH) - 1));
      const int g = P ^ (r & 7);
      stage16(src + (size_t)r * 1024 + k0 + g * 8, dst + r * 64 + P * 8);
    }
  };

  f32x4 acc[8][4] = {};
  bf16x8 af[4][2], bf[2][2];

  // prologue: E0 (4 parts) + O0.A0, O0.B0; vmcnt(4) retires E0 (FIFO).
  STG(A, 0, 0, Ae, 6);  STG(Bt, 0, 0, Be, 5);
  STG(A, 0, 1, Ae, 6);  STG(Bt, 0, 1, Be, 5);
  STG(A, 64, 0, Ao, 6); STG(Bt, 64, 0, Bo, 5);
  asm volatile("s_waitcnt vmcnt(4)" ::: "memory");
  __syncthreads();

  for (int i = 0; i < 8; ++i) {
    const int kE1 = (i + 1) * 128;       // next even K-tile
    const int kO0 = i * 128 + 64;        // this iter's odd K-tile
    const int kO1 = kE1 + 64;            // next odd K-tile
    const bool more = (i + 1 < 8);
    // ph0: E q(0,0); stage O_i.A1
    ph_read<0, 0>(Ae, Be, wr, wc, lr, lq, af, bf);
    STG(A, kO0, 1, Ao, 6);
    ph_sync();
    ph_mfma<0, 0>(acc, af, bf);
    // ph1: E q(0,1); stage O_i.B1
    ph_read<0, 1>(Ae, Be, wr, wc, lr, lq, af, bf);
    STG(Bt, kO0, 1, Bo, 5);
    ph_sync();
    ph_mfma<0, 1>(acc, af, bf);
    // ph2: E q(1,0); stage E'.A0
    ph_read<1, 0>(Ae, Be, wr, wc, lr, lq, af, bf);
    if (more) STG(A, kE1, 0, Ae, 6);
    ph_sync();
    ph_mfma<1, 0>(acc, af, bf);
    // ph3: E q(1,1); stage E'.B0; vmcnt retires all O_i parts
    ph_read<1, 1>(Ae, Be, wr, wc, lr, lq, af, bf);
    if (more) {
      STG(Bt, kE1, 0, Be, 5);
      asm volatile("s_waitcnt vmcnt(4)" ::: "memory");
    } else {
      asm volatile("s_waitcnt vmcnt(0)" ::: "memory");
    }
    ph_sync();
    ph_mfma<1, 1>(acc, af, bf);
    // ph4: O q(0,0); stage E'.A1
    ph_read<0, 0>(Ao, Bo, wr, wc, lr, lq, af, bf);
    if (more) STG(A, kE1, 1, Ae, 6);
    ph_sync();
    ph_mfma<0, 0>(acc, af, bf);
    // ph5: O q(0,1); stage E'.B1
    ph_read<0, 1>(Ao, Bo, wr, wc, lr, lq, af, bf);
    if (more) STG(Bt, kE1, 1, Be, 5);
    ph_sync();
    ph_mfma<0, 1>(acc, af, bf);
    // ph6: O q(1,0); stage O'.A0
    ph_read<1, 0>(Ao, Bo, wr, wc, lr, lq, af, bf);
    if (more) STG(A, kO1, 0, Ao, 6);
    ph_sync();
    ph_mfma<1, 0>(acc, af, bf);
    // ph7: O q(1,1); stage O'.B0; vmcnt retires all E' parts
    ph_read<1, 1>(Ao, Bo, wr, wc, lr, lq, af, bf);
    if (more) {
      STG(Bt, kO1, 0, Bo, 5);
      asm volatile("s_waitcnt vmcnt(4)" ::: "memory");
    }
    ph_sync();
    ph_mfma<1, 1>(acc, af, bf);
  }

  // epilogue: tanh-GELU -> bf16 via 4x 64-row lc passes (lc = smem)
  short* lc = smem;
  #pragma unroll
  for (int pr = 0; pr < 4; pr++) {
    if ((wid >> 2) == (pr >> 1)) {
      const int mib = (pr & 1) * 4;
      #pragma unroll
      for (int mi2 = 0; mi2 < 4; mi2++)
        #pragma unroll
        for (int ni = 0; ni < 4; ni++)
          #pragma unroll
          for (int rr = 0; rr < 4; rr++) {
            const int rloc = mi2 * 16 + lq * 4 + rr;
            const int col = (wid & 3) * 64 + ni * 16 + lr;
            float v = acc[mib + mi2][ni][rr] + b1[col0 + col];
            const float u2 = fminf(v * (2.3022079f + 0.1029434f * v * v), 80.f);
            const float e = __builtin_amdgcn_exp2f(u2);
            v = v * e * __builtin_amdgcn_rcpf(e + 1.f);
            lc[rloc * 264 + col] = f2bf_s(v);
          }
    }
    __syncthreads();
    #pragma unroll
    for (int c = 0; c < 4; c++) {
      const int f = tid + 512 * c;       // 2048 chunks: 64 rows x 32 chunks
      const int r = f >> 5, cc = f & 31;
      float4 vv = *(const float4*)(lc + r * 264 + cc * 8);
      *(float4*)(G + ((size_t)(row0 + pr * 64 + r) << 12) + col0 + cc * 8) = vv;
    }
    __syncthreads();
  }
}

// ======== 4-phase mlp2 MFMA helper (16 MFMA, compile-time MH) ========
template<int MH>
DEVINL void mm2(f32x4 (&acc)[4][4], bf16x8 (&af)[2][2], bf16x8 (&bf)[4][2]) {
  __builtin_amdgcn_s_setprio(1);
  #pragma unroll
  for (int mi2 = 0; mi2 < 2; mi2++)
    #pragma unroll
    for (int ni = 0; ni < 4; ni++)
      #pragma unroll
      for (int ks = 0; ks < 2; ks++)
        acc[MH * 2 + mi2][ni] = __builtin_amdgcn_mfma_f32_16x16x32_bf16(
            af[mi2][ks], bf[ni][ks], acc[MH * 2 + mi2][ni], 0, 0, 0);
  __builtin_amdgcn_s_setprio(0);
  __builtin_amdgcn_s_barrier();
}

// ---- MLP2: out += G @ W2t^T, split-K=2, counted-vmcnt 4-phase ----
// 256x128 tile, grid(16,8,2)=256 blocks=1/CU, 512 thr (8 waves 4Mx2N).
// BK=64, 2 K-tiles/iter (E,O), 4 phases x 16 MFMA; bf cached across MH.
// Ledger: phE0{stage Ao_i.hi; vmcnt(2)} phE1{Be',Ae'.lo} phO0{Ae'.hi;
// vmcnt(6)} phO1{Bo',Ao'.lo; vmcnt(4)}. Prologue replicates steady FIFO.
__global__ __launch_bounds__(512, 2) void k_gemm_mlp2(const __hip_bfloat16* __restrict__ G,
                                                      const __hip_bfloat16* __restrict__ W2t,
                                                      float* __restrict__ out) {
  __shared__ alignas(16) short smem[49152];  // 96KB: Ae(16K) Ao(16K) Be(8K) Bo(8K)
  short* Ae = smem;
  short* Ao = smem + 16384;
  short* Be = smem + 32768;
  short* Bo = smem + 40960;
  const int row0 = blockIdx.x * 256, col0 = blockIdx.y * 128;
  const int kOff = blockIdx.z * 2048;
  const int tid = threadIdx.x, lane = tid & 63, wid = tid >> 6;
  const int lr = lane & 15, lq = lane >> 4;
  const int wr = wid >> 1, wc = wid & 1;       // wave: 64 rows x 64 cols
  const __hip_bfloat16* A = G + (size_t)row0 * 4096 + kOff;
  const __hip_bfloat16* Bt = W2t + (size_t)col0 * 4096 + kOff;

  // stage A-half h (128 rows with bit5==h) of the K-tile at k0
  auto STGA = [&](int k0, int h, short* dst) {
    #pragma unroll
    for (int ii = 0; ii < 2; ii++) {
      const int f = tid + ii * 512;            // 0..1023
      const int rp = f >> 3, P = f & 7;
      const int r = ((rp >> 5) << 6) | (h << 5) | (rp & 31);
      const int g = P ^ (r & 7);
      stage16(A + (size_t)r * 4096 + k0 + g * 8, dst + r * 64 + P * 8);
    }
  };
  auto STGB = [&](int k0, short* dst) {
    #pragma unroll
    for (int ii = 0; ii < 2; ii++) {
      const int f = tid + ii * 512;
      const int r = f >> 3, P = f & 7;
      const int g = P ^ (r & 7);
      stage16(Bt + (size_t)r * 4096 + k0 + g * 8, dst + r * 64 + P * 8);
    }
  };

  f32x4 acc[4][4] = {};
  bf16x8 af[2][2], bf[4][2];

  auto RDA = [&](const short* pa, int MH) {
    #pragma unroll
    for (int mi2 = 0; mi2 < 2; mi2++)
      #pragma unroll
      for (int ks = 0; ks < 2; ks++) {
        const int r = wr * 64 + MH * 32 + mi2 * 16 + lr;
        af[mi2][ks] = *(const bf16x8*)(pa + r * 64 + (((ks * 4 + lq) ^ (r & 7)) << 3));
      }
  };
  auto RDB = [&](const short* pb) {
    #pragma unroll
    for (int ni = 0; ni < 4; ni++)
      #pragma unroll
      for (int ks = 0; ks < 2; ks++) {
        const int n = wc * 64 + ni * 16 + lr;
        bf[ni][ks] = *(const bf16x8*)(pb + n * 64 + (((ks * 4 + lq) ^ (n & 7)) << 3));
      }
  };

  // prologue in steady-state FIFO order: [Be0,Ae0.lo][Ae0.hi][Bo0,Ao0.lo]
  STGB(0, Be); STGA(0, 0, Ae);
  STGA(0, 1, Ae);
  STGB(64, Bo); STGA(64, 0, Ao);
  asm volatile("s_waitcnt vmcnt(4)" ::: "memory");  // E0 complete; 4 fly
  __syncthreads();

  for (int i = 0; i < 16; ++i) {
    const int kE1 = (i + 1) * 128, kO0 = i * 128 + 64, kO1 = kE1 + 64;
    const bool more = (i + 1 < 16);
    // phE0: read E.MH0 + B(E); stage Ao_i.hi; vmcnt(2) retires prev-phO1's 4
    RDA(Ae, 0); RDB(Be);
    STGA(kO0, 1, Ao);
    asm volatile("s_waitcnt vmcnt(2)" ::: "memory");
    ph_sync();
    mm2<0>(acc, af, bf);
    // phE1: read E.MH1 (bf cached); stage Be', Ae'.lo
    RDA(Ae, 1);
    if (more) { STGB(kE1, Be); STGA(kE1, 0, Ae); }
    ph_sync();
    mm2<1>(acc, af, bf);
    // phO0: read O.MH0 + B(O); stage Ae'.hi; vmcnt retires Ao_i.hi
    RDA(Ao, 0); RDB(Bo);
    if (more) {
      STGA(kE1, 1, Ae);
      asm volatile("s_waitcnt vmcnt(6)" ::: "memory");
    } else {
      asm volatile("s_waitcnt vmcnt(0)" ::: "memory");
    }
    ph_sync();
    mm2<0>(acc, af, bf);
    // phO1: read O.MH1; stage Bo', Ao'.lo; vmcnt retires E' parts
    RDA(Ao, 1);
    if (more) {
      STGB(kO1, Bo); STGA(kO1, 0, Ao);
      asm volatile("s_waitcnt vmcnt(4)" ::: "memory");
    }
    ph_sync();
    mm2<1>(acc, af, bf);
  }

  // epilogue: atomic f32 accumulate (out pre-initialized with x2 + b2)
  #pragma unroll
  for (int mi = 0; mi < 4; mi++)
    #pragma unroll
    for (int ni = 0; ni < 4; ni++)
      #pragma unroll
      for (int rr = 0; rr < 4; rr++) {
        const int grow = row0 + wr * 64 + mi * 16 + lq * 4 + rr;
        const int gcol = col0 + wc * 64 + ni * 16 + lr;
        atomicAdd(out + (((size_t)grow << 10) + gcol), acc[mi][ni][rr]);
      }
}

extern "C" void kernel_launch(void* const* d_in, const int* in_sizes, int n_in,
                              void* d_out, int out_size, void* d_ws, size_t ws_size,
                              hipStream_t stream) {
  const float* x     = (const float*)d_in[0];
  const float* ln1_g = (const float*)d_in[1];
  const float* ln1_b = (const float*)d_in[2];
  const float* ln2_g = (const float*)d_in[3];
  const float* ln2_b = (const float*)d_in[4];
  const float* Wq    = (const float*)d_in[5];
  const float* bq    = (const float*)d_in[6];
  const float* Wk    = (const float*)d_in[7];
  const float* bk    = (const float*)d_in[8];
  const float* Wv    = (const float*)d_in[9];
  const float* bv    = (const float*)d_in[10];
  const float* W1    = (const float*)d_in[11];
  const float* b1    = (const float*)d_in[12];
  const float* W2    = (const float*)d_in[13];
  const float* b2    = (const float*)d_in[14];
  float* out = (float*)d_out;

  char* p = (char*)d_ws;
  auto alloc = [&](size_t bytes) { char* r = p; p += (bytes + 255) & ~(size_t)255; return r; };
  __hip_bfloat16* wqkv = (__hip_bfloat16*)alloc(3072 * 1024 * 2);
  __hip_bfloat16* w1t  = (__hip_bfloat16*)alloc(4096 * 1024 * 2);
  __hip_bfloat16* w2t  = (__hip_bfloat16*)alloc(1024 * 4096 * 2);
  float*          bqkv = (float*)alloc(3072 * 4);
  __hip_bfloat16* h1   = (__hip_bfloat16*)alloc(4096 * 1024 * 2);
  __hip_bfloat16* Qb   = (__hip_bfloat16*)alloc((size_t)64 * 65536 * 2);  // [64][1024][64]
  __hip_bfloat16* Kb   = (__hip_bfloat16*)alloc((size_t)64 * 65536 * 2);
  __hip_bfloat16* Vt   = (__hip_bfloat16*)alloc((size_t)64 * 65536 * 2);  // [64][64][1024]
  float*          TV   = (float*)alloc((size_t)64 * 8 * 64 * 4);
  float*          yb   = (float*)alloc((size_t)4096 * 1024 * 4);
  __hip_bfloat16* h2   = (__hip_bfloat16*)alloc(4096 * 1024 * 2);
  __hip_bfloat16* G    = (__hip_bfloat16*)alloc((size_t)4096 * 4096 * 2);
  (void)ws_size; (void)in_sizes; (void)n_in; (void)out_size;

  const dim3 b256(256), bt(32, 8);
  k_tcvt3<<<dim3(32, 32, 3), bt, 0, stream>>>(Wq, Wk, Wv, wqkv);
  k_tcvt<<<dim3(128, 32), bt, 0, stream>>>(W1, w1t, 1024, 4096, 0, 1024);
  k_tcvt<<<dim3(32, 128), bt, 0, stream>>>(W2, w2t, 4096, 1024, 0, 4096);
  k_pack_bias<<<12, b256, 0, stream>>>(bq, bk, bv, bqkv);

  k_ln<<<4096, b256, 0, stream>>>(x, nullptr, ln1_g, ln1_b, h1, nullptr, nullptr);
  k_gemm_qkv<<<dim3(32, 24), b256, 0, stream>>>(h1, wqkv, bqkv, Qb, Kb, Vt);
  k_tailv<<<64, b256, 0, stream>>>(Vt, TV);
  k_attn<<<dim3(16, 64), b256, 0, stream>>>(Qb, Kb, Vt, TV, yb);

  k_ln<<<4096, b256, 0, stream>>>(x, yb, ln2_g, ln2_b, h2, b2, out);
  k_gemm_mlp1<<<dim3(16, 16), dim3(512), 0, stream>>>(h2, w1t, b1, G);
  k_gemm_mlp2<<<dim3(16, 8, 2), dim3(512), 0, stream>>>(G, w2t, out);
}

// Round 11
// 307.564 us; speedup vs baseline: 1.1728x; 1.0677x over previous
//
#include <hip/hip_runtime.h>
#include <hip/hip_bf16.h>
#include <math.h>

// Transformer block (pre-LN attn + MLP), B=4 T=1024 H=1024 K=16 HD=64.
// R21: mlp2 loses split-K + atomics (R11/R12 measured ~1.5us per M atomics;
// 8.4M atomics ~= 12us of mlp2's 59). New mlp2: 128x128 tile, grid(32,8)
// = 256 blocks = 1/CU, K=4096, 512 thr (8 waves 2Mx4N, 64x32 out/wave),
// 4-phase counted-vmcnt pipeline (32 iters x 2 K-tiles), LDS 64KB ->
// 2 blocks/CU. Epilogue: plain RMW (out pre-init with x2+b2 by k_ln).
// Ledger (FIFO; A-half=1 load/thr, B=2/thr; stages/phase:
//   phE0:Ao_i.hi(1) phE1:Be'+Ae'.lo(3) phO0:Ae'.hi(1) phO1:Bo'+Ao'.lo(3)):
//   vmcnt(4) at EVERY phase (after stage, before ph_sync) retires exactly
//   the parts read next-next phase; reads in phase p are always covered by
//   a vmcnt in an earlier phase + the intervening barrier (R19/R20 rule).
//   Tails: phE1 vmcnt(1), phO0 vmcnt(0). Prologue [Be0+Ae0.lo][Ae0.hi]
//   [Bo0+Ao0.lo] + vmcnt(4) replicates the steady FIFO.
// mlp1: R19 8-phase 256x256 (unchanged). All other kernels unchanged.
// Attention: fused flash-style, 64-row Q-tiles, separate lK/lV, 2 barriers
// per kt, K(kt+1) prefetch hidden under softmax, setprio on MFMA clusters;
// masked logits FILLED with 1e-9; fully-masked K-tiles contribute
// exp(1e-9-m)*suffixV analytically (TV precomputed).

typedef __attribute__((ext_vector_type(8))) short bf16x8;
typedef __attribute__((ext_vector_type(4))) float f32x4;

#define DEVINL __device__ __forceinline__

#define LOG2E_SCALE 0.18033688f      /* 0.125 * log2(e) */
#define MASK2 1.4426950408889634e-9f /* 1e-9 * log2(e) */

DEVINL void stage16(const __hip_bfloat16* g, short* l) {
  __builtin_amdgcn_global_load_lds(
      (const __attribute__((address_space(1))) unsigned int*)g,
      (__attribute__((address_space(3))) unsigned int*)l, 16, 0, 0);
}

DEVINL float bf2f(short u) {
  unsigned x = ((unsigned)(unsigned short)u) << 16;
  float f; __builtin_memcpy(&f, &x, 4); return f;
}

DEVINL short f2bf_s(float f) {
  __hip_bfloat16 h = __float2bfloat16(f);
  short s; __builtin_memcpy(&s, &h, 2); return s;
}

DEVINL float block_sum(float v, float* sb) {
  #pragma unroll
  for (int o = 32; o; o >>= 1) v += __shfl_down(v, o);
  const int lane = threadIdx.x & 63, w = threadIdx.x >> 6;
  if (lane == 0) sb[w] = v;
  __syncthreads();
  float r = sb[0] + sb[1] + sb[2] + sb[3];
  __syncthreads();
  return r;
}

// ---- GEMM core BK=64: C[M,N] += A[M,Kd] * Bt[N,Kd]^T, 256 threads ----
template<int BM, int BN, int WM, int WN>
DEVINL void gemm_core64(const __hip_bfloat16* __restrict__ A, int lda,
                        const __hip_bfloat16* __restrict__ Bt, int ldb,
                        int Kd, int row0, int col0,
                        f32x4 (&acc)[WM/16][WN/16],
                        short* lds_a, short* lds_b) {
  constexpr int MI = WM / 16, NI = WN / 16, WNC = BN / WN;
  constexpr int CA = BM * 8, CB = BN * 8;  // 16B chunks per tile
  const int tid = threadIdx.x;
  const int lane = tid & 63, wave = tid >> 6;
  const int wm = (wave / WNC) * WM, wn = (wave % WNC) * WN;
  const int lr = lane & 15, lq = lane >> 4;
  for (int k0 = 0; k0 < Kd; k0 += 64) {
    #pragma unroll
    for (int c = tid; c < CA; c += 256) {
      const int r = c >> 3, kc = ((c & 7) ^ (r & 7)) << 3;
      stage16(A + (size_t)(row0 + r) * lda + k0 + kc, lds_a + c * 8);
    }
    #pragma unroll
    for (int c = tid; c < CB; c += 256) {
      const int r = c >> 3, kc = ((c & 7) ^ (r & 7)) << 3;
      stage16(Bt + (size_t)(col0 + r) * ldb + k0 + kc, lds_b + c * 8);
    }
    __syncthreads();
    #pragma unroll
    for (int s = 0; s < 2; s++) {
      bf16x8 af[MI], bfr[NI];
      #pragma unroll
      for (int mi = 0; mi < MI; mi++) {
        const int m = wm + mi * 16 + lr;
        af[mi] = *(const bf16x8*)(lds_a + m * 64 + (((s * 4 + lq) ^ (m & 7)) << 3));
      }
      #pragma unroll
      for (int ni = 0; ni < NI; ni++) {
        const int n = wn + ni * 16 + lr;
        bfr[ni] = *(const bf16x8*)(lds_b + n * 64 + (((s * 4 + lq) ^ (n & 7)) << 3));
      }
      #pragma unroll
      for (int mi = 0; mi < MI; mi++)
        #pragma unroll
        for (int ni = 0; ni < NI; ni++)
          acc[mi][ni] = __builtin_amdgcn_mfma_f32_16x16x32_bf16(
              af[mi], bfr[ni], acc[mi][ni], 0, 0, 0);
    }
    __syncthreads();
  }
}

// ---- transpose + f32->bf16: src[R][C] -> dst[(c+off)][r], dst pitch P ----
__global__ __launch_bounds__(256) void k_tcvt(const float* __restrict__ src,
                                              __hip_bfloat16* __restrict__ dst,
                                              int R, int C, int dstOff, int dstPitch) {
  __shared__ float tile[32][33];
  const int c0 = blockIdx.x * 32, r0 = blockIdx.y * 32;
  const int tx = threadIdx.x, ty = threadIdx.y;  // (32,8)
  #pragma unroll
  for (int i = 0; i < 32; i += 8)
    tile[ty + i][tx] = src[(size_t)(r0 + ty + i) * C + c0 + tx];
  __syncthreads();
  #pragma unroll
  for (int i = 0; i < 32; i += 8)
    dst[(size_t)(c0 + ty + i + dstOff) * dstPitch + r0 + tx] =
        __float2bfloat16(tile[tx][ty + i]);
}

// fused Wq/Wk/Wv transpose (z picks source; all 1024x1024, dst pitch 1024)
__global__ __launch_bounds__(256) void k_tcvt3(const float* __restrict__ Wq,
                                               const float* __restrict__ Wk,
                                               const float* __restrict__ Wv,
                                               __hip_bfloat16* __restrict__ dst) {
  __shared__ float tile[32][33];
  const float* src = blockIdx.z == 0 ? Wq : (blockIdx.z == 1 ? Wk : Wv);
  const int dstOff = blockIdx.z << 10;
  const int c0 = blockIdx.x * 32, r0 = blockIdx.y * 32;
  const int tx = threadIdx.x, ty = threadIdx.y;
  #pragma unroll
  for (int i = 0; i < 32; i += 8)
    tile[ty + i][tx] = src[(size_t)(r0 + ty + i) * 1024 + c0 + tx];
  __syncthreads();
  #pragma unroll
  for (int i = 0; i < 32; i += 8)
    dst[(size_t)(c0 + ty + i + dstOff) * 1024 + r0 + tx] =
        __float2bfloat16(tile[tx][ty + i]);
}

__global__ __launch_bounds__(256) void k_pack_bias(const float* __restrict__ bq,
                                                   const float* __restrict__ bk,
                                                   const float* __restrict__ bv,
                                                   float* __restrict__ o) {
  const int i = blockIdx.x * 256 + threadIdx.x;
  if (i < 3072)
    o[i] = i < 1024 ? bq[i] : (i < 2048 ? bk[i - 1024] : bv[i - 2048]);
}

// ---- LayerNorm (+residual add; optionally init out = x2 + b2) ----
__global__ __launch_bounds__(256) void k_ln(const float* __restrict__ x,
                                            const float* __restrict__ y,
                                            const float* __restrict__ g,
                                            const float* __restrict__ bb,
                                            __hip_bfloat16* __restrict__ o,
                                            const float* __restrict__ badd,
                                            float* __restrict__ oinit) {
  __shared__ float sb[4];
  const int t = threadIdx.x;
  const size_t base = (size_t)blockIdx.x * 1024 + t * 4;
  const int c = t * 4;
  float4 xv = *(const float4*)(x + base);
  if (y) {
    float4 yv = *(const float4*)(y + base);
    xv.x += yv.x; xv.y += yv.y; xv.z += yv.z; xv.w += yv.w;
    float4 ov;
    ov.x = xv.x + badd[c + 0]; ov.y = xv.y + badd[c + 1];
    ov.z = xv.z + badd[c + 2]; ov.w = xv.w + badd[c + 3];
    *(float4*)(oinit + base) = ov;
  }
  const float mu = block_sum(xv.x + xv.y + xv.z + xv.w, sb) * (1.f / 1024.f);
  const float dx = xv.x - mu, dy = xv.y - mu, dz = xv.z - mu, dw = xv.w - mu;
  const float var = block_sum(dx * dx + dy * dy + dz * dz + dw * dw, sb) * (1.f / 1024.f);
  const float rs = rsqrtf(var + 1e-5f);
  o[base + 0] = __float2bfloat16(dx * rs * g[c + 0] + bb[c + 0]);
  o[base + 1] = __float2bfloat16(dy * rs * g[c + 1] + bb[c + 1]);
  o[base + 2] = __float2bfloat16(dz * rs * g[c + 2] + bb[c + 2]);
  o[base + 3] = __float2bfloat16(dw * rs * g[c + 3] + bb[c + 3]);
}

// ---- QKV GEMM: h1[4096,1024] @ Wqkv_t[3072,1024]^T -> Q/K [hb][t][d], Vt [hb][d][t]
// Q is PRE-SCALED by 0.125*log2e so attention logits are base-2.
__global__ __launch_bounds__(256) void k_gemm_qkv(
    const __hip_bfloat16* __restrict__ h1, const __hip_bfloat16* __restrict__ Wt,
    const float* __restrict__ bqkv, __hip_bfloat16* __restrict__ Q,
    __hip_bfloat16* __restrict__ K, __hip_bfloat16* __restrict__ Vt) {
  __shared__ alignas(16) short smem[16896];   // la(8192) lb(8192) | lc(16896)
  short* la = smem;
  short* lb = smem + 8192;
  short* lc = smem;
  const int row0 = blockIdx.x * 128, col0 = blockIdx.y * 128;
  f32x4 acc[4][4] = {};
  gemm_core64<128, 128, 64, 64>(h1, 1024, Wt, 1024, 1024, row0, col0, acc, la, lb);
  const int tid = threadIdx.x, lane = tid & 63, wave = tid >> 6;
  const int wm = (wave >> 1) * 64, wn = (wave & 1) * 64, lr = lane & 15, lq = lane >> 4;
  const int which = col0 >> 10;                 // uniform: 0=Q 1=K 2=V
  const int h0 = (col0 & 1023) >> 6;
  const int b = row0 >> 10, t0 = row0 & 1023;
  if (which < 2) {
    const float qs = (which == 0) ? LOG2E_SCALE : 1.f;
    #pragma unroll
    for (int mi = 0; mi < 4; mi++)
      #pragma unroll
      for (int ni = 0; ni < 4; ni++)
        #pragma unroll
        for (int r = 0; r < 4; r++) {
          const int row = wm + mi * 16 + lq * 4 + r;
          const int col = wn + ni * 16 + lr;
          lc[row * 132 + col] = f2bf_s((acc[mi][ni][r] + bqkv[col0 + col]) * qs);
        }
    __syncthreads();
    __hip_bfloat16* O = which == 0 ? Q : K;
    #pragma unroll
    for (int c = 0; c < 8; c++) {
      const int f = tid + 256 * c;              // flat 16B-chunk id
      const int r = f >> 4, cc = f & 15;
      const int col = cc * 8;
      const int head = h0 + (col >> 6), d = col & 63;
      float4 vv = *(const float4*)(lc + r * 132 + col);
      *(float4*)(O + (((size_t)(b * 16 + head)) << 16) + (t0 + r) * 64 + d) = vv;
    }
  } else {
    // transposed epilogue: lc[col][row]
    #pragma unroll
    for (int mi = 0; mi < 4; mi++)
      #pragma unroll
      for (int ni = 0; ni < 4; ni++)
        #pragma unroll
        for (int r = 0; r < 4; r++) {
          const int row = wm + mi * 16 + lq * 4 + r;
          const int col = wn + ni * 16 + lr;
          lc[col * 132 + row] = f2bf_s(acc[mi][ni][r] + bqkv[col0 + col]);
        }
    __syncthreads();
    #pragma unroll
    for (int c = 0; c < 8; c++) {
      const int f = tid + 256 * c;
      const int dl = f >> 4, tc = f & 15;       // local d 0..127, t-chunk
      const int head = h0 + (dl >> 6), d = dl & 63;
      float4 vv = *(const float4*)(lc + dl * 132 + tc * 8);
      *(float4*)(Vt + (((size_t)(b * 16 + head)) << 16) + (size_t)d * 1024 +
                 t0 + tc * 8) = vv;
    }
  }
}

// ---- tail V sums: TV[hb][qt][d] = sum_{t >= (qt+1)*128} Vt[hb][d][t] ----
__global__ __launch_bounds__(256) void k_tailv(const __hip_bfloat16* __restrict__ Vt,
                                               float* __restrict__ TV) {
  __shared__ float ts[8][64];
  const int hb = blockIdx.x, tid = threadIdx.x;
  const __hip_bfloat16* Vh = Vt + ((size_t)hb << 16);
  for (int w = tid; w < 512; w += 256) {
    const int kt = w >> 6, d = w & 63;
    const short* p = (const short*)(Vh + (size_t)d * 1024 + kt * 128);
    float s = 0.f;
    for (int j = 0; j < 128; j += 8) {
      bf16x8 v = *(const bf16x8*)(p + j);
      #pragma unroll
      for (int e = 0; e < 8; e++) s += bf2f(v[e]);
    }
    ts[kt][d] = s;
  }
  __syncthreads();
  for (int w = tid; w < 512; w += 256) {
    const int qt = w >> 6, d = w & 63;
    float s = 0.f;
    for (int kt = qt + 1; kt < 8; kt++) s += ts[kt][d];
    TV[((size_t)hb * 8 + qt) * 64 + d] = s;
  }
}

// ---- fused attention: one block = (64 q-rows, one head); 1024 blocks ----
// Separate lK/lV buffers; 2 barriers per kt; K(kt+1) prefetched alongside
// V(kt) so its latency hides under softmax+PV; setprio on MFMA clusters.
__global__ __launch_bounds__(256, 3) void k_attn(
    const __hip_bfloat16* __restrict__ Q, const __hip_bfloat16* __restrict__ K,
    const __hip_bfloat16* __restrict__ Vt, const float* __restrict__ TV,
    float* __restrict__ y) {
  __shared__ short lp[64 * 130];   // P-tile (padded)
  __shared__ short lK[128 * 64];   // K-tile, swizzled
  __shared__ short lV[128 * 64];   // V^T-tile, swizzled
  const int hb = blockIdx.y;
  const int j = (blockIdx.y & 32) ? (15 - (int)blockIdx.x) : (int)blockIdx.x;
  const int q0 = j * 64;
  const int nkt = (j >> 1) + 1;    // K-tiles (128 wide) to compute
  const int tid = threadIdx.x, lane = tid & 63, wave = tid >> 6;
  const int lr = lane & 15, lq = lane >> 4;
  const int wm = wave * 16;        // wave owns q-rows [q0+wm, q0+wm+16)
  const __hip_bfloat16* Qh = Q + ((size_t)hb << 16);
  const __hip_bfloat16* Kh = K + ((size_t)hb << 16);
  const __hip_bfloat16* Vh = Vt + ((size_t)hb << 16);

  // Q A-frags: direct global loads (rows q0+wm+lr, cols s*32+lq*8)
  bf16x8 qf[2];
  #pragma unroll
  for (int s = 0; s < 2; s++)
    qf[s] = *(const bf16x8*)((const short*)Qh +
                             (size_t)(q0 + wm + lr) * 64 + s * 32 + lq * 8);

  f32x4 oacc[4] = {};
  float mrow[4], lrow[4];
  #pragma unroll
  for (int r = 0; r < 4; r++) { mrow[r] = -1e30f; lrow[r] = 0.f; }

  // prologue: stage K(0)
  for (int c = tid; c < 1024; c += 256)
    stage16(Kh + (size_t)(c >> 3) * 64 + (((c & 7) ^ ((c >> 3) & 7)) << 3),
            lK + c * 8);
  __syncthreads();  // K(0) visible

  for (int kt = 0; kt < nkt; kt++) {
    const int k0 = kt * 128;
    // ---- QK^T from lK ----
    f32x4 sacc[8] = {};
    __builtin_amdgcn_s_setprio(1);
    #pragma unroll
    for (int s = 0; s < 2; s++) {
      bf16x8 bf[8];
      #pragma unroll
      for (int ni = 0; ni < 8; ni++) {
        const int n = ni * 16 + lr;
        bf[ni] = *(const bf16x8*)(lK + n * 64 + (((s * 4 + lq) ^ (n & 7)) << 3));
      }
      #pragma unroll
      for (int ni = 0; ni < 8; ni++)
        sacc[ni] = __builtin_amdgcn_mfma_f32_16x16x32_bf16(
            qf[s], bf[ni], sacc[ni], 0, 0, 0);
    }
    __builtin_amdgcn_s_setprio(0);
    __syncthreads();  // barA: lK frag reads + prev PV's lp/lV reads done
    // ---- V(kt) + K(kt+1) DMA (latency hides under softmax below) ----
    for (int c = tid; c < 1024; c += 256)
      stage16(Vh + (size_t)(c >> 4) * 1024 + k0 + (((c & 15) ^ ((c >> 4) & 15)) << 3),
              lV + c * 8);
    if (kt + 1 < nkt) {
      const int k1 = k0 + 128;
      for (int c = tid; c < 1024; c += 256)
        stage16(Kh + (size_t)(k1 + (c >> 3)) * 64 + (((c & 7) ^ ((c >> 3) & 7)) << 3),
                lK + c * 8);
    }
    // ---- online softmax, base-2 domain ----
    const bool last = (kt == nkt - 1);
    #pragma unroll
    for (int r = 0; r < 4; r++) {
      const int grow = q0 + wm + lq * 4 + r;   // global q row
      float tmax = -1e30f;
      #pragma unroll
      for (int ni = 0; ni < 8; ni++) {
        float v = sacc[ni][r];
        if (last && (k0 + ni * 16 + lr) > grow) v = MASK2;
        sacc[ni][r] = v;
        tmax = fmaxf(tmax, v);
      }
      #pragma unroll
      for (int msk = 8; msk; msk >>= 1) tmax = fmaxf(tmax, __shfl_xor(tmax, msk));
      const float mn = fmaxf(mrow[r], tmax);
      const float al = __builtin_amdgcn_exp2f(mrow[r] - mn);
      float rs = 0.f;
      #pragma unroll
      for (int ni = 0; ni < 8; ni++) {
        const float pv = __builtin_amdgcn_exp2f(sacc[ni][r] - mn);
        sacc[ni][r] = pv;
        rs += pv;
      }
      #pragma unroll
      for (int msk = 8; msk; msk >>= 1) rs += __shfl_xor(rs, msk);
      mrow[r] = mn;
      lrow[r] = lrow[r] * al + rs;
      #pragma unroll
      for (int ni = 0; ni < 4; ni++) oacc[ni][r] *= al;
    }
    // P -> lp (padded pitch 130)
    #pragma unroll
    for (int r = 0; r < 4; r++) {
      const int row = wm + lq * 4 + r;
      #pragma unroll
      for (int ni = 0; ni < 8; ni++)
        lp[row * 130 + ni * 16 + lr] = f2bf_s(sacc[ni][r]);
    }
    __syncthreads();  // barB: V(kt)+K(kt+1) landed (vmcnt drain) + P visible
    // ---- PV from lp, lV ----
    __builtin_amdgcn_s_setprio(1);
    #pragma unroll
    for (int ks = 0; ks < 4; ks++) {
      bf16x8 pa, vb[4];
      pa = *(const bf16x8*)(lp + (wm + lr) * 130 + ks * 32 + lq * 8);
      #pragma unroll
      for (int ni = 0; ni < 4; ni++) {
        const int d = ni * 16 + lr;
        vb[ni] = *(const bf16x8*)(lV + d * 128 + (((ks * 4 + lq) ^ (d & 15)) << 3));
      }
      #pragma unroll
      for (int ni = 0; ni < 4; ni++)
        oacc[ni] = __builtin_amdgcn_mfma_f32_16x16x32_bf16(
            pa, vb[ni], oacc[ni], 0, 0, 0);
    }
    __builtin_amdgcn_s_setprio(0);
    // no barrier here: next QK reads lK (disjoint from lp/lV); barA covers reuse
  }

  const int b = hb >> 4, h = hb & 15;
  const float cv = (float)(1024 - nkt * 128);
  const float* tv = TV + ((size_t)hb * 8 + (j >> 1)) * 64;
  #pragma unroll
  for (int r = 0; r < 4; r++) {
    const int t = q0 + wm + lq * 4 + r;
    const float tail = __builtin_amdgcn_exp2f(MASK2 - mrow[r]);
    const float inv = 1.f / (lrow[r] + cv * tail);
    #pragma unroll
    for (int ni = 0; ni < 4; ni++) {
      const int d = ni * 16 + lr;
      y[((size_t)(b * 1024 + t) << 10) + h * 64 + d] =
          (oacc[ni][r] + tail * tv[d]) * inv;
    }
  }
}

// ======== 8-phase mlp1 helpers ========
template<int MH, int NH>
DEVINL void ph_read(const short* pa, const short* pb, int wr, int wc,
                    int lr, int lq, bf16x8 (&af)[4][2], bf16x8 (&bf)[2][2]) {
  if (NH == 0) {
    #pragma unroll
    for (int mi2 = 0; mi2 < 4; mi2++)
      #pragma unroll
      for (int ks = 0; ks < 2; ks++) {
        const int r = wr * 128 + MH * 64 + mi2 * 16 + lr;
        af[mi2][ks] = *(const bf16x8*)(pa + r * 64 + (((ks * 4 + lq) ^ (r & 7)) << 3));
      }
  }
  #pragma unroll
  for (int ni2 = 0; ni2 < 2; ni2++)
    #pragma unroll
    for (int ks = 0; ks < 2; ks++) {
      const int n = wc * 64 + NH * 32 + ni2 * 16 + lr;
      bf[ni2][ks] = *(const bf16x8*)(pb + n * 64 + (((ks * 4 + lq) ^ (n & 7)) << 3));
    }
}

DEVINL void ph_sync() {
  __builtin_amdgcn_s_barrier();
  asm volatile("s_waitcnt lgkmcnt(0)" ::: "memory");
  __builtin_amdgcn_sched_barrier(0);
}

template<int MH, int NH>
DEVINL void ph_mfma(f32x4 (&acc)[8][4], bf16x8 (&af)[4][2], bf16x8 (&bf)[2][2]) {
  __builtin_amdgcn_s_setprio(1);
  #pragma unroll
  for (int mi2 = 0; mi2 < 4; mi2++)
    #pragma unroll
    for (int ni2 = 0; ni2 < 2; ni2++)
      #pragma unroll
      for (int ks = 0; ks < 2; ks++)
        acc[MH * 4 + mi2][NH * 2 + ni2] = __builtin_amdgcn_mfma_f32_16x16x32_bf16(
            af[mi2][ks], bf[ni2][ks], acc[MH * 4 + mi2][NH * 2 + ni2], 0, 0, 0);
  __builtin_amdgcn_s_setprio(0);
  __builtin_amdgcn_s_barrier();
}

// ---- MLP1: h2[4096,1024] @ W1t[4096,1024]^T + b1 -> tanh-GELU -> G bf16 ----
// 256x256 tile, 512 thr, BK=64, 2 K-tiles/iter, 8-phase counted-vmcnt.
__global__ __launch_bounds__(512, 2) void k_gemm_mlp1(const __hip_bfloat16* __restrict__ h2,
                                                      const __hip_bfloat16* __restrict__ W1t,
                                                      const float* __restrict__ b1,
                                                      __hip_bfloat16* __restrict__ G) {
  __shared__ alignas(16) short smem[65536];  // 128KB: Ae Ao Be Bo x 16384
  short* Ae = smem;
  short* Ao = smem + 16384;
  short* Be = smem + 32768;
  short* Bo = smem + 49152;
  const int row0 = blockIdx.x * 256, col0 = blockIdx.y * 256;
  const int tid = threadIdx.x, lane = tid & 63, wid = tid >> 6;
  const int lr = lane & 15, lq = lane >> 4;
  const int wr = wid >> 2, wc = wid & 3;
  const __hip_bfloat16* A = h2 + (size_t)row0 * 1024;
  const __hip_bfloat16* Bt = W1t + (size_t)col0 * 1024;

  // stage one part (128 rows x 64 cols bf16) of a K-tile into dst buffer.
  // part h = rows with ((r>>SH)&1)==h (A: SH=6, B: SH=5). 2 loads/thread,
  // LDS dst linear in lane (base + lane*16B) as gload_lds requires.
  auto STG = [&](const __hip_bfloat16* src, int k0, int h, short* dst, int SH) {
    #pragma unroll
    for (int ii = 0; ii < 2; ii++) {
      const int f = tid + ii * 512;
      const int rp = f >> 3, P = f & 7;
      const int r = ((rp >> SH) << (SH + 1)) | (h << SH) | (rp & ((1 << SH) - 1));
      const int g = P ^ (r & 7);
      stage16(src + (size_t)r * 1024 + k0 + g * 8, dst + r * 64 + P * 8);
    }
  };

  f32x4 acc[8][4] = {};
  bf16x8 af[4][2], bf[2][2];

  // prologue: E0 (4 parts) + O0.A0, O0.B0; vmcnt(4) retires E0 (FIFO).
  STG(A, 0, 0, Ae, 6);  STG(Bt, 0, 0, Be, 5);
  STG(A, 0, 1, Ae, 6);  STG(Bt, 0, 1, Be, 5);
  STG(A, 64, 0, Ao, 6); STG(Bt, 64, 0, Bo, 5);
  asm volatile("s_waitcnt vmcnt(4)" ::: "memory");
  __syncthreads();

  for (int i = 0; i < 8; ++i) {
    const int kE1 = (i + 1) * 128;       // next even K-tile
    const int kO0 = i * 128 + 64;        // this iter's odd K-tile
    const int kO1 = kE1 + 64;            // next odd K-tile
    const bool more = (i + 1 < 8);
    // ph0: E q(0,0); stage O_i.A1
    ph_read<0, 0>(Ae, Be, wr, wc, lr, lq, af, bf);
    STG(A, kO0, 1, Ao, 6);
    ph_sync();
    ph_mfma<0, 0>(acc, af, bf);
    // ph1: E q(0,1); stage O_i.B1
    ph_read<0, 1>(Ae, Be, wr, wc, lr, lq, af, bf);
    STG(Bt, kO0, 1, Bo, 5);
    ph_sync();
    ph_mfma<0, 1>(acc, af, bf);
    // ph2: E q(1,0); stage E'.A0
    ph_read<1, 0>(Ae, Be, wr, wc, lr, lq, af, bf);
    if (more) STG(A, kE1, 0, Ae, 6);
    ph_sync();
    ph_mfma<1, 0>(acc, af, bf);
    // ph3: E q(1,1); stage E'.B0; vmcnt retires all O_i parts
    ph_read<1, 1>(Ae, Be, wr, wc, lr, lq, af, bf);
    if (more) {
      STG(Bt, kE1, 0, Be, 5);
      asm volatile("s_waitcnt vmcnt(4)" ::: "memory");
    } else {
      asm volatile("s_waitcnt vmcnt(0)" ::: "memory");
    }
    ph_sync();
    ph_mfma<1, 1>(acc, af, bf);
    // ph4: O q(0,0); stage E'.A1
    ph_read<0, 0>(Ao, Bo, wr, wc, lr, lq, af, bf);
    if (more) STG(A, kE1, 1, Ae, 6);
    ph_sync();
    ph_mfma<0, 0>(acc, af, bf);
    // ph5: O q(0,1); stage E'.B1
    ph_read<0, 1>(Ao, Bo, wr, wc, lr, lq, af, bf);
    if (more) STG(Bt, kE1, 1, Be, 5);
    ph_sync();
    ph_mfma<0, 1>(acc, af, bf);
    // ph6: O q(1,0); stage O'.A0
    ph_read<1, 0>(Ao, Bo, wr, wc, lr, lq, af, bf);
    if (more) STG(A, kO1, 0, Ao, 6);
    ph_sync();
    ph_mfma<1, 0>(acc, af, bf);
    // ph7: O q(1,1); stage O'.B0; vmcnt retires all E' parts
    ph_read<1, 1>(Ao, Bo, wr, wc, lr, lq, af, bf);
    if (more) {
      STG(Bt, kO1, 0, Bo, 5);
      asm volatile("s_waitcnt vmcnt(4)" ::: "memory");
    }
    ph_sync();
    ph_mfma<1, 1>(acc, af, bf);
  }

  // epilogue: tanh-GELU -> bf16 via 4x 64-row lc passes (lc = smem)
  short* lc = smem;
  #pragma unroll
  for (int pr = 0; pr < 4; pr++) {
    if ((wid >> 2) == (pr >> 1)) {
      const int mib = (pr & 1) * 4;
      #pragma unroll
      for (int mi2 = 0; mi2 < 4; mi2++)
        #pragma unroll
        for (int ni = 0; ni < 4; ni++)
          #pragma unroll
          for (int rr = 0; rr < 4; rr++) {
            const int rloc = mi2 * 16 + lq * 4 + rr;
            const int col = (wid & 3) * 64 + ni * 16 + lr;
            float v = acc[mib + mi2][ni][rr] + b1[col0 + col];
            const float u2 = fminf(v * (2.3022079f + 0.1029434f * v * v), 80.f);
            const float e = __builtin_amdgcn_exp2f(u2);
            v = v * e * __builtin_amdgcn_rcpf(e + 1.f);
            lc[rloc * 264 + col] = f2bf_s(v);
          }
    }
    __syncthreads();
    #pragma unroll
    for (int c = 0; c < 4; c++) {
      const int f = tid + 512 * c;       // 2048 chunks: 64 rows x 32 chunks
      const int r = f >> 5, cc = f & 31;
      float4 vv = *(const float4*)(lc + r * 264 + cc * 8);
      *(float4*)(G + ((size_t)(row0 + pr * 64 + r) << 12) + col0 + cc * 8) = vv;
    }
    __syncthreads();
  }
}

// ======== mlp2 8-MFMA phase helper ========
template<int MH>
DEVINL void mmh(f32x4 (&acc)[4][2], bf16x8 (&af)[2][2], bf16x8 (&bf)[2][2]) {
  __builtin_amdgcn_s_setprio(1);
  #pragma unroll
  for (int mi2 = 0; mi2 < 2; mi2++)
    #pragma unroll
    for (int ni = 0; ni < 2; ni++)
      #pragma unroll
      for (int ks = 0; ks < 2; ks++)
        acc[MH * 2 + mi2][ni] = __builtin_amdgcn_mfma_f32_16x16x32_bf16(
            af[mi2][ks], bf[ni][ks], acc[MH * 2 + mi2][ni], 0, 0, 0);
  __builtin_amdgcn_s_setprio(0);
  __builtin_amdgcn_s_barrier();
}

// ---- MLP2: out += G @ W2t^T, NO split-K, NO atomics (RMW epilogue) ----
// 128x128 tile, grid(32,8)=256 blocks, K=4096, 512 thr (8 waves 2Mx4N,
// 64x32 out/wave), BK=64, 2 K-tiles/iter (32 iters), 4 phases x 8 MFMA.
// LDS 64KB -> 2 blocks/CU. Ledger in file header.
__global__ __launch_bounds__(512, 2) void k_gemm_mlp2(const __hip_bfloat16* __restrict__ G,
                                                      const __hip_bfloat16* __restrict__ W2t,
                                                      float* __restrict__ out) {
  __shared__ alignas(16) short smem[32768];  // 64KB: Ae Ao Be Bo x 8192
  short* Ae = smem;
  short* Ao = smem + 8192;
  short* Be = smem + 16384;
  short* Bo = smem + 24576;
  const int row0 = blockIdx.x * 128, col0 = blockIdx.y * 128;
  const int tid = threadIdx.x, lane = tid & 63, wid = tid >> 6;
  const int lr = lane & 15, lq = lane >> 4;
  const int wr = wid >> 2, wc = wid & 3;     // 2M x 4N: 64 rows x 32 cols
  const __hip_bfloat16* A = G + (size_t)row0 * 4096;
  const __hip_bfloat16* Bt = W2t + (size_t)col0 * 4096;

  // stage A-half h (64 rows with bit5==h): 512 chunks, 1 load/thread.
  // Wave-uniform LDS base + lane*16B (r = base + (lane>>3), P = lane&7).
  auto STGA = [&](int k0, int h, short* dst) {
    const int rp = tid >> 3, P = tid & 7;    // rp 0-63
    const int r = ((rp >> 5) << 6) | (h << 5) | (rp & 31);
    const int g = P ^ (r & 7);
    stage16(A + (size_t)r * 4096 + k0 + g * 8, dst + r * 64 + P * 8);
  };
  // stage B full tile (128 rows): 1024 chunks, 2 loads/thread
  auto STGB = [&](int k0, short* dst) {
    #pragma unroll
    for (int ii = 0; ii < 2; ii++) {
      const int f = tid + ii * 512;
      const int r = f >> 3, P = f & 7;
      const int g = P ^ (r & 7);
      stage16(Bt + (size_t)r * 4096 + k0 + g * 8, dst + r * 64 + P * 8);
    }
  };

  f32x4 acc[4][2] = {};
  bf16x8 af[2][2], bf[2][2];

  auto RDA = [&](const short* pa, int MH) {
    #pragma unroll
    for (int mi2 = 0; mi2 < 2; mi2++)
      #pragma unroll
      for (int ks = 0; ks < 2; ks++) {
        const int r = wr * 64 + MH * 32 + mi2 * 16 + lr;   // bit5 == MH
        af[mi2][ks] = *(const bf16x8*)(pa + r * 64 + (((ks * 4 + lq) ^ (r & 7)) << 3));
      }
  };
  auto RDB = [&](const short* pb) {
    #pragma unroll
    for (int ni = 0; ni < 2; ni++)
      #pragma unroll
      for (int ks = 0; ks < 2; ks++) {
        const int n = wc * 32 + ni * 16 + lr;
        bf[ni][ks] = *(const bf16x8*)(pb + n * 64 + (((ks * 4 + lq) ^ (n & 7)) << 3));
      }
  };

  // prologue (FIFO = steady state entering phE0): [Be0+Ae0.lo(3)]
  // [Ae0.hi(1)] [Bo0+Ao0.lo(3)] = 7 in flight; vmcnt(4) retires first 3.
  STGB(0, Be); STGA(0, 0, Ae);
  STGA(0, 1, Ae);
  STGB(64, Bo); STGA(64, 0, Ao);
  asm volatile("s_waitcnt vmcnt(4)" ::: "memory");
  __syncthreads();

  for (int i = 0; i < 32; ++i) {
    const int kE1 = (i + 1) * 128, kO0 = i * 128 + 64, kO1 = kE1 + 64;
    const bool more = (i + 1 < 32);
    // phE0: read E.MH0+B(E); stage Ao_i.hi; vmcnt(4) retires phO0'(Ae_i.hi)
    RDA(Ae, 0); RDB(Be);
    STGA(kO0, 1, Ao);
    asm volatile("s_waitcnt vmcnt(4)" ::: "memory");
    ph_sync();
    mmh<0>(acc, af, bf);
    // phE1: read E.MH1 (bf cached); stage Be'+Ae'.lo; vmcnt retires phO1'
    RDA(Ae, 1);
    if (more) {
      STGB(kE1, Be); STGA(kE1, 0, Ae);
      asm volatile("s_waitcnt vmcnt(4)" ::: "memory");
    } else {
      asm volatile("s_waitcnt vmcnt(1)" ::: "memory");
    }
    ph_sync();
    mmh<1>(acc, af, bf);
    // phO0: read O.MH0+B(O); stage Ae'.hi; vmcnt retires phE0 (Ao_i.hi)
    RDA(Ao, 0); RDB(Bo);
    if (more) {
      STGA(kE1, 1, Ae);
      asm volatile("s_waitcnt vmcnt(4)" ::: "memory");
    } else {
      asm volatile("s_waitcnt vmcnt(0)" ::: "memory");
    }
    ph_sync();
    mmh<0>(acc, af, bf);
    // phO1: read O.MH1; stage Bo'+Ao'.lo; vmcnt retires phE1' (Be',Ae'.lo)
    RDA(Ao, 1);
    if (more) {
      STGB(kO1, Bo); STGA(kO1, 0, Ao);
      asm volatile("s_waitcnt vmcnt(4)" ::: "memory");
    }
    ph_sync();
    mmh<1>(acc, af, bf);
  }

  // epilogue: plain RMW (out pre-initialized with x2 + b2 by k_ln)
  #pragma unroll
  for (int mi = 0; mi < 4; mi++)
    #pragma unroll
    for (int ni = 0; ni < 2; ni++)
      #pragma unroll
      for (int rr = 0; rr < 4; rr++) {
        const int grow = row0 + wr * 64 + (mi >> 1) * 32 + (mi & 1) * 16 + lq * 4 + rr;
        const int gcol = col0 + wc * 32 + ni * 16 + lr;
        float* p = out + (((size_t)grow << 10) + gcol);
        *p += acc[mi][ni][rr];
      }
}

extern "C" void kernel_launch(void* const* d_in, const int* in_sizes, int n_in,
                              void* d_out, int out_size, void* d_ws, size_t ws_size,
                              hipStream_t stream) {
  const float* x     = (const float*)d_in[0];
  const float* ln1_g = (const float*)d_in[1];
  const float* ln1_b = (const float*)d_in[2];
  const float* ln2_g = (const float*)d_in[3];
  const float* ln2_b = (const float*)d_in[4];
  const float* Wq    = (const float*)d_in[5];
  const float* bq    = (const float*)d_in[6];
  const float* Wk    = (const float*)d_in[7];
  const float* bk    = (const float*)d_in[8];
  const float* Wv    = (const float*)d_in[9];
  const float* bv    = (const float*)d_in[10];
  const float* W1    = (const float*)d_in[11];
  const float* b1    = (const float*)d_in[12];
  const float* W2    = (const float*)d_in[13];
  const float* b2    = (const float*)d_in[14];
  float* out = (float*)d_out;

  char* p = (char*)d_ws;
  auto alloc = [&](size_t bytes) { char* r = p; p += (bytes + 255) & ~(size_t)255; return r; };
  __hip_bfloat16* wqkv = (__hip_bfloat16*)alloc(3072 * 1024 * 2);
  __hip_bfloat16* w1t  = (__hip_bfloat16*)alloc(4096 * 1024 * 2);
  __hip_bfloat16* w2t  = (__hip_bfloat16*)alloc(1024 * 4096 * 2);
  float*          bqkv = (float*)alloc(3072 * 4);
  __hip_bfloat16* h1   = (__hip_bfloat16*)alloc(4096 * 1024 * 2);
  __hip_bfloat16* Qb   = (__hip_bfloat16*)alloc((size_t)64 * 65536 * 2);  // [64][1024][64]
  __hip_bfloat16* Kb   = (__hip_bfloat16*)alloc((size_t)64 * 65536 * 2);
  __hip_bfloat16* Vt   = (__hip_bfloat16*)alloc((size_t)64 * 65536 * 2);  // [64][64][1024]
  float*          TV   = (float*)alloc((size_t)64 * 8 * 64 * 4);
  float*          yb   = (float*)alloc((size_t)4096 * 1024 * 4);
  __hip_bfloat16* h2   = (__hip_bfloat16*)alloc(4096 * 1024 * 2);
  __hip_bfloat16* G    = (__hip_bfloat16*)alloc((size_t)4096 * 4096 * 2);
  (void)ws_size; (void)in_sizes; (void)n_in; (void)out_size;

  const dim3 b256(256), bt(32, 8);
  k_tcvt3<<<dim3(32, 32, 3), bt, 0, stream>>>(Wq, Wk, Wv, wqkv);
  k_tcvt<<<dim3(128, 32), bt, 0, stream>>>(W1, w1t, 1024, 4096, 0, 1024);
  k_tcvt<<<dim3(32, 128), bt, 0, stream>>>(W2, w2t, 4096, 1024, 0, 4096);
  k_pack_bias<<<12, b256, 0, stream>>>(bq, bk, bv, bqkv);

  k_ln<<<4096, b256, 0, stream>>>(x, nullptr, ln1_g, ln1_b, h1, nullptr, nullptr);
  k_gemm_qkv<<<dim3(32, 24), b256, 0, stream>>>(h1, wqkv, bqkv, Qb, Kb, Vt);
  k_tailv<<<64, b256, 0, stream>>>(Vt, TV);
  k_attn<<<dim3(16, 64), b256, 0, stream>>>(Qb, Kb, Vt, TV, yb);

  k_ln<<<4096, b256, 0, stream>>>(x, yb, ln2_g, ln2_b, h2, b2, out);
  k_gemm_mlp1<<<dim3(16, 16), dim3(512), 0, stream>>>(h2, w1t, b1, G);
  k_gemm_mlp2<<<dim3(32, 8), dim3(512), 0, stream>>>(G, w2t, out);
}

// Round 12
// 304.455 us; speedup vs baseline: 1.1848x; 1.0102x over previous
//
#include <hip/hip_runtime.h>
#include <hip/hip_bf16.h>
#include <math.h>

// Transformer block (pre-LN attn + MLP), B=4 T=1024 H=1024 K=16 HD=64.
// R22: k_gemm_qkv ported to the R21-mlp2 proven 4-phase counted-vmcnt loop
// (128x128 tile, 512 thr, 8 waves 2Mx4N 64x32/wave, BK=64, 64KB LDS ->
// 2 blocks/CU, identical staging ledger incl. tail vmcnts), lda=1024,
// 8 iters (K=1024), grid(32,24)=768 blocks. Q/K/V scatter epilogue
// remapped to the 8-wave acc layout; lc pitch 132 as before.
// mlp1: R19 8-phase 256x256. mlp2: R21 128x128 no-split-K RMW (atomic
// elimination confirmed: WRITE 32768->16384KB, 59.2->48.9us).
// Attention: fused flash-style, 64-row Q-tiles, separate lK/lV, 2 barriers
// per kt, K(kt+1) prefetch hidden under softmax, setprio on MFMA clusters;
// masked logits FILLED with 1e-9; fully-masked K-tiles contribute
// exp(1e-9-m)*suffixV analytically (TV precomputed).

typedef __attribute__((ext_vector_type(8))) short bf16x8;
typedef __attribute__((ext_vector_type(4))) float f32x4;

#define DEVINL __device__ __forceinline__

#define LOG2E_SCALE 0.18033688f      /* 0.125 * log2(e) */
#define MASK2 1.4426950408889634e-9f /* 1e-9 * log2(e) */

DEVINL void stage16(const __hip_bfloat16* g, short* l) {
  __builtin_amdgcn_global_load_lds(
      (const __attribute__((address_space(1))) unsigned int*)g,
      (__attribute__((address_space(3))) unsigned int*)l, 16, 0, 0);
}

DEVINL float bf2f(short u) {
  unsigned x = ((unsigned)(unsigned short)u) << 16;
  float f; __builtin_memcpy(&f, &x, 4); return f;
}

DEVINL short f2bf_s(float f) {
  __hip_bfloat16 h = __float2bfloat16(f);
  short s; __builtin_memcpy(&s, &h, 2); return s;
}

DEVINL float block_sum(float v, float* sb) {
  #pragma unroll
  for (int o = 32; o; o >>= 1) v += __shfl_down(v, o);
  const int lane = threadIdx.x & 63, w = threadIdx.x >> 6;
  if (lane == 0) sb[w] = v;
  __syncthreads();
  float r = sb[0] + sb[1] + sb[2] + sb[3];
  __syncthreads();
  return r;
}

// ======== shared phase-schedule helpers ========
DEVINL void ph_sync() {
  __builtin_amdgcn_s_barrier();
  asm volatile("s_waitcnt lgkmcnt(0)" ::: "memory");
  __builtin_amdgcn_sched_barrier(0);
}

// 8-MFMA phase (acc[4][2]; af = A-half MH, bf = 2 N-frags) — mlp2/qkv shape
template<int MH>
DEVINL void mmh(f32x4 (&acc)[4][2], bf16x8 (&af)[2][2], bf16x8 (&bf)[2][2]) {
  __builtin_amdgcn_s_setprio(1);
  #pragma unroll
  for (int mi2 = 0; mi2 < 2; mi2++)
    #pragma unroll
    for (int ni = 0; ni < 2; ni++)
      #pragma unroll
      for (int ks = 0; ks < 2; ks++)
        acc[MH * 2 + mi2][ni] = __builtin_amdgcn_mfma_f32_16x16x32_bf16(
            af[mi2][ks], bf[ni][ks], acc[MH * 2 + mi2][ni], 0, 0, 0);
  __builtin_amdgcn_s_setprio(0);
  __builtin_amdgcn_s_barrier();
}

// 16-MFMA phase for mlp1 (acc[8][4])
template<int MH, int NH>
DEVINL void ph_read(const short* pa, const short* pb, int wr, int wc,
                    int lr, int lq, bf16x8 (&af)[4][2], bf16x8 (&bf)[2][2]) {
  if (NH == 0) {
    #pragma unroll
    for (int mi2 = 0; mi2 < 4; mi2++)
      #pragma unroll
      for (int ks = 0; ks < 2; ks++) {
        const int r = wr * 128 + MH * 64 + mi2 * 16 + lr;
        af[mi2][ks] = *(const bf16x8*)(pa + r * 64 + (((ks * 4 + lq) ^ (r & 7)) << 3));
      }
  }
  #pragma unroll
  for (int ni2 = 0; ni2 < 2; ni2++)
    #pragma unroll
    for (int ks = 0; ks < 2; ks++) {
      const int n = wc * 64 + NH * 32 + ni2 * 16 + lr;
      bf[ni2][ks] = *(const bf16x8*)(pb + n * 64 + (((ks * 4 + lq) ^ (n & 7)) << 3));
    }
}

template<int MH, int NH>
DEVINL void ph_mfma(f32x4 (&acc)[8][4], bf16x8 (&af)[4][2], bf16x8 (&bf)[2][2]) {
  __builtin_amdgcn_s_setprio(1);
  #pragma unroll
  for (int mi2 = 0; mi2 < 4; mi2++)
    #pragma unroll
    for (int ni2 = 0; ni2 < 2; ni2++)
      #pragma unroll
      for (int ks = 0; ks < 2; ks++)
        acc[MH * 4 + mi2][NH * 2 + ni2] = __builtin_amdgcn_mfma_f32_16x16x32_bf16(
            af[mi2][ks], bf[ni2][ks], acc[MH * 4 + mi2][NH * 2 + ni2], 0, 0, 0);
  __builtin_amdgcn_s_setprio(0);
  __builtin_amdgcn_s_barrier();
}

// ---- transpose + f32->bf16: src[R][C] -> dst[(c+off)][r], dst pitch P ----
__global__ __launch_bounds__(256) void k_tcvt(const float* __restrict__ src,
                                              __hip_bfloat16* __restrict__ dst,
                                              int R, int C, int dstOff, int dstPitch) {
  __shared__ float tile[32][33];
  const int c0 = blockIdx.x * 32, r0 = blockIdx.y * 32;
  const int tx = threadIdx.x, ty = threadIdx.y;  // (32,8)
  #pragma unroll
  for (int i = 0; i < 32; i += 8)
    tile[ty + i][tx] = src[(size_t)(r0 + ty + i) * C + c0 + tx];
  __syncthreads();
  #pragma unroll
  for (int i = 0; i < 32; i += 8)
    dst[(size_t)(c0 + ty + i + dstOff) * dstPitch + r0 + tx] =
        __float2bfloat16(tile[tx][ty + i]);
}

// fused Wq/Wk/Wv transpose (z picks source; all 1024x1024, dst pitch 1024)
__global__ __launch_bounds__(256) void k_tcvt3(const float* __restrict__ Wq,
                                               const float* __restrict__ Wk,
                                               const float* __restrict__ Wv,
                                               __hip_bfloat16* __restrict__ dst) {
  __shared__ float tile[32][33];
  const float* src = blockIdx.z == 0 ? Wq : (blockIdx.z == 1 ? Wk : Wv);
  const int dstOff = blockIdx.z << 10;
  const int c0 = blockIdx.x * 32, r0 = blockIdx.y * 32;
  const int tx = threadIdx.x, ty = threadIdx.y;
  #pragma unroll
  for (int i = 0; i < 32; i += 8)
    tile[ty + i][tx] = src[(size_t)(r0 + ty + i) * 1024 + c0 + tx];
  __syncthreads();
  #pragma unroll
  for (int i = 0; i < 32; i += 8)
    dst[(size_t)(c0 + ty + i + dstOff) * 1024 + r0 + tx] =
        __float2bfloat16(tile[tx][ty + i]);
}

__global__ __launch_bounds__(256) void k_pack_bias(const float* __restrict__ bq,
                                                   const float* __restrict__ bk,
                                                   const float* __restrict__ bv,
                                                   float* __restrict__ o) {
  const int i = blockIdx.x * 256 + threadIdx.x;
  if (i < 3072)
    o[i] = i < 1024 ? bq[i] : (i < 2048 ? bk[i - 1024] : bv[i - 2048]);
}

// ---- LayerNorm (+residual add; optionally init out = x2 + b2) ----
__global__ __launch_bounds__(256) void k_ln(const float* __restrict__ x,
                                            const float* __restrict__ y,
                                            const float* __restrict__ g,
                                            const float* __restrict__ bb,
                                            __hip_bfloat16* __restrict__ o,
                                            const float* __restrict__ badd,
                                            float* __restrict__ oinit) {
  __shared__ float sb[4];
  const int t = threadIdx.x;
  const size_t base = (size_t)blockIdx.x * 1024 + t * 4;
  const int c = t * 4;
  float4 xv = *(const float4*)(x + base);
  if (y) {
    float4 yv = *(const float4*)(y + base);
    xv.x += yv.x; xv.y += yv.y; xv.z += yv.z; xv.w += yv.w;
    float4 ov;
    ov.x = xv.x + badd[c + 0]; ov.y = xv.y + badd[c + 1];
    ov.z = xv.z + badd[c + 2]; ov.w = xv.w + badd[c + 3];
    *(float4*)(oinit + base) = ov;
  }
  const float mu = block_sum(xv.x + xv.y + xv.z + xv.w, sb) * (1.f / 1024.f);
  const float dx = xv.x - mu, dy = xv.y - mu, dz = xv.z - mu, dw = xv.w - mu;
  const float var = block_sum(dx * dx + dy * dy + dz * dz + dw * dw, sb) * (1.f / 1024.f);
  const float rs = rsqrtf(var + 1e-5f);
  o[base + 0] = __float2bfloat16(dx * rs * g[c + 0] + bb[c + 0]);
  o[base + 1] = __float2bfloat16(dy * rs * g[c + 1] + bb[c + 1]);
  o[base + 2] = __float2bfloat16(dz * rs * g[c + 2] + bb[c + 2]);
  o[base + 3] = __float2bfloat16(dw * rs * g[c + 3] + bb[c + 3]);
}

// ---- QKV GEMM (R22): h1[4096,1024] @ Wqkv_t[3072,1024]^T, 4-phase ----
// 128x128 tile, grid(32,24)=768 blocks, 512 thr (8 waves 2Mx4N, 64x32
// out/wave), BK=64, 2 K-tiles/iter (8 iters), LDS 64KB -> 2 blocks/CU.
// Loop + ledger == R21 mlp2 (verified). Q pre-scaled by 0.125*log2e.
__global__ __launch_bounds__(512, 2) void k_gemm_qkv(
    const __hip_bfloat16* __restrict__ h1, const __hip_bfloat16* __restrict__ Wt,
    const float* __restrict__ bqkv, __hip_bfloat16* __restrict__ Q,
    __hip_bfloat16* __restrict__ K, __hip_bfloat16* __restrict__ Vt) {
  __shared__ alignas(16) short smem[32768];  // 64KB: Ae Ao Be Bo x 8192
  short* Ae = smem;
  short* Ao = smem + 8192;
  short* Be = smem + 16384;
  short* Bo = smem + 24576;
  const int row0 = blockIdx.x * 128, col0 = blockIdx.y * 128;
  const int tid = threadIdx.x, lane = tid & 63, wid = tid >> 6;
  const int lr = lane & 15, lq = lane >> 4;
  const int wr = wid >> 2, wc = wid & 3;     // 2M x 4N: 64 rows x 32 cols
  const __hip_bfloat16* A = h1 + (size_t)row0 * 1024;
  const __hip_bfloat16* Bt = Wt + (size_t)col0 * 1024;

  auto STGA = [&](int k0, int h, short* dst) {
    const int rp = tid >> 3, P = tid & 7;    // rp 0-63
    const int r = ((rp >> 5) << 6) | (h << 5) | (rp & 31);
    const int g = P ^ (r & 7);
    stage16(A + (size_t)r * 1024 + k0 + g * 8, dst + r * 64 + P * 8);
  };
  auto STGB = [&](int k0, short* dst) {
    #pragma unroll
    for (int ii = 0; ii < 2; ii++) {
      const int f = tid + ii * 512;
      const int r = f >> 3, P = f & 7;
      const int g = P ^ (r & 7);
      stage16(Bt + (size_t)r * 1024 + k0 + g * 8, dst + r * 64 + P * 8);
    }
  };

  f32x4 acc[4][2] = {};
  bf16x8 af[2][2], bf[2][2];

  auto RDA = [&](const short* pa, int MH) {
    #pragma unroll
    for (int mi2 = 0; mi2 < 2; mi2++)
      #pragma unroll
      for (int ks = 0; ks < 2; ks++) {
        const int r = wr * 64 + MH * 32 + mi2 * 16 + lr;   // bit5 == MH
        af[mi2][ks] = *(const bf16x8*)(pa + r * 64 + (((ks * 4 + lq) ^ (r & 7)) << 3));
      }
  };
  auto RDB = [&](const short* pb) {
    #pragma unroll
    for (int ni = 0; ni < 2; ni++)
      #pragma unroll
      for (int ks = 0; ks < 2; ks++) {
        const int n = wc * 32 + ni * 16 + lr;
        bf[ni][ks] = *(const bf16x8*)(pb + n * 64 + (((ks * 4 + lq) ^ (n & 7)) << 3));
      }
  };

  // prologue (FIFO): [Be0+Ae0.lo(3)] [Ae0.hi(1)] [Bo0+Ao0.lo(3)] = 7;
  // vmcnt(4) retires first 3.
  STGB(0, Be); STGA(0, 0, Ae);
  STGA(0, 1, Ae);
  STGB(64, Bo); STGA(64, 0, Ao);
  asm volatile("s_waitcnt vmcnt(4)" ::: "memory");
  __syncthreads();

  for (int i = 0; i < 8; ++i) {
    const int kE1 = (i + 1) * 128, kO0 = i * 128 + 64, kO1 = kE1 + 64;
    const bool more = (i + 1 < 8);
    // phE0
    RDA(Ae, 0); RDB(Be);
    STGA(kO0, 1, Ao);
    asm volatile("s_waitcnt vmcnt(4)" ::: "memory");
    ph_sync();
    mmh<0>(acc, af, bf);
    // phE1
    RDA(Ae, 1);
    if (more) {
      STGB(kE1, Be); STGA(kE1, 0, Ae);
      asm volatile("s_waitcnt vmcnt(4)" ::: "memory");
    } else {
      asm volatile("s_waitcnt vmcnt(1)" ::: "memory");
    }
    ph_sync();
    mmh<1>(acc, af, bf);
    // phO0
    RDA(Ao, 0); RDB(Bo);
    if (more) {
      STGA(kE1, 1, Ae);
      asm volatile("s_waitcnt vmcnt(4)" ::: "memory");
    } else {
      asm volatile("s_waitcnt vmcnt(0)" ::: "memory");
    }
    ph_sync();
    mmh<0>(acc, af, bf);
    // phO1
    RDA(Ao, 1);
    if (more) {
      STGB(kO1, Bo); STGA(kO1, 0, Ao);
      asm volatile("s_waitcnt vmcnt(4)" ::: "memory");
    }
    ph_sync();
    mmh<1>(acc, af, bf);
  }

  // ---- Q/K/V scatter epilogue (8-wave remap of the original) ----
  const int which = col0 >> 10;                 // uniform: 0=Q 1=K 2=V
  const int h0 = (col0 & 1023) >> 6;
  const int b = row0 >> 10, t0 = row0 & 1023;
  short* lc = smem;                             // 128*132 = 16896 shorts
  if (which < 2) {
    const float qs = (which == 0) ? LOG2E_SCALE : 1.f;
    #pragma unroll
    for (int mi = 0; mi < 4; mi++)
      #pragma unroll
      for (int ni = 0; ni < 2; ni++)
        #pragma unroll
        for (int rr = 0; rr < 4; rr++) {
          const int row = wr * 64 + (mi >> 1) * 32 + (mi & 1) * 16 + lq * 4 + rr;
          const int col = wc * 32 + ni * 16 + lr;
          lc[row * 132 + col] = f2bf_s((acc[mi][ni][rr] + bqkv[col0 + col]) * qs);
        }
    __syncthreads();
    __hip_bfloat16* O = which == 0 ? Q : K;
    #pragma unroll
    for (int c = 0; c < 4; c++) {
      const int f = tid + 512 * c;              // 2048 16B-chunks (128x128)
      const int r = f >> 4, cc = f & 15;
      const int col = cc * 8;
      const int head = h0 + (col >> 6), d = col & 63;
      float4 vv = *(const float4*)(lc + r * 132 + col);
      *(float4*)(O + (((size_t)(b * 16 + head)) << 16) + (t0 + r) * 64 + d) = vv;
    }
  } else {
    // transposed epilogue: lc[col][row]
    #pragma unroll
    for (int mi = 0; mi < 4; mi++)
      #pragma unroll
      for (int ni = 0; ni < 2; ni++)
        #pragma unroll
        for (int rr = 0; rr < 4; rr++) {
          const int row = wr * 64 + (mi >> 1) * 32 + (mi & 1) * 16 + lq * 4 + rr;
          const int col = wc * 32 + ni * 16 + lr;
          lc[col * 132 + row] = f2bf_s(acc[mi][ni][rr] + bqkv[col0 + col]);
        }
    __syncthreads();
    #pragma unroll
    for (int c = 0; c < 4; c++) {
      const int f = tid + 512 * c;
      const int dl = f >> 4, tc = f & 15;       // local d 0..127, t-chunk
      const int head = h0 + (dl >> 6), d = dl & 63;
      float4 vv = *(const float4*)(lc + dl * 132 + tc * 8);
      *(float4*)(Vt + (((size_t)(b * 16 + head)) << 16) + (size_t)d * 1024 +
                 t0 + tc * 8) = vv;
    }
  }
}

// ---- tail V sums: TV[hb][qt][d] = sum_{t >= (qt+1)*128} Vt[hb][d][t] ----
__global__ __launch_bounds__(256) void k_tailv(const __hip_bfloat16* __restrict__ Vt,
                                               float* __restrict__ TV) {
  __shared__ float ts[8][64];
  const int hb = blockIdx.x, tid = threadIdx.x;
  const __hip_bfloat16* Vh = Vt + ((size_t)hb << 16);
  for (int w = tid; w < 512; w += 256) {
    const int kt = w >> 6, d = w & 63;
    const short* p = (const short*)(Vh + (size_t)d * 1024 + kt * 128);
    float s = 0.f;
    for (int j = 0; j < 128; j += 8) {
      bf16x8 v = *(const bf16x8*)(p + j);
      #pragma unroll
      for (int e = 0; e < 8; e++) s += bf2f(v[e]);
    }
    ts[kt][d] = s;
  }
  __syncthreads();
  for (int w = tid; w < 512; w += 256) {
    const int qt = w >> 6, d = w & 63;
    float s = 0.f;
    for (int kt = qt + 1; kt < 8; kt++) s += ts[kt][d];
    TV[((size_t)hb * 8 + qt) * 64 + d] = s;
  }
}

// ---- fused attention: one block = (64 q-rows, one head); 1024 blocks ----
// Separate lK/lV buffers; 2 barriers per kt; K(kt+1) prefetched alongside
// V(kt) so its latency hides under softmax+PV; setprio on MFMA clusters.
__global__ __launch_bounds__(256, 3) void k_attn(
    const __hip_bfloat16* __restrict__ Q, const __hip_bfloat16* __restrict__ K,
    const __hip_bfloat16* __restrict__ Vt, const float* __restrict__ TV,
    float* __restrict__ y) {
  __shared__ short lp[64 * 130];   // P-tile (padded)
  __shared__ short lK[128 * 64];   // K-tile, swizzled
  __shared__ short lV[128 * 64];   // V^T-tile, swizzled
  const int hb = blockIdx.y;
  const int j = (blockIdx.y & 32) ? (15 - (int)blockIdx.x) : (int)blockIdx.x;
  const int q0 = j * 64;
  const int nkt = (j >> 1) + 1;    // K-tiles (128 wide) to compute
  const int tid = threadIdx.x, lane = tid & 63, wave = tid >> 6;
  const int lr = lane & 15, lq = lane >> 4;
  const int wm = wave * 16;        // wave owns q-rows [q0+wm, q0+wm+16)
  const __hip_bfloat16* Qh = Q + ((size_t)hb << 16);
  const __hip_bfloat16* Kh = K + ((size_t)hb << 16);
  const __hip_bfloat16* Vh = Vt + ((size_t)hb << 16);

  // Q A-frags: direct global loads (rows q0+wm+lr, cols s*32+lq*8)
  bf16x8 qf[2];
  #pragma unroll
  for (int s = 0; s < 2; s++)
    qf[s] = *(const bf16x8*)((const short*)Qh +
                             (size_t)(q0 + wm + lr) * 64 + s * 32 + lq * 8);

  f32x4 oacc[4] = {};
  float mrow[4], lrow[4];
  #pragma unroll
  for (int r = 0; r < 4; r++) { mrow[r] = -1e30f; lrow[r] = 0.f; }

  // prologue: stage K(0)
  for (int c = tid; c < 1024; c += 256)
    stage16(Kh + (size_t)(c >> 3) * 64 + (((c & 7) ^ ((c >> 3) & 7)) << 3),
            lK + c * 8);
  __syncthreads();  // K(0) visible

  for (int kt = 0; kt < nkt; kt++) {
    const int k0 = kt * 128;
    // ---- QK^T from lK ----
    f32x4 sacc[8] = {};
    __builtin_amdgcn_s_setprio(1);
    #pragma unroll
    for (int s = 0; s < 2; s++) {
      bf16x8 bf[8];
      #pragma unroll
      for (int ni = 0; ni < 8; ni++) {
        const int n = ni * 16 + lr;
        bf[ni] = *(const bf16x8*)(lK + n * 64 + (((s * 4 + lq) ^ (n & 7)) << 3));
      }
      #pragma unroll
      for (int ni = 0; ni < 8; ni++)
        sacc[ni] = __builtin_amdgcn_mfma_f32_16x16x32_bf16(
            qf[s], bf[ni], sacc[ni], 0, 0, 0);
    }
    __builtin_amdgcn_s_setprio(0);
    __syncthreads();  // barA: lK frag reads + prev PV's lp/lV reads done
    // ---- V(kt) + K(kt+1) DMA (latency hides under softmax below) ----
    for (int c = tid; c < 1024; c += 256)
      stage16(Vh + (size_t)(c >> 4) * 1024 + k0 + (((c & 15) ^ ((c >> 4) & 15)) << 3),
              lV + c * 8);
    if (kt + 1 < nkt) {
      const int k1 = k0 + 128;
      for (int c = tid; c < 1024; c += 256)
        stage16(Kh + (size_t)(k1 + (c >> 3)) * 64 + (((c & 7) ^ ((c >> 3) & 7)) << 3),
                lK + c * 8);
    }
    // ---- online softmax, base-2 domain ----
    const bool last = (kt == nkt - 1);
    #pragma unroll
    for (int r = 0; r < 4; r++) {
      const int grow = q0 + wm + lq * 4 + r;   // global q row
      float tmax = -1e30f;
      #pragma unroll
      for (int ni = 0; ni < 8; ni++) {
        float v = sacc[ni][r];
        if (last && (k0 + ni * 16 + lr) > grow) v = MASK2;
        sacc[ni][r] = v;
        tmax = fmaxf(tmax, v);
      }
      #pragma unroll
      for (int msk = 8; msk; msk >>= 1) tmax = fmaxf(tmax, __shfl_xor(tmax, msk));
      const float mn = fmaxf(mrow[r], tmax);
      const float al = __builtin_amdgcn_exp2f(mrow[r] - mn);
      float rs = 0.f;
      #pragma unroll
      for (int ni = 0; ni < 8; ni++) {
        const float pv = __builtin_amdgcn_exp2f(sacc[ni][r] - mn);
        sacc[ni][r] = pv;
        rs += pv;
      }
      #pragma unroll
      for (int msk = 8; msk; msk >>= 1) rs += __shfl_xor(rs, msk);
      mrow[r] = mn;
      lrow[r] = lrow[r] * al + rs;
      #pragma unroll
      for (int ni = 0; ni < 4; ni++) oacc[ni][r] *= al;
    }
    // P -> lp (padded pitch 130)
    #pragma unroll
    for (int r = 0; r < 4; r++) {
      const int row = wm + lq * 4 + r;
      #pragma unroll
      for (int ni = 0; ni < 8; ni++)
        lp[row * 130 + ni * 16 + lr] = f2bf_s(sacc[ni][r]);
    }
    __syncthreads();  // barB: V(kt)+K(kt+1) landed (vmcnt drain) + P visible
    // ---- PV from lp, lV ----
    __builtin_amdgcn_s_setprio(1);
    #pragma unroll
    for (int ks = 0; ks < 4; ks++) {
      bf16x8 pa, vb[4];
      pa = *(const bf16x8*)(lp + (wm + lr) * 130 + ks * 32 + lq * 8);
      #pragma unroll
      for (int ni = 0; ni < 4; ni++) {
        const int d = ni * 16 + lr;
        vb[ni] = *(const bf16x8*)(lV + d * 128 + (((ks * 4 + lq) ^ (d & 15)) << 3));
      }
      #pragma unroll
      for (int ni = 0; ni < 4; ni++)
        oacc[ni] = __builtin_amdgcn_mfma_f32_16x16x32_bf16(
            pa, vb[ni], oacc[ni], 0, 0, 0);
    }
    __builtin_amdgcn_s_setprio(0);
    // no barrier here: next QK reads lK (disjoint from lp/lV); barA covers reuse
  }

  const int b = hb >> 4, h = hb & 15;
  const float cv = (float)(1024 - nkt * 128);
  const float* tv = TV + ((size_t)hb * 8 + (j >> 1)) * 64;
  #pragma unroll
  for (int r = 0; r < 4; r++) {
    const int t = q0 + wm + lq * 4 + r;
    const float tail = __builtin_amdgcn_exp2f(MASK2 - mrow[r]);
    const float inv = 1.f / (lrow[r] + cv * tail);
    #pragma unroll
    for (int ni = 0; ni < 4; ni++) {
      const int d = ni * 16 + lr;
      y[((size_t)(b * 1024 + t) << 10) + h * 64 + d] =
          (oacc[ni][r] + tail * tv[d]) * inv;
    }
  }
}

// ---- MLP1: h2[4096,1024] @ W1t[4096,1024]^T + b1 -> tanh-GELU -> G bf16 ----
// 256x256 tile, 512 thr, BK=64, 2 K-tiles/iter, 8-phase counted-vmcnt.
__global__ __launch_bounds__(512, 2) void k_gemm_mlp1(const __hip_bfloat16* __restrict__ h2,
                                                      const __hip_bfloat16* __restrict__ W1t,
                                                      const float* __restrict__ b1,
                                                      __hip_bfloat16* __restrict__ G) {
  __shared__ alignas(16) short smem[65536];  // 128KB: Ae Ao Be Bo x 16384
  short* Ae = smem;
  short* Ao = smem + 16384;
  short* Be = smem + 32768;
  short* Bo = smem + 49152;
  const int row0 = blockIdx.x * 256, col0 = blockIdx.y * 256;
  const int tid = threadIdx.x, lane = tid & 63, wid = tid >> 6;
  const int lr = lane & 15, lq = lane >> 4;
  const int wr = wid >> 2, wc = wid & 3;
  const __hip_bfloat16* A = h2 + (size_t)row0 * 1024;
  const __hip_bfloat16* Bt = W1t + (size_t)col0 * 1024;

  auto STG = [&](const __hip_bfloat16* src, int k0, int h, short* dst, int SH) {
    #pragma unroll
    for (int ii = 0; ii < 2; ii++) {
      const int f = tid + ii * 512;
      const int rp = f >> 3, P = f & 7;
      const int r = ((rp >> SH) << (SH + 1)) | (h << SH) | (rp & ((1 << SH) - 1));
      const int g = P ^ (r & 7);
      stage16(src + (size_t)r * 1024 + k0 + g * 8, dst + r * 64 + P * 8);
    }
  };

  f32x4 acc[8][4] = {};
  bf16x8 af[4][2], bf[2][2];

  // prologue: E0 (4 parts) + O0.A0, O0.B0; vmcnt(4) retires E0 (FIFO).
  STG(A, 0, 0, Ae, 6);  STG(Bt, 0, 0, Be, 5);
  STG(A, 0, 1, Ae, 6);  STG(Bt, 0, 1, Be, 5);
  STG(A, 64, 0, Ao, 6); STG(Bt, 64, 0, Bo, 5);
  asm volatile("s_waitcnt vmcnt(4)" ::: "memory");
  __syncthreads();

  for (int i = 0; i < 8; ++i) {
    const int kE1 = (i + 1) * 128;       // next even K-tile
    const int kO0 = i * 128 + 64;        // this iter's odd K-tile
    const int kO1 = kE1 + 64;            // next odd K-tile
    const bool more = (i + 1 < 8);
    ph_read<0, 0>(Ae, Be, wr, wc, lr, lq, af, bf);
    STG(A, kO0, 1, Ao, 6);
    ph_sync();
    ph_mfma<0, 0>(acc, af, bf);
    ph_read<0, 1>(Ae, Be, wr, wc, lr, lq, af, bf);
    STG(Bt, kO0, 1, Bo, 5);
    ph_sync();
    ph_mfma<0, 1>(acc, af, bf);
    ph_read<1, 0>(Ae, Be, wr, wc, lr, lq, af, bf);
    if (more) STG(A, kE1, 0, Ae, 6);
    ph_sync();
    ph_mfma<1, 0>(acc, af, bf);
    ph_read<1, 1>(Ae, Be, wr, wc, lr, lq, af, bf);
    if (more) {
      STG(Bt, kE1, 0, Be, 5);
      asm volatile("s_waitcnt vmcnt(4)" ::: "memory");
    } else {
      asm volatile("s_waitcnt vmcnt(0)" ::: "memory");
    }
    ph_sync();
    ph_mfma<1, 1>(acc, af, bf);
    ph_read<0, 0>(Ao, Bo, wr, wc, lr, lq, af, bf);
    if (more) STG(A, kE1, 1, Ae, 6);
    ph_sync();
    ph_mfma<0, 0>(acc, af, bf);
    ph_read<0, 1>(Ao, Bo, wr, wc, lr, lq, af, bf);
    if (more) STG(Bt, kE1, 1, Be, 5);
    ph_sync();
    ph_mfma<0, 1>(acc, af, bf);
    ph_read<1, 0>(Ao, Bo, wr, wc, lr, lq, af, bf);
    if (more) STG(A, kO1, 0, Ao, 6);
    ph_sync();
    ph_mfma<1, 0>(acc, af, bf);
    ph_read<1, 1>(Ao, Bo, wr, wc, lr, lq, af, bf);
    if (more) {
      STG(Bt, kO1, 0, Bo, 5);
      asm volatile("s_waitcnt vmcnt(4)" ::: "memory");
    }
    ph_sync();
    ph_mfma<1, 1>(acc, af, bf);
  }

  // epilogue: tanh-GELU -> bf16 via 4x 64-row lc passes (lc = smem)
  short* lc = smem;
  #pragma unroll
  for (int pr = 0; pr < 4; pr++) {
    if ((wid >> 2) == (pr >> 1)) {
      const int mib = (pr & 1) * 4;
      #pragma unroll
      for (int mi2 = 0; mi2 < 4; mi2++)
        #pragma unroll
        for (int ni = 0; ni < 4; ni++)
          #pragma unroll
          for (int rr = 0; rr < 4; rr++) {
            const int rloc = mi2 * 16 + lq * 4 + rr;
            const int col = (wid & 3) * 64 + ni * 16 + lr;
            float v = acc[mib + mi2][ni][rr] + b1[col0 + col];
            const float u2 = fminf(v * (2.3022079f + 0.1029434f * v * v), 80.f);
            const float e = __builtin_amdgcn_exp2f(u2);
            v = v * e * __builtin_amdgcn_rcpf(e + 1.f);
            lc[rloc * 264 + col] = f2bf_s(v);
          }
    }
    __syncthreads();
    #pragma unroll
    for (int c = 0; c < 4; c++) {
      const int f = tid + 512 * c;       // 2048 chunks: 64 rows x 32 chunks
      const int r = f >> 5, cc = f & 31;
      float4 vv = *(const float4*)(lc + r * 264 + cc * 8);
      *(float4*)(G + ((size_t)(row0 + pr * 64 + r) << 12) + col0 + cc * 8) = vv;
    }
    __syncthreads();
  }
}

// ---- MLP2: out += G @ W2t^T, NO split-K, NO atomics (RMW epilogue) ----
// 128x128 tile, grid(32,8)=256 blocks, K=4096, 512 thr (8 waves 2Mx4N,
// 64x32 out/wave), BK=64, 2 K-tiles/iter (32 iters), 4 phases x 8 MFMA.
// LDS 64KB -> 2 blocks/CU.
__global__ __launch_bounds__(512, 2) void k_gemm_mlp2(const __hip_bfloat16* __restrict__ G,
                                                      const __hip_bfloat16* __restrict__ W2t,
                                                      float* __restrict__ out) {
  __shared__ alignas(16) short smem[32768];  // 64KB: Ae Ao Be Bo x 8192
  short* Ae = smem;
  short* Ao = smem + 8192;
  short* Be = smem + 16384;
  short* Bo = smem + 24576;
  const int row0 = blockIdx.x * 128, col0 = blockIdx.y * 128;
  const int tid = threadIdx.x, lane = tid & 63, wid = tid >> 6;
  const int lr = lane & 15, lq = lane >> 4;
  const int wr = wid >> 2, wc = wid & 3;     // 2M x 4N: 64 rows x 32 cols
  const __hip_bfloat16* A = G + (size_t)row0 * 4096;
  const __hip_bfloat16* Bt = W2t + (size_t)col0 * 4096;

  auto STGA = [&](int k0, int h, short* dst) {
    const int rp = tid >> 3, P = tid & 7;    // rp 0-63
    const int r = ((rp >> 5) << 6) | (h << 5) | (rp & 31);
    const int g = P ^ (r & 7);
    stage16(A + (size_t)r * 4096 + k0 + g * 8, dst + r * 64 + P * 8);
  };
  auto STGB = [&](int k0, short* dst) {
    #pragma unroll
    for (int ii = 0; ii < 2; ii++) {
      const int f = tid + ii * 512;
      const int r = f >> 3, P = f & 7;
      const int g = P ^ (r & 7);
      stage16(Bt + (size_t)r * 4096 + k0 + g * 8, dst + r * 64 + P * 8);
    }
  };

  f32x4 acc[4][2] = {};
  bf16x8 af[2][2], bf[2][2];

  auto RDA = [&](const short* pa, int MH) {
    #pragma unroll
    for (int mi2 = 0; mi2 < 2; mi2++)
      #pragma unroll
      for (int ks = 0; ks < 2; ks++) {
        const int r = wr * 64 + MH * 32 + mi2 * 16 + lr;   // bit5 == MH
        af[mi2][ks] = *(const bf16x8*)(pa + r * 64 + (((ks * 4 + lq) ^ (r & 7)) << 3));
      }
  };
  auto RDB = [&](const short* pb) {
    #pragma unroll
    for (int ni = 0; ni < 2; ni++)
      #pragma unroll
      for (int ks = 0; ks < 2; ks++) {
        const int n = wc * 32 + ni * 16 + lr;
        bf[ni][ks] = *(const bf16x8*)(pb + n * 64 + (((ks * 4 + lq) ^ (n & 7)) << 3));
      }
  };

  STGB(0, Be); STGA(0, 0, Ae);
  STGA(0, 1, Ae);
  STGB(64, Bo); STGA(64, 0, Ao);
  asm volatile("s_waitcnt vmcnt(4)" ::: "memory");
  __syncthreads();

  for (int i = 0; i < 32; ++i) {
    const int kE1 = (i + 1) * 128, kO0 = i * 128 + 64, kO1 = kE1 + 64;
    const bool more = (i + 1 < 32);
    RDA(Ae, 0); RDB(Be);
    STGA(kO0, 1, Ao);
    asm volatile("s_waitcnt vmcnt(4)" ::: "memory");
    ph_sync();
    mmh<0>(acc, af, bf);
    RDA(Ae, 1);
    if (more) {
      STGB(kE1, Be); STGA(kE1, 0, Ae);
      asm volatile("s_waitcnt vmcnt(4)" ::: "memory");
    } else {
      asm volatile("s_waitcnt vmcnt(1)" ::: "memory");
    }
    ph_sync();
    mmh<1>(acc, af, bf);
    RDA(Ao, 0); RDB(Bo);
    if (more) {
      STGA(kE1, 1, Ae);
      asm volatile("s_waitcnt vmcnt(4)" ::: "memory");
    } else {
      asm volatile("s_waitcnt vmcnt(0)" ::: "memory");
    }
    ph_sync();
    mmh<0>(acc, af, bf);
    RDA(Ao, 1);
    if (more) {
      STGB(kO1, Bo); STGA(kO1, 0, Ao);
      asm volatile("s_waitcnt vmcnt(4)" ::: "memory");
    }
    ph_sync();
    mmh<1>(acc, af, bf);
  }

  // epilogue: plain RMW (out pre-initialized with x2 + b2 by k_ln)
  #pragma unroll
  for (int mi = 0; mi < 4; mi++)
    #pragma unroll
    for (int ni = 0; ni < 2; ni++)
      #pragma unroll
      for (int rr = 0; rr < 4; rr++) {
        const int grow = row0 + wr * 64 + (mi >> 1) * 32 + (mi & 1) * 16 + lq * 4 + rr;
        const int gcol = col0 + wc * 32 + ni * 16 + lr;
        float* p = out + (((size_t)grow << 10) + gcol);
        *p += acc[mi][ni][rr];
      }
}

extern "C" void kernel_launch(void* const* d_in, const int* in_sizes, int n_in,
                              void* d_out, int out_size, void* d_ws, size_t ws_size,
                              hipStream_t stream) {
  const float* x     = (const float*)d_in[0];
  const float* ln1_g = (const float*)d_in[1];
  const float* ln1_b = (const float*)d_in[2];
  const float* ln2_g = (const float*)d_in[3];
  const float* ln2_b = (const float*)d_in[4];
  const float* Wq    = (const float*)d_in[5];
  const float* bq    = (const float*)d_in[6];
  const float* Wk    = (const float*)d_in[7];
  const float* bk    = (const float*)d_in[8];
  const float* Wv    = (const float*)d_in[9];
  const float* bv    = (const float*)d_in[10];
  const float* W1    = (const float*)d_in[11];
  const float* b1    = (const float*)d_in[12];
  const float* W2    = (const float*)d_in[13];
  const float* b2    = (const float*)d_in[14];
  float* out = (float*)d_out;

  char* p = (char*)d_ws;
  auto alloc = [&](size_t bytes) { char* r = p; p += (bytes + 255) & ~(size_t)255; return r; };
  __hip_bfloat16* wqkv = (__hip_bfloat16*)alloc(3072 * 1024 * 2);
  __hip_bfloat16* w1t  = (__hip_bfloat16*)alloc(4096 * 1024 * 2);
  __hip_bfloat16* w2t  = (__hip_bfloat16*)alloc(1024 * 4096 * 2);
  float*          bqkv = (float*)alloc(3072 * 4);
  __hip_bfloat16* h1   = (__hip_bfloat16*)alloc(4096 * 1024 * 2);
  __hip_bfloat16* Qb   = (__hip_bfloat16*)alloc((size_t)64 * 65536 * 2);  // [64][1024][64]
  __hip_bfloat16* Kb   = (__hip_bfloat16*)alloc((size_t)64 * 65536 * 2);
  __hip_bfloat16* Vt   = (__hip_bfloat16*)alloc((size_t)64 * 65536 * 2);  // [64][64][1024]
  float*          TV   = (float*)alloc((size_t)64 * 8 * 64 * 4);
  float*          yb   = (float*)alloc((size_t)4096 * 1024 * 4);
  __hip_bfloat16* h2   = (__hip_bfloat16*)alloc(4096 * 1024 * 2);
  __hip_bfloat16* G    = (__hip_bfloat16*)alloc((size_t)4096 * 4096 * 2);
  (void)ws_size; (void)in_sizes; (void)n_in; (void)out_size;

  const dim3 b256(256), bt(32, 8);
  k_tcvt3<<<dim3(32, 32, 3), bt, 0, stream>>>(Wq, Wk, Wv, wqkv);
  k_tcvt<<<dim3(128, 32), bt, 0, stream>>>(W1, w1t, 1024, 4096, 0, 1024);
  k_tcvt<<<dim3(32, 128), bt, 0, stream>>>(W2, w2t, 4096, 1024, 0, 4096);
  k_pack_bias<<<12, b256, 0, stream>>>(bq, bk, bv, bqkv);

  k_ln<<<4096, b256, 0, stream>>>(x, nullptr, ln1_g, ln1_b, h1, nullptr, nullptr);
  k_gemm_qkv<<<dim3(32, 24), dim3(512), 0, stream>>>(h1, wqkv, bqkv, Qb, Kb, Vt);
  k_tailv<<<64, b256, 0, stream>>>(Vt, TV);
  k_attn<<<dim3(16, 64), b256, 0, stream>>>(Qb, Kb, Vt, TV, yb);

  k_ln<<<4096, b256, 0, stream>>>(x, yb, ln2_g, ln2_b, h2, b2, out);
  k_gemm_mlp1<<<dim3(16, 16), dim3(512), 0, stream>>>(h2, w1t, b1, G);
  k_gemm_mlp2<<<dim3(32, 8), dim3(512), 0, stream>>>(G, w2t, out);
}